// Round 4
// baseline (3686.328 us; speedup 1.0000x reference)
//
#include <hip/hip_runtime.h>
#include <hip/hip_bf16.h>

namespace {

constexpr int NN   = 8192;    // nodes
constexpr int NE   = 131072;  // edges
constexpr int SD   = 256;     // SDIM
constexpr int ED   = 128;     // EDIM
constexpr int NL   = 5;       // layers
constexpr int DINc = 644;     // 2*SD + ED + 4
constexpr int KP1  = 672;     // DIN padded to mult of 32
constexpr int DOUTc= 513;
constexpr int HIDc = 256;

typedef __bf16 bf16x8 __attribute__((ext_vector_type(8)));
typedef float  f32x4  __attribute__((ext_vector_type(4)));

__device__ __forceinline__ float siluf(float x) { return x / (1.0f + __expf(-x)); }

enum { MODE_H = 0, MODE_OUT2 = 1, MODE_SADD = 2, MODE_SADD2 = 3 };
enum { SRC_FEAT = 0, SRC_BF16 = 1, SRC_F32 = 2 };

struct GemmArgs {
  const __hip_bfloat16* Wt;     // [256][K] bf16, row-major (k contiguous)
  const float* bias;            // f32 bias (b1L / b2L / bU1L / bU2L)
  const __hip_bfloat16* Abf;    // SRC_BF16 source, [M][K]
  const float* Af32;            // SRC_F32 source, [M][K]
  const int* src; const int* tgt;
  const __hip_bfloat16* s_ln;   // [NN][256]
  const __hip_bfloat16* e_bf;   // [NE][128]
  const __hip_bfloat16* tail;   // [NE][8] = {d,a,pn_s,pn_t,0,0,0,0}
  const __hip_bfloat16* w384;   // [256] W2[:,384] for fused wp
  const float* rn;              // [NE][3]
  float* mp;                    // [NE][3] out (fused wp)
  __hip_bfloat16* bf_out;       // h or t output
  __hip_bfloat16* wv_out;       // [NE][128] bf16
  __hip_bfloat16* e_bf_out;     // [NE][128]
  float* e_f32_out;             // d_out e region
  float* s_out;                 // d_out s region (RMW)
  const int* rawcnt;
  int write_e_f32;
};

__device__ __forceinline__ uint4 cvt8f(const float* p) {
  alignas(16) __hip_bfloat16 t8[8];
#pragma unroll
  for (int i = 0; i < 8; i++) t8[i] = __float2bfloat16(p[i]);
  return *(const uint4*)t8;
}

__device__ __forceinline__ float dot8(const uint4& a, const __hip_bfloat16* w) {
  const __hip_bfloat16* ap = (const __hip_bfloat16*)&a;
  float s = 0.f;
#pragma unroll
  for (int j = 0; j < 8; j++) s += __bfloat162float(ap[j]) * __bfloat162float(w[j]);
  return s;
}

// 16B-chunk positions in k-chunk-major LDS with XOR swizzle.
// Write (lane=(row*4+kc)) and read (lane=(kc=lhi, row=f*16+l16)) phases both conflict-free.
__device__ __forceinline__ int apos(int kc, int row) { return kc * 128 + (row ^ (kc << 2)); }
__device__ __forceinline__ int bpos(int kc, int n)   { return kc * 256 + (n   ^ (kc << 2)); }

// BM=128, BN=256, BK=32. 4 waves; wave-tile 128x64 (acc[8][4], 32 MFMA/step/wave).
// Reg-staged (merge-friendly 64B global runs) -> swizzled LDS; next-step loads issued
// before the MFMA block (issue-early / consume-late).
template<int MODE, int SRC, int KTOT>
__global__ __launch_bounds__(256) void gemm_k(GemmArgs g) {
  __shared__ alignas(16) unsigned short Ash[4 * 128 * 8];   // 8 KB
  __shared__ alignas(16) unsigned short Bsh[4 * 256 * 8];   // 16 KB
  const int tid = threadIdx.x, lane = tid & 63, wave = tid >> 6;
  const int l16 = lane & 15, lhi = lane >> 4;
  const int row0 = blockIdx.x * 128;
  const int ar = tid >> 2, aq = tid & 3;          // staging: row ar / ar+64, k-quarter aq
  const int arow0 = row0 + ar, arow1 = arow0 + 64;
  f32x4 acc[8][4] = {};
  float pwp0 = 0.f, pwp1 = 0.f;
  int sn0 = 0, tn0 = 0, sn1 = 0, tn1 = 0;
  if constexpr (SRC == SRC_FEAT) {
    sn0 = g.src[arow0]; tn0 = g.tgt[arow0];
    sn1 = g.src[arow1]; tn1 = g.tgt[arow1];
  }

  auto loadA = [&](int k0, uint4& o0, uint4& o1) {
    const int kq = k0 + aq * 8;
    if constexpr (SRC == SRC_FEAT) {
      if (k0 >= 640) {
        o0.x = o0.y = o0.z = o0.w = 0; o1 = o0;
        if (aq == 0) { o0 = *(const uint4*)(g.tail + (size_t)arow0 * 8);
                       o1 = *(const uint4*)(g.tail + (size_t)arow1 * 8); }
      } else {
        const __hip_bfloat16 *p0, *p1;
        if (k0 < 256)      { p0 = g.s_ln + (size_t)sn0 * SD + kq;         p1 = g.s_ln + (size_t)sn1 * SD + kq; }
        else if (k0 < 512) { p0 = g.s_ln + (size_t)tn0 * SD + (kq - 256); p1 = g.s_ln + (size_t)tn1 * SD + (kq - 256); }
        else               { p0 = g.e_bf + (size_t)arow0 * ED + (kq - 512); p1 = g.e_bf + (size_t)arow1 * ED + (kq - 512); }
        o0 = *(const uint4*)p0; o1 = *(const uint4*)p1;
      }
    } else if constexpr (SRC == SRC_BF16) {
      o0 = *(const uint4*)(g.Abf + (size_t)arow0 * KTOT + kq);
      o1 = *(const uint4*)(g.Abf + (size_t)arow1 * KTOT + kq);
    } else {
      o0 = cvt8f(g.Af32 + (size_t)arow0 * KTOT + kq);
      o1 = cvt8f(g.Af32 + (size_t)arow1 * KTOT + kq);
    }
  };
  auto loadB = [&](int k0, uint4* bc) {
#pragma unroll
    for (int i = 0; i < 4; i++) {
      const int c = tid + i * 256, n = c >> 2, q = c & 3;
      bc[i] = *(const uint4*)(g.Wt + (size_t)n * KTOT + k0 + q * 8);
    }
  };

  uint4 a0, a1, bc[4];
  loadA(0, a0, a1); loadB(0, bc);

  for (int k0 = 0; k0 < KTOT; k0 += 32) {
    // ---- store staged regs -> LDS (swizzled, conflict-free)
    *(uint4*)&Ash[apos(aq, ar) * 8]      = a0;
    *(uint4*)&Ash[apos(aq, ar + 64) * 8] = a1;
#pragma unroll
    for (int i = 0; i < 4; i++) {
      const int c = tid + i * 256, n = c >> 2, q = c & 3;
      *(uint4*)&Bsh[bpos(q, n) * 8] = bc[i];
    }
    __syncthreads();

    if constexpr (MODE == MODE_OUT2) {   // fused wp: uses this step's A regs
      pwp0 += dot8(a0, g.w384 + k0 + aq * 8);
      pwp1 += dot8(a1, g.w384 + k0 + aq * 8);
    }

    // ---- issue next step's global loads early (consumed after MFMA)
    uint4 na0, na1, nbc[4];
    const bool more = (k0 + 32 < KTOT);
    if (more) { loadA(k0 + 32, na0, na1); loadB(k0 + 32, nbc); }

    // ---- fragments + MFMA
    bf16x8 bfr[4];
#pragma unroll
    for (int fc = 0; fc < 4; fc++)
      bfr[fc] = *(const bf16x8*)&Bsh[bpos(lhi, wave * 64 + fc * 16 + l16) * 8];
#pragma unroll
    for (int fr = 0; fr < 8; fr++) {
      const bf16x8 afr = *(const bf16x8*)&Ash[apos(lhi, fr * 16 + l16) * 8];
#pragma unroll
      for (int fc = 0; fc < 4; fc++)
        acc[fr][fc] = __builtin_amdgcn_mfma_f32_16x16x32_bf16(afr, bfr[fc], acc[fr][fc], 0, 0, 0);
    }
    __syncthreads();
    if (more) {
      a0 = na0; a1 = na1;
#pragma unroll
      for (int i = 0; i < 4; i++) bc[i] = nbc[i];
    }
  }

  if constexpr (MODE == MODE_OUT2) {
    // quad-reduce (lanes 4a..4a+3) -> full dot for rows ar / ar+64
    pwp0 += __shfl_xor(pwp0, 1); pwp0 += __shfl_xor(pwp0, 2);
    pwp1 += __shfl_xor(pwp1, 1); pwp1 += __shfl_xor(pwp1, 2);
    if (aq == 0) {
      const float b384 = g.bias[384];
      const float w0 = tanhf(pwp0 + b384), w1 = tanhf(pwp1 + b384);
#pragma unroll
      for (int c = 0; c < 3; c++) {
        g.mp[(size_t)arow0 * 3 + c] = w0 * g.rn[(size_t)arow0 * 3 + c];
        g.mp[(size_t)arow1 * 3 + c] = w1 * g.rn[(size_t)arow1 * 3 + c];
      }
    }
  }

  // ---- epilogue: D[row = 4*(lane>>4)+r][col = lane&15] per 16x16 tile
#pragma unroll
  for (int fr = 0; fr < 8; fr++) {
#pragma unroll
    for (int fc = 0; fc < 4; fc++) {
      const int n = wave * 64 + fc * 16 + l16;
#pragma unroll
      for (int r = 0; r < 4; r++) {
        const int row = row0 + fr * 16 + lhi * 4 + r;
        const float valf = acc[fr][fc][r];
        if constexpr (MODE == MODE_H) {
          g.bf_out[(size_t)row * HIDc + n] = __float2bfloat16(siluf(valf + g.bias[n]));
        } else if constexpr (MODE == MODE_OUT2) {
          if (n < 128) {
            g.wv_out[(size_t)row * 128 + n] = __float2bfloat16(valf + g.bias[256 + n]);
          } else {
            const float sv = siluf(valf + g.bias[257 + n]);   // e_new cols = W2 cols 385..512
            g.e_bf_out[(size_t)row * ED + (n - 128)] = __float2bfloat16(sv);
            if (g.write_e_f32) g.e_f32_out[(size_t)row * ED + (n - 128)] = sv;
          }
        } else if constexpr (MODE == MODE_SADD) {
          const float rc = (float)g.rawcnt[row];
          g.s_out[(size_t)row * SD + n] += valf + rc * g.bias[n];
        } else {  // MODE_SADD2
          g.s_out[(size_t)row * SD + n] += valf + g.bias[n];
        }
      }
    }
  }
}

// ---- LayerNorm. 4 nodes/block, wave per node.
__global__ __launch_bounds__(256) void ln_k(const float* __restrict__ s,
                                            const float* __restrict__ gl, const float* __restrict__ bl,
                                            __hip_bfloat16* __restrict__ s_ln) {
  const int wave = threadIdx.x >> 6, lane = threadIdx.x & 63;
  const int node = blockIdx.x * 4 + wave;
  const float* srow = s + (size_t)node * SD;
  float x[4], sum = 0.f, sq = 0.f;
#pragma unroll
  for (int i = 0; i < 4; i++) { x[i] = srow[lane * 4 + i]; sum += x[i]; sq += x[i] * x[i]; }
#pragma unroll
  for (int off = 1; off < 64; off <<= 1) { sum += __shfl_xor(sum, off); sq += __shfl_xor(sq, off); }
  const float mu = sum * (1.0f / SD);
  const float var = sq * (1.0f / SD) - mu * mu;
  const float rstd = rsqrtf(var + 1e-5f);
#pragma unroll
  for (int i = 0; i < 4; i++) {
    const int c = lane * 4 + i;
    s_ln[(size_t)node * SD + c] = __float2bfloat16(gl[c] * (x[i] - mu) * rstd + bl[c]);
  }
}

// ---- per-edge attrs: rn + bf16 tail block {d,a,pn_src,pn_tgt,0,0,0,0}
__global__ void edge_attr_k(const float* __restrict__ p, const int* __restrict__ src, const int* __restrict__ tgt,
                            float* __restrict__ rn, __hip_bfloat16* __restrict__ tail) {
  const int e = blockIdx.x * blockDim.x + threadIdx.x;
  if (e >= NE) return;
  const int s_ = src[e], t_ = tgt[e];
  const float sx = p[s_ * 3], sy = p[s_ * 3 + 1], sz = p[s_ * 3 + 2];
  const float tx = p[t_ * 3], ty = p[t_ * 3 + 1], tz = p[t_ * 3 + 2];
  const float rx = tx - sx, ry = ty - sy, rz = tz - sz;
  const float a = tx * sx + ty * sy + tz * sz;
  const float rr = rx * rx + ry * ry + rz * rz;
  const float d = sqrtf(fmaxf(rr, 1e-6f));
  const float inv = 1.0f / (1.0f + d);
  rn[e * 3] = rx * inv; rn[e * 3 + 1] = ry * inv; rn[e * 3 + 2] = rz * inv;
  alignas(16) __hip_bfloat16 t8[8];
  t8[0] = __float2bfloat16(d);
  t8[1] = __float2bfloat16(a);
  t8[2] = __float2bfloat16(sqrtf(sx * sx + sy * sy + sz * sz));
  t8[3] = __float2bfloat16(sqrtf(tx * tx + ty * ty + tz * tz));
  t8[4] = t8[5] = t8[6] = t8[7] = __float2bfloat16(0.0f);
  *(uint4*)(tail + (size_t)e * 8) = *(const uint4*)t8;
}

__global__ void cvt_e_k(const float* __restrict__ e, __hip_bfloat16* __restrict__ ebf) {
  const int i = blockIdx.x * blockDim.x + threadIdx.x;   // one 8-elem chunk each
  const float* p = e + (size_t)i * 8;
  alignas(16) __hip_bfloat16 t8[8];
#pragma unroll
  for (int j = 0; j < 8; j++) t8[j] = __float2bfloat16(p[j]);
  *(uint4*)(ebf + (size_t)i * 8) = *(const uint4*)t8;
}

__global__ void count_k(const int* __restrict__ tgt, int* __restrict__ rawcnt) {
  const int e = blockIdx.x * blockDim.x + threadIdx.x;
  if (e < NE) atomicAdd(&rawcnt[tgt[e]], 1);
}

// ---- exclusive scan of rawcnt[NN] -> off[NN+1]; single block of 256 threads, 32 elems each.
__global__ __launch_bounds__(256) void scan_k(const int* __restrict__ rawcnt, int* __restrict__ off) {
  __shared__ int ts[256];
  const int tid = threadIdx.x;
  const int base = tid * 32;
  int local[32];
  int s = 0;
#pragma unroll
  for (int i = 0; i < 32; i++) { local[i] = s; s += rawcnt[base + i]; }
  ts[tid] = s;
  __syncthreads();
  if (tid == 0) {
    int acc = 0;
    for (int i = 0; i < 256; i++) { int t = ts[i]; ts[i] = acc; acc += t; }
    off[NN] = acc;
  }
  __syncthreads();
  const int pre = ts[tid];
#pragma unroll
  for (int i = 0; i < 32; i++) off[base + i] = pre + local[i];
}

__global__ void scatter_k(const int* __restrict__ tgt, const int* __restrict__ off,
                          int* __restrict__ cursor, int* __restrict__ eperm) {
  const int e = blockIdx.x * blockDim.x + threadIdx.x;
  if (e < NE) {
    const int t = tgt[e];
    const int r = atomicAdd(&cursor[t], 1);
    eperm[off[t] + r] = e;
  }
}

// ---- CSR aggregation: one block (256 thr) per node. Zero atomics.
__global__ __launch_bounds__(256) void agg_k(const int* __restrict__ off, const int* __restrict__ eperm,
                                             const int* __restrict__ srcp,
                                             const __hip_bfloat16* __restrict__ h,
                                             const __hip_bfloat16* __restrict__ wv,
                                             const float* __restrict__ mp,
                                             const float* __restrict__ rn,
                                             const float* __restrict__ vprev,
                                             float* __restrict__ Hagg,
                                             float* __restrict__ v_o, float* __restrict__ p_o,
                                             int hasv) {
  const int n = blockIdx.x;
  const int c = threadIdx.x;
  const int e0 = off[n], e1 = off[n + 1];
  const int c3 = c >> 6, ln = c & 63;
  float hs = 0.f, vs = 0.f, ps = 0.f;
  for (int j = e0; j < e1; j++) {
    const int e = eperm[j];
    hs += __bfloat162float(h[(size_t)e * HIDc + c]);
    if (c < 192) {
      float mv = __bfloat162float(wv[(size_t)e * 128 + 64 + ln]) * rn[(size_t)e * 3 + c3];
      if (hasv) mv += __bfloat162float(wv[(size_t)e * 128 + ln]) * vprev[(size_t)srcp[e] * 192 + c];
      vs += mv;
    } else if (c < 195) {
      ps += mp[(size_t)e * 3 + (c - 192)];
    }
  }
  Hagg[(size_t)n * HIDc + c] = hs;
  const float inv = 1.0f / fmaxf((float)(e1 - e0), 1.0f);
  if (c < 192)      v_o[(size_t)n * 192 + c] += vs * inv;
  else if (c < 195) p_o[n * 3 + (c - 192)]   += ps * inv;
}

__global__ void zero_k(float* __restrict__ ptr, int n) {
  const int i = blockIdx.x * blockDim.x + threadIdx.x;
  if (i < n) ptr[i] = 0.f;
}

// ---- weight prep: transpose to [l][n][k] bf16 (k contiguous)
__global__ void prep_w1t_k(const float* __restrict__ W1, __hip_bfloat16* __restrict__ W1T) {
  const int idx = blockIdx.x * blockDim.x + threadIdx.x;
  if (idx >= NL * HIDc * KP1) return;
  const int k = idx % KP1, n = (idx / KP1) % HIDc, l = idx / (KP1 * HIDc);
  const float v = (k < DINc) ? W1[((size_t)l * DINc + k) * HIDc + n] : 0.f;
  W1T[idx] = __float2bfloat16(v);
}

__global__ void prep_w2t_k(const float* __restrict__ W2, __hip_bfloat16* __restrict__ W2sT,
                           __hip_bfloat16* __restrict__ W2aT, __hip_bfloat16* __restrict__ w384) {
  const int idx = blockIdx.x * blockDim.x + threadIdx.x;
  if (idx >= NL * HIDc * HIDc) return;
  const int k = idx % HIDc, n = (idx / HIDc) % HIDc, l = idx / (HIDc * HIDc);
  const float* W2l = W2 + (size_t)l * HIDc * DOUTc;
  const int cs = (n < 128) ? (256 + n) : (257 + n);  // wv1|wv2 then e_new (skip col 384)
  W2sT[idx] = __float2bfloat16(W2l[(size_t)k * DOUTc + cs]);
  W2aT[idx] = __float2bfloat16(W2l[(size_t)k * DOUTc + n]);
  if (n == 0) w384[l * HIDc + k] = __float2bfloat16(W2l[(size_t)k * DOUTc + 384]);
}

__global__ void prep_ut_k(const float* __restrict__ U1, const float* __restrict__ U2,
                          __hip_bfloat16* __restrict__ U1T, __hip_bfloat16* __restrict__ U2T) {
  const int idx = blockIdx.x * blockDim.x + threadIdx.x;
  if (idx >= NL * HIDc * HIDc) return;
  const int k = idx % HIDc, n = (idx / HIDc) % HIDc, l = idx / (HIDc * HIDc);
  U1T[idx] = __float2bfloat16(U1[((size_t)l * HIDc + k) * HIDc + n]);
  U2T[idx] = __float2bfloat16(U2[((size_t)l * HIDc + k) * HIDc + n]);
}

}  // namespace

extern "C" void kernel_launch(void* const* d_in, const int* in_sizes, int n_in,
                              void* d_out, int out_size, void* d_ws, size_t ws_size,
                              hipStream_t stream) {
  (void)in_sizes; (void)n_in; (void)out_size; (void)ws_size;
  const float* s_in = (const float*)d_in[0];
  const float* v_in = (const float*)d_in[1];
  const float* p_in = (const float*)d_in[2];
  const float* e_in = (const float*)d_in[3];
  const int*   ei   = (const int*)d_in[4];
  const float* ln_g = (const float*)d_in[5];
  const float* ln_b = (const float*)d_in[6];
  const float* W1   = (const float*)d_in[7];
  const float* b1   = (const float*)d_in[8];
  const float* W2   = (const float*)d_in[9];
  const float* b2   = (const float*)d_in[10];
  const float* U1   = (const float*)d_in[11];
  const float* bU1  = (const float*)d_in[12];
  const float* U2   = (const float*)d_in[13];
  const float* bU2  = (const float*)d_in[14];

  float* s_o = (float*)d_out;
  float* v_o = s_o + (size_t)NN * SD;
  float* e_o = v_o + (size_t)NN * 192;
  float* p_o = e_o + (size_t)NE * ED;

  const int* srcp = ei;
  const int* tgtp = ei + NE;

  char* wp = (char*)d_ws;
  auto alloc = [&](size_t bytes) -> char* {
    char* r = wp; wp += (bytes + 255) & ~(size_t)255; return r;
  };
  __hip_bfloat16* s_ln = (__hip_bfloat16*)alloc((size_t)NN * SD * 2);
  __hip_bfloat16* hbuf = (__hip_bfloat16*)alloc((size_t)NE * HIDc * 2);
  __hip_bfloat16* ebf  = (__hip_bfloat16*)alloc((size_t)NE * ED * 2);
  __hip_bfloat16* tbuf = (__hip_bfloat16*)alloc((size_t)NN * HIDc * 2);
  __hip_bfloat16* wvbuf= (__hip_bfloat16*)alloc((size_t)NE * 128 * 2);
  __hip_bfloat16* tailb= (__hip_bfloat16*)alloc((size_t)NE * 8 * 2);
  float* rnbuf = (float*)alloc((size_t)NE * 3 * 4);
  float* Hagg  = (float*)alloc((size_t)NN * SD * 4);
  float* vprev = (float*)alloc((size_t)NN * 192 * 4);
  float* mpbuf = (float*)alloc((size_t)NE * 3 * 4);
  int*   rawcnt= (int*)alloc((size_t)NN * 4);
  int*   offb  = (int*)alloc((size_t)(NN + 1) * 4);
  int*   cursor= (int*)alloc((size_t)NN * 4);
  int*   eperm = (int*)alloc((size_t)NE * 4);
  __hip_bfloat16* W1T  = (__hip_bfloat16*)alloc((size_t)NL * HIDc * KP1 * 2);
  __hip_bfloat16* W2sT = (__hip_bfloat16*)alloc((size_t)NL * HIDc * HIDc * 2);
  __hip_bfloat16* W2aT = (__hip_bfloat16*)alloc((size_t)NL * HIDc * HIDc * 2);
  __hip_bfloat16* U1T  = (__hip_bfloat16*)alloc((size_t)NL * HIDc * HIDc * 2);
  __hip_bfloat16* U2T  = (__hip_bfloat16*)alloc((size_t)NL * HIDc * HIDc * 2);
  __hip_bfloat16* w384 = (__hip_bfloat16*)alloc((size_t)NL * HIDc * 2);

  hipMemcpyAsync(s_o, s_in, (size_t)NN * SD * 4, hipMemcpyDeviceToDevice, stream);
  hipMemcpyAsync(v_o, v_in, (size_t)NN * 192 * 4, hipMemcpyDeviceToDevice, stream);
  hipMemcpyAsync(p_o, p_in, (size_t)NN * 3 * 4, hipMemcpyDeviceToDevice, stream);

  prep_w1t_k<<<(NL * HIDc * KP1 + 255) / 256, 256, 0, stream>>>(W1, W1T);
  prep_w2t_k<<<(NL * HIDc * HIDc + 255) / 256, 256, 0, stream>>>(W2, W2sT, W2aT, w384);
  prep_ut_k<<<(NL * HIDc * HIDc + 255) / 256, 256, 0, stream>>>(U1, U2, U1T, U2T);
  cvt_e_k<<<NE * ED / 8 / 256, 256, 0, stream>>>(e_in, ebf);

  // ---- CSR build (once; edge_index layer-invariant)
  zero_k<<<(NN + 255) / 256, 256, 0, stream>>>((float*)rawcnt, NN);
  zero_k<<<(NN + 255) / 256, 256, 0, stream>>>((float*)cursor, NN);
  count_k<<<NE / 256, 256, 0, stream>>>(tgtp, rawcnt);
  scan_k<<<1, 256, 0, stream>>>(rawcnt, offb);
  scatter_k<<<NE / 256, 256, 0, stream>>>(tgtp, offb, cursor, eperm);

  for (int l = 0; l < NL; l++) {
    ln_k<<<NN / 4, 256, 0, stream>>>(s_o, ln_g + l * SD, ln_b + l * SD, s_ln);
    edge_attr_k<<<NE / 256, 256, 0, stream>>>(p_o, srcp, tgtp, rnbuf, tailb);

    GemmArgs g1{};
    g1.Wt = W1T + (size_t)l * HIDc * KP1; g1.bias = b1 + l * HIDc;
    g1.src = srcp; g1.tgt = tgtp; g1.s_ln = s_ln; g1.e_bf = ebf;
    g1.tail = tailb; g1.bf_out = hbuf;
    gemm_k<MODE_H, SRC_FEAT, KP1><<<NE / 128, 256, 0, stream>>>(g1);

    GemmArgs g2{};
    g2.Wt = W2sT + (size_t)l * HIDc * HIDc; g2.bias = b2 + l * DOUTc;
    g2.Abf = hbuf; g2.wv_out = wvbuf; g2.e_bf_out = ebf; g2.e_f32_out = e_o;
    g2.w384 = w384 + l * HIDc; g2.rn = rnbuf; g2.mp = mpbuf;
    g2.write_e_f32 = (l == NL - 1) ? 1 : 0;
    gemm_k<MODE_OUT2, SRC_BF16, HIDc><<<NE / 128, 256, 0, stream>>>(g2);

    // pre-update v snapshot (messages read v[src] from BEFORE this layer's update)
    hipMemcpyAsync(vprev, v_o, (size_t)NN * 192 * 4, hipMemcpyDeviceToDevice, stream);

    agg_k<<<NN, 256, 0, stream>>>(offb, eperm, srcp, hbuf, wvbuf, mpbuf, rnbuf, vprev,
                                  Hagg, v_o, p_o, (l > 0) ? 1 : 0);

    GemmArgs g3{};
    g3.Wt = W2aT + (size_t)l * HIDc * HIDc; g3.bias = b2 + l * DOUTc;
    g3.Af32 = Hagg; g3.s_out = s_o; g3.rawcnt = rawcnt;
    gemm_k<MODE_SADD, SRC_F32, HIDc><<<NN / 128, 256, 0, stream>>>(g3);

    if (l < NL - 1) {
      GemmArgs g4{};
      g4.Wt = U1T + (size_t)l * HIDc * HIDc; g4.bias = bU1 + l * HIDc;
      g4.Af32 = s_o; g4.bf_out = tbuf;
      gemm_k<MODE_H, SRC_F32, HIDc><<<NN / 128, 256, 0, stream>>>(g4);

      GemmArgs g5{};
      g5.Wt = U2T + (size_t)l * HIDc * HIDc; g5.bias = bU2 + l * HIDc;
      g5.Abf = tbuf; g5.s_out = s_o;
      gemm_k<MODE_SADD2, SRC_BF16, HIDc><<<NN / 128, 256, 0, stream>>>(g5);
    }
  }
}

// Round 5
// 1710.010 us; speedup vs baseline: 2.1557x; 2.1557x over previous
//
#include <hip/hip_runtime.h>
#include <hip/hip_bf16.h>

namespace {

constexpr int NN   = 8192;    // nodes
constexpr int NE   = 131072;  // edges
constexpr int SD   = 256;     // SDIM
constexpr int ED   = 128;     // EDIM
constexpr int NL   = 5;       // layers
constexpr int DINc = 644;     // 2*SD + ED + 4
constexpr int KP1  = 672;     // DIN padded to mult of 32 (21 k-steps)
constexpr int T1   = 21;      // KP1/32
constexpr int T2   = 8;       // 256/32
constexpr int DOUTc= 513;
constexpr int HIDc = 256;

typedef __bf16 bf16x8 __attribute__((ext_vector_type(8)));
typedef float  f32x4  __attribute__((ext_vector_type(4)));

__device__ __forceinline__ float siluf(float x) { return x / (1.0f + __expf(-x)); }

// async global->LDS, 16B/lane. LDS dest is wave-uniform base (+lane*16 in HW);
// global src is per-lane.
__device__ __forceinline__ void gl_lds16(const void* gsrc, void* lds_uniform_base) {
  __builtin_amdgcn_global_load_lds(
      (const __attribute__((address_space(1))) unsigned int*)gsrc,
      (__attribute__((address_space(3))) unsigned int*)lds_uniform_base, 16, 0, 0);
}

// bank-group swizzle: XOR set {0,5,2,7} -> write AND read phases are 8-permutations.
__device__ __host__ __forceinline__ int swz(int kc) { return (kc * 5) & 7; }
__device__ __forceinline__ int apos(int kc, int row) { return kc * 64  + (row ^ swz(kc)); }
__device__ __forceinline__ int bpos(int kc, int n)   { return kc * 256 + (n   ^ swz(kc)); }

enum { MODE_H = 0, MODE_OUT2 = 1, MODE_SADD = 2, MODE_SADD2 = 3 };
enum { SRC_FEAT = 0, SRC_BF16 = 1, SRC_F32 = 2 };

struct GemmArgs {
  const __hip_bfloat16* Wt;     // swizzled B stream: [T][1024 chunks][8 bf16]
  const float* bias;            // f32 bias (b1L / b2L / bU1L / bU2L)
  const __hip_bfloat16* Abf;    // SRC_BF16 source, [M][K]
  const float* Af32;            // SRC_F32 source, [M][K]
  const int* src; const int* tgt;
  const __hip_bfloat16* s_ln;   // [NN][256]
  const __hip_bfloat16* e_bf;   // [NE][128]
  const __hip_bfloat16* tail;   // [NE][8] = {d,a,pn_s,pn_t,0,0,0,0}
  const __hip_bfloat16* w384;   // [256] W2[:,384] for fused wp
  const float* rn;              // [NE][3]
  float* mp;                    // [NE][3] out (fused wp)
  __hip_bfloat16* bf_out;       // h or t output
  __hip_bfloat16* wv_out;       // [NE][128] bf16
  __hip_bfloat16* e_bf_out;     // [NE][128]
  float* e_f32_out;             // d_out e region
  float* s_out;                 // d_out s region (RMW)
  const int* rawcnt;
  int write_e_f32;
};

__device__ __forceinline__ uint4 cvt8f(const float* p) {
  alignas(16) __hip_bfloat16 t8[8];
#pragma unroll
  for (int i = 0; i < 8; i++) t8[i] = __float2bfloat16(p[i]);
  return *(const uint4*)t8;
}

__device__ __forceinline__ float dot8(const uint4& a, const __hip_bfloat16* w) {
  const __hip_bfloat16* ap = (const __hip_bfloat16*)&a;
  float s = 0.f;
#pragma unroll
  for (int j = 0; j < 8; j++) s += __bfloat162float(ap[j]) * __bfloat162float(w[j]);
  return s;
}

// BM=64, BN=256, BK=32, 4 waves, acc[4][4] (low VGPR -> occupancy).
// B: global_load_lds (dbuf, pre-swizzled DRAM stream, issued under MFMA).
// A: reg-staged 1 chunk/thread -> swizzled ds_write (conflict-free both phases).
template<int MODE, int SRC, int KTOT>
__global__ __launch_bounds__(256) void gemm_k(GemmArgs g) {
  constexpr int T = KTOT / 32;
  __shared__ alignas(16) unsigned short Ash[4 * 64 * 8];        // 4 KB
  __shared__ alignas(16) unsigned short Bsh[2][4 * 256 * 8];    // 32 KB
  const int tid = threadIdx.x, lane = tid & 63, wave = tid >> 6;
  const int l16 = lane & 15, lhi = lane >> 4;
  const int row0 = blockIdx.x * 64;
  const int ar = tid >> 2, aq = tid & 3;   // A: row ar, k-chunk aq
  const int arow = row0 + ar;
  f32x4 acc[4][4] = {};
  float pwp = 0.f;
  int sn = 0, tn = 0;
  if constexpr (SRC == SRC_FEAT) { sn = g.src[arow]; tn = g.tgt[arow]; }

  auto loadA = [&](int t, uint4& o) {
    const int kq = t * 32 + aq * 8;
    if constexpr (SRC == SRC_FEAT) {
      if (kq >= 640) {
        o.x = o.y = o.z = o.w = 0;
        if (aq == 0) o = *(const uint4*)(g.tail + (size_t)arow * 8);
      } else {
        const __hip_bfloat16* p;
        if (kq < 256)      p = g.s_ln + (size_t)sn * SD + kq;
        else if (kq < 512) p = g.s_ln + (size_t)tn * SD + (kq - 256);
        else               p = g.e_bf + (size_t)arow * ED + (kq - 512);
        o = *(const uint4*)p;
      }
    } else if constexpr (SRC == SRC_BF16) {
      o = *(const uint4*)(g.Abf + (size_t)arow * KTOT + kq);
    } else {
      o = cvt8f(g.Af32 + (size_t)arow * KTOT + kq);
    }
  };
  auto issueB = [&](int t, int buf) {
    const __hip_bfloat16* src = g.Wt + (size_t)t * 1024 * 8;
    unsigned short* dst = &Bsh[buf][0];
#pragma unroll
    for (int i = 0; i < 4; i++)
      gl_lds16(src + (size_t)(i * 256 + wave * 64 + lane) * 8, dst + (i * 256 + wave * 64) * 8);
  };

  uint4 a;
  loadA(0, a);
  issueB(0, 0);
  int cur = 0;

  for (int t = 0; t < T; ++t) {
    *(uint4*)&Ash[apos(aq, ar) * 8] = a;
    if constexpr (MODE == MODE_OUT2) pwp += dot8(a, g.w384 + t * 32 + aq * 8);
    __syncthreads();   // Ash visible; B[t] (issued last iter) landed
    if (t + 1 < T) { issueB(t + 1, cur ^ 1); loadA(t + 1, a); }  // flight overlaps MFMA
    bf16x8 bfr[4];
#pragma unroll
    for (int fc = 0; fc < 4; fc++)
      bfr[fc] = *(const bf16x8*)&Bsh[cur][bpos(lhi, wave * 64 + fc * 16 + l16) * 8];
#pragma unroll
    for (int fr = 0; fr < 4; fr++) {
      const bf16x8 afr = *(const bf16x8*)&Ash[apos(lhi, fr * 16 + l16) * 8];
#pragma unroll
      for (int fc = 0; fc < 4; fc++)
        acc[fr][fc] = __builtin_amdgcn_mfma_f32_16x16x32_bf16(afr, bfr[fc], acc[fr][fc], 0, 0, 0);
    }
    __syncthreads();   // frees Ash/Bsh[cur]; drains prefetches
    cur ^= 1;
  }

  if constexpr (MODE == MODE_OUT2) {
    // quad (same row, aq 0..3, same wave) reduce -> full dot
    pwp += __shfl_xor(pwp, 1);
    pwp += __shfl_xor(pwp, 2);
    if (aq == 0) {
      const float wpt = tanhf(pwp + g.bias[384]);
#pragma unroll
      for (int c = 0; c < 3; c++)
        g.mp[(size_t)arow * 3 + c] = wpt * g.rn[(size_t)arow * 3 + c];
    }
  }

  // ---- epilogue: D[row = 4*(lane>>4)+r][col = lane&15] per 16x16 tile
#pragma unroll
  for (int fr = 0; fr < 4; fr++) {
#pragma unroll
    for (int fc = 0; fc < 4; fc++) {
      const int n = wave * 64 + fc * 16 + l16;
#pragma unroll
      for (int r = 0; r < 4; r++) {
        const int row = row0 + fr * 16 + lhi * 4 + r;
        const float valf = acc[fr][fc][r];
        if constexpr (MODE == MODE_H) {
          g.bf_out[(size_t)row * HIDc + n] = __float2bfloat16(siluf(valf + g.bias[n]));
        } else if constexpr (MODE == MODE_OUT2) {
          if (n < 128) {
            g.wv_out[(size_t)row * 128 + n] = __float2bfloat16(valf + g.bias[256 + n]);
          } else {
            const float sv = siluf(valf + g.bias[257 + n]);   // e_new cols = W2 cols 385..512
            g.e_bf_out[(size_t)row * ED + (n - 128)] = __float2bfloat16(sv);
            if (g.write_e_f32) g.e_f32_out[(size_t)row * ED + (n - 128)] = sv;
          }
        } else if constexpr (MODE == MODE_SADD) {
          const float rc = (float)g.rawcnt[row];
          g.s_out[(size_t)row * SD + n] += valf + rc * g.bias[n];
        } else {  // MODE_SADD2
          g.s_out[(size_t)row * SD + n] += valf + g.bias[n];
        }
      }
    }
  }
}

// ---- LayerNorm. 4 nodes/block, wave per node.
__global__ __launch_bounds__(256) void ln_k(const float* __restrict__ s,
                                            const float* __restrict__ gl, const float* __restrict__ bl,
                                            __hip_bfloat16* __restrict__ s_ln) {
  const int wave = threadIdx.x >> 6, lane = threadIdx.x & 63;
  const int node = blockIdx.x * 4 + wave;
  const float* srow = s + (size_t)node * SD;
  float x[4], sum = 0.f, sq = 0.f;
#pragma unroll
  for (int i = 0; i < 4; i++) { x[i] = srow[lane * 4 + i]; sum += x[i]; sq += x[i] * x[i]; }
#pragma unroll
  for (int off = 1; off < 64; off <<= 1) { sum += __shfl_xor(sum, off); sq += __shfl_xor(sq, off); }
  const float mu = sum * (1.0f / SD);
  const float var = sq * (1.0f / SD) - mu * mu;
  const float rstd = rsqrtf(var + 1e-5f);
#pragma unroll
  for (int i = 0; i < 4; i++) {
    const int c = lane * 4 + i;
    s_ln[(size_t)node * SD + c] = __float2bfloat16(gl[c] * (x[i] - mu) * rstd + bl[c]);
  }
}

// ---- per-edge attrs: rn + bf16 tail block {d,a,pn_src,pn_tgt,0,0,0,0}
__global__ void edge_attr_k(const float* __restrict__ p, const int* __restrict__ src, const int* __restrict__ tgt,
                            float* __restrict__ rn, __hip_bfloat16* __restrict__ tail) {
  const int e = blockIdx.x * blockDim.x + threadIdx.x;
  if (e >= NE) return;
  const int s_ = src[e], t_ = tgt[e];
  const float sx = p[s_ * 3], sy = p[s_ * 3 + 1], sz = p[s_ * 3 + 2];
  const float tx = p[t_ * 3], ty = p[t_ * 3 + 1], tz = p[t_ * 3 + 2];
  const float rx = tx - sx, ry = ty - sy, rz = tz - sz;
  const float a = tx * sx + ty * sy + tz * sz;
  const float rr = rx * rx + ry * ry + rz * rz;
  const float d = sqrtf(fmaxf(rr, 1e-6f));
  const float inv = 1.0f / (1.0f + d);
  rn[e * 3] = rx * inv; rn[e * 3 + 1] = ry * inv; rn[e * 3 + 2] = rz * inv;
  alignas(16) __hip_bfloat16 t8[8];
  t8[0] = __float2bfloat16(d);
  t8[1] = __float2bfloat16(a);
  t8[2] = __float2bfloat16(sqrtf(sx * sx + sy * sy + sz * sz));
  t8[3] = __float2bfloat16(sqrtf(tx * tx + ty * ty + tz * tz));
  t8[4] = t8[5] = t8[6] = t8[7] = __float2bfloat16(0.0f);
  *(uint4*)(tail + (size_t)e * 8) = *(const uint4*)t8;
}

__global__ void cvt_e_k(const float* __restrict__ e, __hip_bfloat16* __restrict__ ebf) {
  const int i = blockIdx.x * blockDim.x + threadIdx.x;   // one 8-elem chunk each
  const float* p = e + (size_t)i * 8;
  alignas(16) __hip_bfloat16 t8[8];
#pragma unroll
  for (int j = 0; j < 8; j++) t8[j] = __float2bfloat16(p[j]);
  *(uint4*)(ebf + (size_t)i * 8) = *(const uint4*)t8;
}

__global__ void count_k(const int* __restrict__ tgt, int* __restrict__ rawcnt) {
  const int e = blockIdx.x * blockDim.x + threadIdx.x;
  if (e < NE) atomicAdd(&rawcnt[tgt[e]], 1);
}

// ---- exclusive scan of rawcnt[NN] -> off[NN+1]; single block of 256 threads, 32 elems each.
__global__ __launch_bounds__(256) void scan_k(const int* __restrict__ rawcnt, int* __restrict__ off) {
  __shared__ int ts[256];
  const int tid = threadIdx.x;
  const int base = tid * 32;
  int local[32];
  int s = 0;
#pragma unroll
  for (int i = 0; i < 32; i++) { local[i] = s; s += rawcnt[base + i]; }
  ts[tid] = s;
  __syncthreads();
  if (tid == 0) {
    int acc = 0;
    for (int i = 0; i < 256; i++) { int t = ts[i]; ts[i] = acc; acc += t; }
    off[NN] = acc;
  }
  __syncthreads();
  const int pre = ts[tid];
#pragma unroll
  for (int i = 0; i < 32; i++) off[base + i] = pre + local[i];
}

__global__ void scatter_k(const int* __restrict__ tgt, const int* __restrict__ off,
                          int* __restrict__ cursor, int* __restrict__ eperm) {
  const int e = blockIdx.x * blockDim.x + threadIdx.x;
  if (e < NE) {
    const int t = tgt[e];
    const int r = atomicAdd(&cursor[t], 1);
    eperm[off[t] + r] = e;
  }
}

// ---- CSR aggregation: one block (256 thr) per node. Zero atomics.
__global__ __launch_bounds__(256) void agg_k(const int* __restrict__ off, const int* __restrict__ eperm,
                                             const int* __restrict__ srcp,
                                             const __hip_bfloat16* __restrict__ h,
                                             const __hip_bfloat16* __restrict__ wv,
                                             const float* __restrict__ mp,
                                             const float* __restrict__ rn,
                                             const float* __restrict__ vprev,
                                             float* __restrict__ Hagg,
                                             float* __restrict__ v_o, float* __restrict__ p_o,
                                             int hasv) {
  const int n = blockIdx.x;
  const int c = threadIdx.x;
  const int e0 = off[n], e1 = off[n + 1];
  const int c3 = c >> 6, ln = c & 63;
  float hs = 0.f, vs = 0.f, ps = 0.f;
  for (int j = e0; j < e1; j++) {
    const int e = eperm[j];
    hs += __bfloat162float(h[(size_t)e * HIDc + c]);
    if (c < 192) {
      float mv = __bfloat162float(wv[(size_t)e * 128 + 64 + ln]) * rn[(size_t)e * 3 + c3];
      if (hasv) mv += __bfloat162float(wv[(size_t)e * 128 + ln]) * vprev[(size_t)srcp[e] * 192 + c];
      vs += mv;
    } else if (c < 195) {
      ps += mp[(size_t)e * 3 + (c - 192)];
    }
  }
  Hagg[(size_t)n * HIDc + c] = hs;
  const float inv = 1.0f / fmaxf((float)(e1 - e0), 1.0f);
  if (c < 192)      v_o[(size_t)n * 192 + c] += vs * inv;
  else if (c < 195) p_o[n * 3 + (c - 192)]   += ps * inv;
}

__global__ void zero_k(float* __restrict__ ptr, int n) {
  const int i = blockIdx.x * blockDim.x + threadIdx.x;
  if (i < n) ptr[i] = 0.f;
}

// ---- weight prep -> swizzled B streams: chunk p of k-step t holds
// W^T[n][t*32 + kc*8 .. +8) where kc = p>>8, n = (p&255) ^ swz(kc).
__global__ void prep_w1s_k(const float* __restrict__ W1, __hip_bfloat16* __restrict__ W1S) {
  const int idx = blockIdx.x * blockDim.x + threadIdx.x;
  if (idx >= NL * T1 * 1024) return;
  const int p = idx & 1023, tl = idx >> 10;
  const int t = tl % T1, l = tl / T1;
  const int kc = p >> 8, n = (p & 255) ^ swz(kc);
  alignas(16) __hip_bfloat16 t8[8];
#pragma unroll
  for (int j = 0; j < 8; j++) {
    const int k = t * 32 + kc * 8 + j;
    t8[j] = __float2bfloat16(k < DINc ? W1[((size_t)l * DINc + k) * HIDc + n] : 0.f);
  }
  *(uint4*)(W1S + (size_t)idx * 8) = *(const uint4*)t8;
}

__global__ void prep_w2s_k(const float* __restrict__ W2, __hip_bfloat16* __restrict__ W2sS,
                           __hip_bfloat16* __restrict__ W2aS) {
  const int idx = blockIdx.x * blockDim.x + threadIdx.x;
  if (idx >= NL * T2 * 1024) return;
  const int p = idx & 1023, t = (idx >> 10) & 7, l = idx >> 13;
  const int kc = p >> 8, n = (p & 255) ^ swz(kc);
  const float* W2l = W2 + (size_t)l * HIDc * DOUTc;
  const int cs = (n < 128) ? (256 + n) : (257 + n);  // wv1|wv2 then e_new (skip col 384)
  alignas(16) __hip_bfloat16 s8[8], a8[8];
#pragma unroll
  for (int j = 0; j < 8; j++) {
    const int k = t * 32 + kc * 8 + j;
    s8[j] = __float2bfloat16(W2l[(size_t)k * DOUTc + cs]);
    a8[j] = __float2bfloat16(W2l[(size_t)k * DOUTc + n]);
  }
  *(uint4*)(W2sS + (size_t)idx * 8) = *(const uint4*)s8;
  *(uint4*)(W2aS + (size_t)idx * 8) = *(const uint4*)a8;
}

__global__ void prep_uts_k(const float* __restrict__ U1, const float* __restrict__ U2,
                           __hip_bfloat16* __restrict__ U1S, __hip_bfloat16* __restrict__ U2S) {
  const int idx = blockIdx.x * blockDim.x + threadIdx.x;
  if (idx >= NL * T2 * 1024) return;
  const int p = idx & 1023, t = (idx >> 10) & 7, l = idx >> 13;
  const int kc = p >> 8, n = (p & 255) ^ swz(kc);
  alignas(16) __hip_bfloat16 u1[8], u2[8];
#pragma unroll
  for (int j = 0; j < 8; j++) {
    const int k = t * 32 + kc * 8 + j;
    u1[j] = __float2bfloat16(U1[((size_t)l * HIDc + k) * HIDc + n]);
    u2[j] = __float2bfloat16(U2[((size_t)l * HIDc + k) * HIDc + n]);
  }
  *(uint4*)(U1S + (size_t)idx * 8) = *(const uint4*)u1;
  *(uint4*)(U2S + (size_t)idx * 8) = *(const uint4*)u2;
}

__global__ void prep_w384_k(const float* __restrict__ W2, __hip_bfloat16* __restrict__ w384) {
  const int idx = blockIdx.x * blockDim.x + threadIdx.x;
  if (idx >= NL * HIDc) return;
  const int k = idx & 255, l = idx >> 8;
  w384[idx] = __float2bfloat16(W2[((size_t)l * HIDc + k) * DOUTc + 384]);
}

}  // namespace

extern "C" void kernel_launch(void* const* d_in, const int* in_sizes, int n_in,
                              void* d_out, int out_size, void* d_ws, size_t ws_size,
                              hipStream_t stream) {
  (void)in_sizes; (void)n_in; (void)out_size; (void)ws_size;
  const float* s_in = (const float*)d_in[0];
  const float* v_in = (const float*)d_in[1];
  const float* p_in = (const float*)d_in[2];
  const float* e_in = (const float*)d_in[3];
  const int*   ei   = (const int*)d_in[4];
  const float* ln_g = (const float*)d_in[5];
  const float* ln_b = (const float*)d_in[6];
  const float* W1   = (const float*)d_in[7];
  const float* b1   = (const float*)d_in[8];
  const float* W2   = (const float*)d_in[9];
  const float* b2   = (const float*)d_in[10];
  const float* U1   = (const float*)d_in[11];
  const float* bU1  = (const float*)d_in[12];
  const float* U2   = (const float*)d_in[13];
  const float* bU2  = (const float*)d_in[14];

  float* s_o = (float*)d_out;
  float* v_o = s_o + (size_t)NN * SD;
  float* e_o = v_o + (size_t)NN * 192;
  float* p_o = e_o + (size_t)NE * ED;

  const int* srcp = ei;
  const int* tgtp = ei + NE;

  char* wp = (char*)d_ws;
  auto alloc = [&](size_t bytes) -> char* {
    char* r = wp; wp += (bytes + 255) & ~(size_t)255; return r;
  };
  __hip_bfloat16* s_ln = (__hip_bfloat16*)alloc((size_t)NN * SD * 2);
  __hip_bfloat16* hbuf = (__hip_bfloat16*)alloc((size_t)NE * HIDc * 2);
  __hip_bfloat16* ebf  = (__hip_bfloat16*)alloc((size_t)NE * ED * 2);
  __hip_bfloat16* tbuf = (__hip_bfloat16*)alloc((size_t)NN * HIDc * 2);
  __hip_bfloat16* wvbuf= (__hip_bfloat16*)alloc((size_t)NE * 128 * 2);
  __hip_bfloat16* tailb= (__hip_bfloat16*)alloc((size_t)NE * 8 * 2);
  float* rnbuf = (float*)alloc((size_t)NE * 3 * 4);
  float* Hagg  = (float*)alloc((size_t)NN * SD * 4);
  float* vprev = (float*)alloc((size_t)NN * 192 * 4);
  float* mpbuf = (float*)alloc((size_t)NE * 3 * 4);
  int*   rawcnt= (int*)alloc((size_t)NN * 4);
  int*   offb  = (int*)alloc((size_t)(NN + 1) * 4);
  int*   cursor= (int*)alloc((size_t)NN * 4);
  int*   eperm = (int*)alloc((size_t)NE * 4);
  __hip_bfloat16* W1S  = (__hip_bfloat16*)alloc((size_t)NL * T1 * 1024 * 8 * 2);
  __hip_bfloat16* W2sS = (__hip_bfloat16*)alloc((size_t)NL * T2 * 1024 * 8 * 2);
  __hip_bfloat16* W2aS = (__hip_bfloat16*)alloc((size_t)NL * T2 * 1024 * 8 * 2);
  __hip_bfloat16* U1S  = (__hip_bfloat16*)alloc((size_t)NL * T2 * 1024 * 8 * 2);
  __hip_bfloat16* U2S  = (__hip_bfloat16*)alloc((size_t)NL * T2 * 1024 * 8 * 2);
  __hip_bfloat16* w384 = (__hip_bfloat16*)alloc((size_t)NL * HIDc * 2);

  hipMemcpyAsync(s_o, s_in, (size_t)NN * SD * 4, hipMemcpyDeviceToDevice, stream);
  hipMemcpyAsync(v_o, v_in, (size_t)NN * 192 * 4, hipMemcpyDeviceToDevice, stream);
  hipMemcpyAsync(p_o, p_in, (size_t)NN * 3 * 4, hipMemcpyDeviceToDevice, stream);

  prep_w1s_k<<<(NL * T1 * 1024 + 255) / 256, 256, 0, stream>>>(W1, W1S);
  prep_w2s_k<<<(NL * T2 * 1024 + 255) / 256, 256, 0, stream>>>(W2, W2sS, W2aS);
  prep_uts_k<<<(NL * T2 * 1024 + 255) / 256, 256, 0, stream>>>(U1, U2, U1S, U2S);
  prep_w384_k<<<(NL * HIDc + 255) / 256, 256, 0, stream>>>(W2, w384);
  cvt_e_k<<<NE * ED / 8 / 256, 256, 0, stream>>>(e_in, ebf);

  // ---- CSR build (once; edge_index layer-invariant)
  zero_k<<<(NN + 255) / 256, 256, 0, stream>>>((float*)rawcnt, NN);
  zero_k<<<(NN + 255) / 256, 256, 0, stream>>>((float*)cursor, NN);
  count_k<<<NE / 256, 256, 0, stream>>>(tgtp, rawcnt);
  scan_k<<<1, 256, 0, stream>>>(rawcnt, offb);
  scatter_k<<<NE / 256, 256, 0, stream>>>(tgtp, offb, cursor, eperm);

  for (int l = 0; l < NL; l++) {
    ln_k<<<NN / 4, 256, 0, stream>>>(s_o, ln_g + l * SD, ln_b + l * SD, s_ln);
    edge_attr_k<<<NE / 256, 256, 0, stream>>>(p_o, srcp, tgtp, rnbuf, tailb);

    GemmArgs g1{};
    g1.Wt = W1S + (size_t)l * T1 * 1024 * 8; g1.bias = b1 + l * HIDc;
    g1.src = srcp; g1.tgt = tgtp; g1.s_ln = s_ln; g1.e_bf = ebf;
    g1.tail = tailb; g1.bf_out = hbuf;
    gemm_k<MODE_H, SRC_FEAT, KP1><<<NE / 64, 256, 0, stream>>>(g1);

    GemmArgs g2{};
    g2.Wt = W2sS + (size_t)l * T2 * 1024 * 8; g2.bias = b2 + l * DOUTc;
    g2.Abf = hbuf; g2.wv_out = wvbuf; g2.e_bf_out = ebf; g2.e_f32_out = e_o;
    g2.w384 = w384 + l * HIDc; g2.rn = rnbuf; g2.mp = mpbuf;
    g2.write_e_f32 = (l == NL - 1) ? 1 : 0;
    gemm_k<MODE_OUT2, SRC_BF16, HIDc><<<NE / 64, 256, 0, stream>>>(g2);

    // pre-update v snapshot (messages read v[src] from BEFORE this layer's update)
    hipMemcpyAsync(vprev, v_o, (size_t)NN * 192 * 4, hipMemcpyDeviceToDevice, stream);

    agg_k<<<NN, 256, 0, stream>>>(offb, eperm, srcp, hbuf, wvbuf, mpbuf, rnbuf, vprev,
                                  Hagg, v_o, p_o, (l > 0) ? 1 : 0);

    GemmArgs g3{};
    g3.Wt = W2aS + (size_t)l * T2 * 1024 * 8; g3.bias = b2 + l * DOUTc;
    g3.Af32 = Hagg; g3.s_out = s_o; g3.rawcnt = rawcnt;
    gemm_k<MODE_SADD, SRC_F32, HIDc><<<NN / 64, 256, 0, stream>>>(g3);

    if (l < NL - 1) {
      GemmArgs g4{};
      g4.Wt = U1S + (size_t)l * T2 * 1024 * 8; g4.bias = bU1 + l * HIDc;
      g4.Af32 = s_o; g4.bf_out = tbuf;
      gemm_k<MODE_H, SRC_F32, HIDc><<<NN / 64, 256, 0, stream>>>(g4);

      GemmArgs g5{};
      g5.Wt = U2S + (size_t)l * T2 * 1024 * 8; g5.bias = bU2 + l * HIDc;
      g5.Abf = tbuf; g5.s_out = s_o;
      gemm_k<MODE_SADD2, SRC_BF16, HIDc><<<NN / 64, 256, 0, stream>>>(g5);
    }
  }
}

// Round 6
// 1678.265 us; speedup vs baseline: 2.1965x; 1.0189x over previous
//
#include <hip/hip_runtime.h>
#include <hip/hip_bf16.h>

namespace {

constexpr int NN   = 8192;    // nodes
constexpr int NE   = 131072;  // edges
constexpr int SD   = 256;     // SDIM
constexpr int ED   = 128;     // EDIM
constexpr int NL   = 5;       // layers
constexpr int DINc = 644;     // 2*SD + ED + 4
constexpr int KE   = 160;     // edge-GEMM K: 128 e + 4 scalars + pad
constexpr int TE   = 5;       // KE/32
constexpr int T2   = 8;       // 256/32
constexpr int DOUTc= 513;
constexpr int HIDc = 256;

typedef __bf16 bf16x8 __attribute__((ext_vector_type(8)));
typedef float  f32x4  __attribute__((ext_vector_type(4)));

__device__ __forceinline__ float siluf(float x) { return x / (1.0f + __expf(-x)); }

// async global->LDS, 16B/lane. LDS dest is wave-uniform base (+lane*16 in HW).
__device__ __forceinline__ void gl_lds16(const void* gsrc, void* lds_uniform_base) {
  __builtin_amdgcn_global_load_lds(
      (const __attribute__((address_space(1))) unsigned int*)gsrc,
      (__attribute__((address_space(3))) unsigned int*)lds_uniform_base, 16, 0, 0);
}

// bank-group swizzle: XOR set {0,5,2,7} -> write AND read phases are 8-permutations.
__device__ __host__ __forceinline__ int swz(int kc) { return (kc * 5) & 7; }
__device__ __forceinline__ int apos(int kc, int row) { return kc * 64  + (row ^ swz(kc)); }
__device__ __forceinline__ int bpos(int kc, int n)   { return kc * 256 + (n   ^ swz(kc)); }

enum { MODE_H = 0, MODE_OUT2 = 1, MODE_SADD = 2, MODE_SADD2 = 3, MODE_LIN = 4, MODE_HE = 5 };
enum { SRC_EDGE = 0, SRC_BF16 = 1, SRC_F32 = 2 };

struct GemmArgs {
  const __hip_bfloat16* Wt;     // swizzled B stream: [T][1024 chunks][8 bf16]
  const float* bias;            // f32 bias
  const __hip_bfloat16* Abf;    // SRC_BF16 source, [M][K]
  const float* Af32;            // SRC_F32 source, [M][K]
  const int* src; const int* tgt;
  const __hip_bfloat16* e_bf;   // [NE][128]
  const __hip_bfloat16* tail;   // [NE][32] = {d,a,pn_s,pn_t,0,...}
  const __hip_bfloat16* p1;     // [NN][256]  P1 = s_ln@W1a + b1
  const __hip_bfloat16* p2;     // [NN][256]  P2 = s_ln@W1b
  const __hip_bfloat16* w384;   // [256] W2[:,384] for fused wp
  const float* rn;              // [NE][3]
  float* mp;                    // [NE][3] out (fused wp)
  __hip_bfloat16* bf_out;       // h / t / P output
  __hip_bfloat16* wv_out;       // [NE][128] bf16
  __hip_bfloat16* e_bf_out;     // [NE][128]
  float* e_f32_out;             // d_out e region
  float* s_out;                 // d_out s region (RMW)
  const int* rawcnt;
  int write_e_f32;
};

__device__ __forceinline__ uint4 cvt8f(const float* p) {
  alignas(16) __hip_bfloat16 t8[8];
#pragma unroll
  for (int i = 0; i < 8; i++) t8[i] = __float2bfloat16(p[i]);
  return *(const uint4*)t8;
}

__device__ __forceinline__ float dot8(const uint4& a, const __hip_bfloat16* w) {
  const __hip_bfloat16* ap = (const __hip_bfloat16*)&a;
  float s = 0.f;
#pragma unroll
  for (int j = 0; j < 8; j++) s += __bfloat162float(ap[j]) * __bfloat162float(w[j]);
  return s;
}

// BM=64, BN=256, BK=32, 4 waves, acc[4][4].
// B: global_load_lds (dbuf, pre-swizzled DRAM stream, in flight under MFMA).
// A: reg-staged -> swizzled ds_write (conflict-free both phases).
template<int MODE, int SRC, int KTOT>
__global__ __launch_bounds__(256) void gemm_k(GemmArgs g) {
  constexpr int T = KTOT / 32;
  __shared__ alignas(16) unsigned short Ash[4 * 64 * 8];        // 4 KB
  __shared__ alignas(16) unsigned short Bsh[2][4 * 256 * 8];    // 32 KB
  const int tid = threadIdx.x, lane = tid & 63, wave = tid >> 6;
  const int l16 = lane & 15, lhi = lane >> 4;
  const int row0 = blockIdx.x * 64;
  const int ar = tid >> 2, aq = tid & 3;   // A: row ar, k-chunk aq
  const int arow = row0 + ar;
  f32x4 acc[4][4] = {};
  float pwp = 0.f;
  int sn = 0, tn = 0;
  if constexpr (MODE == MODE_HE) { sn = g.src[arow]; tn = g.tgt[arow]; }

  auto loadA = [&](int t, uint4& o) {
    const int kq = t * 32 + aq * 8;
    if constexpr (SRC == SRC_EDGE) {
      if (kq < 128) o = *(const uint4*)(g.e_bf + (size_t)arow * ED + kq);
      else          o = *(const uint4*)(g.tail + (size_t)arow * 32 + (kq - 128));
    } else if constexpr (SRC == SRC_BF16) {
      o = *(const uint4*)(g.Abf + (size_t)arow * KTOT + kq);
    } else {
      o = cvt8f(g.Af32 + (size_t)arow * KTOT + kq);
    }
  };
  auto issueB = [&](int t, int buf) {
    const __hip_bfloat16* src = g.Wt + (size_t)t * 1024 * 8;
    unsigned short* dst = &Bsh[buf][0];
#pragma unroll
    for (int i = 0; i < 4; i++)
      gl_lds16(src + (size_t)(i * 256 + wave * 64 + lane) * 8, dst + (i * 256 + wave * 64) * 8);
  };

  uint4 a;
  loadA(0, a);
  issueB(0, 0);
  int cur = 0;

  for (int t = 0; t < T; ++t) {
    *(uint4*)&Ash[apos(aq, ar) * 8] = a;
    if constexpr (MODE == MODE_OUT2) pwp += dot8(a, g.w384 + t * 32 + aq * 8);
    __syncthreads();   // Ash visible; B[t] landed
    if (t + 1 < T) { issueB(t + 1, cur ^ 1); loadA(t + 1, a); }  // flight overlaps MFMA
    bf16x8 bfr[4];
#pragma unroll
    for (int fc = 0; fc < 4; fc++)
      bfr[fc] = *(const bf16x8*)&Bsh[cur][bpos(lhi, wave * 64 + fc * 16 + l16) * 8];
#pragma unroll
    for (int fr = 0; fr < 4; fr++) {
      const bf16x8 afr = *(const bf16x8*)&Ash[apos(lhi, fr * 16 + l16) * 8];
#pragma unroll
      for (int fc = 0; fc < 4; fc++)
        acc[fr][fc] = __builtin_amdgcn_mfma_f32_16x16x32_bf16(afr, bfr[fc], acc[fr][fc], 0, 0, 0);
    }
    __syncthreads();   // frees Ash/Bsh[cur]; drains prefetches
    cur ^= 1;
  }

  if constexpr (MODE == MODE_OUT2) {
    pwp += __shfl_xor(pwp, 1);
    pwp += __shfl_xor(pwp, 2);
    if (aq == 0) {
      const float wpt = tanhf(pwp + g.bias[384]);
#pragma unroll
      for (int c = 0; c < 3; c++)
        g.mp[(size_t)arow * 3 + c] = wpt * g.rn[(size_t)arow * 3 + c];
    }
  }

  if constexpr (MODE == MODE_HE) {
    // stage Psum = P1[src]+P2[tgt] into Bsh (flat 64x256 bf16 = 32KB).
    // col rotation (j+tid)&7 -> 8 distinct bank groups per 8-lane phase.
    __hip_bfloat16* Ps = (__hip_bfloat16*)&Bsh[0][0];
#pragma unroll
    for (int j = 0; j < 8; j++) {
      const int col = aq * 64 + ((j + tid) & 7) * 8;
      uint4 r1 = *(const uint4*)(g.p1 + (size_t)sn * SD + col);
      uint4 r2 = *(const uint4*)(g.p2 + (size_t)tn * SD + col);
      const __hip_bfloat16* h1 = (const __hip_bfloat16*)&r1;
      const __hip_bfloat16* h2 = (const __hip_bfloat16*)&r2;
      alignas(16) __hip_bfloat16 o8[8];
#pragma unroll
      for (int m = 0; m < 8; m++)
        o8[m] = __float2bfloat16(__bfloat162float(h1[m]) + __bfloat162float(h2[m]));
      *(uint4*)(Ps + ar * 256 + col) = *(const uint4*)o8;
    }
    __syncthreads();
  }

  // ---- epilogue: D[row = 4*(lane>>4)+r][col = lane&15] per 16x16 tile
#pragma unroll
  for (int fr = 0; fr < 4; fr++) {
#pragma unroll
    for (int fc = 0; fc < 4; fc++) {
      const int n = wave * 64 + fc * 16 + l16;
#pragma unroll
      for (int r = 0; r < 4; r++) {
        const int row = row0 + fr * 16 + lhi * 4 + r;
        const float valf = acc[fr][fc][r];
        if constexpr (MODE == MODE_H) {
          g.bf_out[(size_t)row * HIDc + n] = __float2bfloat16(siluf(valf + g.bias[n]));
        } else if constexpr (MODE == MODE_LIN) {
          g.bf_out[(size_t)row * HIDc + n] = __float2bfloat16(valf + g.bias[n]);
        } else if constexpr (MODE == MODE_HE) {
          const __hip_bfloat16* Ps = (const __hip_bfloat16*)&Bsh[0][0];
          const float ps = __bfloat162float(Ps[(fr * 16 + lhi * 4 + r) * 256 + n]);
          g.bf_out[(size_t)row * HIDc + n] = __float2bfloat16(siluf(valf + ps));
        } else if constexpr (MODE == MODE_OUT2) {
          if (n < 128) {
            g.wv_out[(size_t)row * 128 + n] = __float2bfloat16(valf + g.bias[256 + n]);
          } else {
            const float sv = siluf(valf + g.bias[257 + n]);   // e_new cols = W2 cols 385..512
            g.e_bf_out[(size_t)row * ED + (n - 128)] = __float2bfloat16(sv);
            if (g.write_e_f32) g.e_f32_out[(size_t)row * ED + (n - 128)] = sv;
          }
        } else if constexpr (MODE == MODE_SADD) {
          const float rc = (float)g.rawcnt[row];
          g.s_out[(size_t)row * SD + n] += valf + rc * g.bias[n];
        } else {  // MODE_SADD2
          g.s_out[(size_t)row * SD + n] += valf + g.bias[n];
        }
      }
    }
  }
}

// ---- LayerNorm. 4 nodes/block, wave per node.
__global__ __launch_bounds__(256) void ln_k(const float* __restrict__ s,
                                            const float* __restrict__ gl, const float* __restrict__ bl,
                                            __hip_bfloat16* __restrict__ s_ln) {
  const int wave = threadIdx.x >> 6, lane = threadIdx.x & 63;
  const int node = blockIdx.x * 4 + wave;
  const float* srow = s + (size_t)node * SD;
  float x[4], sum = 0.f, sq = 0.f;
#pragma unroll
  for (int i = 0; i < 4; i++) { x[i] = srow[lane * 4 + i]; sum += x[i]; sq += x[i] * x[i]; }
#pragma unroll
  for (int off = 1; off < 64; off <<= 1) { sum += __shfl_xor(sum, off); sq += __shfl_xor(sq, off); }
  const float mu = sum * (1.0f / SD);
  const float var = sq * (1.0f / SD) - mu * mu;
  const float rstd = rsqrtf(var + 1e-5f);
#pragma unroll
  for (int i = 0; i < 4; i++) {
    const int c = lane * 4 + i;
    s_ln[(size_t)node * SD + c] = __float2bfloat16(gl[c] * (x[i] - mu) * rstd + bl[c]);
  }
}

// ---- per-edge attrs: rn + bf16 tail block [NE][32] = {d,a,pn_src,pn_tgt,0,...}
__global__ void edge_attr_k(const float* __restrict__ p, const int* __restrict__ src, const int* __restrict__ tgt,
                            float* __restrict__ rn, __hip_bfloat16* __restrict__ tail) {
  const int e = blockIdx.x * blockDim.x + threadIdx.x;
  if (e >= NE) return;
  const int s_ = src[e], t_ = tgt[e];
  const float sx = p[s_ * 3], sy = p[s_ * 3 + 1], sz = p[s_ * 3 + 2];
  const float tx = p[t_ * 3], ty = p[t_ * 3 + 1], tz = p[t_ * 3 + 2];
  const float rx = tx - sx, ry = ty - sy, rz = tz - sz;
  const float a = tx * sx + ty * sy + tz * sz;
  const float rr = rx * rx + ry * ry + rz * rz;
  const float d = sqrtf(fmaxf(rr, 1e-6f));
  const float inv = 1.0f / (1.0f + d);
  rn[e * 3] = rx * inv; rn[e * 3 + 1] = ry * inv; rn[e * 3 + 2] = rz * inv;
  alignas(16) __hip_bfloat16 t8[8];
  t8[0] = __float2bfloat16(d);
  t8[1] = __float2bfloat16(a);
  t8[2] = __float2bfloat16(sqrtf(sx * sx + sy * sy + sz * sz));
  t8[3] = __float2bfloat16(sqrtf(tx * tx + ty * ty + tz * tz));
  t8[4] = t8[5] = t8[6] = t8[7] = __float2bfloat16(0.0f);
  __hip_bfloat16* tp = tail + (size_t)e * 32;
  uint4 z; z.x = z.y = z.z = z.w = 0;
  *(uint4*)tp = *(const uint4*)t8;
  *(uint4*)(tp + 8) = z;
  *(uint4*)(tp + 16) = z;
  *(uint4*)(tp + 24) = z;
}

__global__ void cvt_e_k(const float* __restrict__ e, __hip_bfloat16* __restrict__ ebf) {
  const int i = blockIdx.x * blockDim.x + threadIdx.x;   // one 8-elem chunk each
  const float* p = e + (size_t)i * 8;
  alignas(16) __hip_bfloat16 t8[8];
#pragma unroll
  for (int j = 0; j < 8; j++) t8[j] = __float2bfloat16(p[j]);
  *(uint4*)(ebf + (size_t)i * 8) = *(const uint4*)t8;
}

__global__ void count_k(const int* __restrict__ tgt, int* __restrict__ rawcnt) {
  const int e = blockIdx.x * blockDim.x + threadIdx.x;
  if (e < NE) atomicAdd(&rawcnt[tgt[e]], 1);
}

// ---- exclusive scan of rawcnt[NN] -> off[NN+1]; single block.
__global__ __launch_bounds__(256) void scan_k(const int* __restrict__ rawcnt, int* __restrict__ off) {
  __shared__ int ts[256];
  const int tid = threadIdx.x;
  const int base = tid * 32;
  int local[32];
  int s = 0;
#pragma unroll
  for (int i = 0; i < 32; i++) { local[i] = s; s += rawcnt[base + i]; }
  ts[tid] = s;
  __syncthreads();
  if (tid == 0) {
    int acc = 0;
    for (int i = 0; i < 256; i++) { int t = ts[i]; ts[i] = acc; acc += t; }
    off[NN] = acc;
  }
  __syncthreads();
  const int pre = ts[tid];
#pragma unroll
  for (int i = 0; i < 32; i++) off[base + i] = pre + local[i];
}

__global__ void scatter_k(const int* __restrict__ tgt, const int* __restrict__ off,
                          int* __restrict__ cursor, int* __restrict__ eperm) {
  const int e = blockIdx.x * blockDim.x + threadIdx.x;
  if (e < NE) {
    const int t = tgt[e];
    const int r = atomicAdd(&cursor[t], 1);
    eperm[off[t] + r] = e;
  }
}

// ---- CSR aggregation: one block (256 thr) per node. Zero atomics.
__global__ __launch_bounds__(256) void agg_k(const int* __restrict__ off, const int* __restrict__ eperm,
                                             const int* __restrict__ srcp,
                                             const __hip_bfloat16* __restrict__ h,
                                             const __hip_bfloat16* __restrict__ wv,
                                             const float* __restrict__ mp,
                                             const float* __restrict__ rn,
                                             const float* __restrict__ vprev,
                                             float* __restrict__ Hagg,
                                             float* __restrict__ v_o, float* __restrict__ p_o,
                                             int hasv) {
  const int n = blockIdx.x;
  const int c = threadIdx.x;
  const int e0 = off[n], e1 = off[n + 1];
  const int c3 = c >> 6, ln = c & 63;
  float hs = 0.f, vs = 0.f, ps = 0.f;
  for (int j = e0; j < e1; j++) {
    const int e = eperm[j];
    hs += __bfloat162float(h[(size_t)e * HIDc + c]);
    if (c < 192) {
      float mv = __bfloat162float(wv[(size_t)e * 128 + 64 + ln]) * rn[(size_t)e * 3 + c3];
      if (hasv) mv += __bfloat162float(wv[(size_t)e * 128 + ln]) * vprev[(size_t)srcp[e] * 192 + c];
      vs += mv;
    } else if (c < 195) {
      ps += mp[(size_t)e * 3 + (c - 192)];
    }
  }
  Hagg[(size_t)n * HIDc + c] = hs;
  const float inv = 1.0f / fmaxf((float)(e1 - e0), 1.0f);
  if (c < 192)      v_o[(size_t)n * 192 + c] += vs * inv;
  else if (c < 195) p_o[n * 3 + (c - 192)]   += ps * inv;
}

__global__ void zero_k(float* __restrict__ ptr, int n) {
  const int i = blockIdx.x * blockDim.x + threadIdx.x;
  if (i < n) ptr[i] = 0.f;
}

// ---- weight prep -> swizzled streams: chunk p of k-step t holds
// W^T[n][t*32 + kc*8 .. +8) with kc = p>>8, n = (p&255) ^ swz(kc).
__global__ void prep_w1abs_k(const float* __restrict__ W1, __hip_bfloat16* __restrict__ W1aS,
                             __hip_bfloat16* __restrict__ W1bS) {
  const int idx = blockIdx.x * blockDim.x + threadIdx.x;
  if (idx >= NL * T2 * 1024) return;
  const int p = idx & 1023, t = (idx >> 10) % T2, l = idx / (T2 * 1024);
  const int kc = p >> 8, n = (p & 255) ^ swz(kc);
  alignas(16) __hip_bfloat16 a8[8], b8[8];
#pragma unroll
  for (int j = 0; j < 8; j++) {
    const int k = t * 32 + kc * 8 + j;   // 0..255
    a8[j] = __float2bfloat16(W1[((size_t)l * DINc + k) * HIDc + n]);
    b8[j] = __float2bfloat16(W1[((size_t)l * DINc + 256 + k) * HIDc + n]);
  }
  *(uint4*)(W1aS + (size_t)idx * 8) = *(const uint4*)a8;
  *(uint4*)(W1bS + (size_t)idx * 8) = *(const uint4*)b8;
}

__global__ void prep_w1es_k(const float* __restrict__ W1, __hip_bfloat16* __restrict__ W1eS) {
  const int idx = blockIdx.x * blockDim.x + threadIdx.x;
  if (idx >= NL * TE * 1024) return;
  const int p = idx & 1023, t = (idx >> 10) % TE, l = idx / (TE * 1024);
  const int kc = p >> 8, n = (p & 255) ^ swz(kc);
  alignas(16) __hip_bfloat16 e8[8];
#pragma unroll
  for (int j = 0; j < 8; j++) {
    const int k = t * 32 + kc * 8 + j;   // 0..159
    const int row = (k < 128) ? (512 + k) : ((k < 132) ? (640 + (k - 128)) : -1);
    e8[j] = __float2bfloat16(row >= 0 ? W1[((size_t)l * DINc + row) * HIDc + n] : 0.f);
  }
  *(uint4*)(W1eS + (size_t)idx * 8) = *(const uint4*)e8;
}

__global__ void prep_w2s_k(const float* __restrict__ W2, __hip_bfloat16* __restrict__ W2sS,
                           __hip_bfloat16* __restrict__ W2aS) {
  const int idx = blockIdx.x * blockDim.x + threadIdx.x;
  if (idx >= NL * T2 * 1024) return;
  const int p = idx & 1023, t = (idx >> 10) & 7, l = idx >> 13;
  const int kc = p >> 8, n = (p & 255) ^ swz(kc);
  const float* W2l = W2 + (size_t)l * HIDc * DOUTc;
  const int cs = (n < 128) ? (256 + n) : (257 + n);  // wv1|wv2 then e_new (skip col 384)
  alignas(16) __hip_bfloat16 s8[8], a8[8];
#pragma unroll
  for (int j = 0; j < 8; j++) {
    const int k = t * 32 + kc * 8 + j;
    s8[j] = __float2bfloat16(W2l[(size_t)k * DOUTc + cs]);
    a8[j] = __float2bfloat16(W2l[(size_t)k * DOUTc + n]);
  }
  *(uint4*)(W2sS + (size_t)idx * 8) = *(const uint4*)s8;
  *(uint4*)(W2aS + (size_t)idx * 8) = *(const uint4*)a8;
}

__global__ void prep_uts_k(const float* __restrict__ U1, const float* __restrict__ U2,
                           __hip_bfloat16* __restrict__ U1S, __hip_bfloat16* __restrict__ U2S) {
  const int idx = blockIdx.x * blockDim.x + threadIdx.x;
  if (idx >= NL * T2 * 1024) return;
  const int p = idx & 1023, t = (idx >> 10) & 7, l = idx >> 13;
  const int kc = p >> 8, n = (p & 255) ^ swz(kc);
  alignas(16) __hip_bfloat16 u1[8], u2[8];
#pragma unroll
  for (int j = 0; j < 8; j++) {
    const int k = t * 32 + kc * 8 + j;
    u1[j] = __float2bfloat16(U1[((size_t)l * HIDc + k) * HIDc + n]);
    u2[j] = __float2bfloat16(U2[((size_t)l * HIDc + k) * HIDc + n]);
  }
  *(uint4*)(U1S + (size_t)idx * 8) = *(const uint4*)u1;
  *(uint4*)(U2S + (size_t)idx * 8) = *(const uint4*)u2;
}

__global__ void prep_w384_k(const float* __restrict__ W2, __hip_bfloat16* __restrict__ w384) {
  const int idx = blockIdx.x * blockDim.x + threadIdx.x;
  if (idx >= NL * HIDc) return;
  const int k = idx & 255, l = idx >> 8;
  w384[idx] = __float2bfloat16(W2[((size_t)l * HIDc + k) * DOUTc + 384]);
}

}  // namespace

extern "C" void kernel_launch(void* const* d_in, const int* in_sizes, int n_in,
                              void* d_out, int out_size, void* d_ws, size_t ws_size,
                              hipStream_t stream) {
  (void)in_sizes; (void)n_in; (void)out_size; (void)ws_size;
  const float* s_in = (const float*)d_in[0];
  const float* v_in = (const float*)d_in[1];
  const float* p_in = (const float*)d_in[2];
  const float* e_in = (const float*)d_in[3];
  const int*   ei   = (const int*)d_in[4];
  const float* ln_g = (const float*)d_in[5];
  const float* ln_b = (const float*)d_in[6];
  const float* W1   = (const float*)d_in[7];
  const float* b1   = (const float*)d_in[8];
  const float* W2   = (const float*)d_in[9];
  const float* b2   = (const float*)d_in[10];
  const float* U1   = (const float*)d_in[11];
  const float* bU1  = (const float*)d_in[12];
  const float* U2   = (const float*)d_in[13];
  const float* bU2  = (const float*)d_in[14];

  float* s_o = (float*)d_out;
  float* v_o = s_o + (size_t)NN * SD;
  float* e_o = v_o + (size_t)NN * 192;
  float* p_o = e_o + (size_t)NE * ED;

  const int* srcp = ei;
  const int* tgtp = ei + NE;

  char* wp = (char*)d_ws;
  auto alloc = [&](size_t bytes) -> char* {
    char* r = wp; wp += (bytes + 255) & ~(size_t)255; return r;
  };
  __hip_bfloat16* s_ln = (__hip_bfloat16*)alloc((size_t)NN * SD * 2);
  __hip_bfloat16* hbuf = (__hip_bfloat16*)alloc((size_t)NE * HIDc * 2);
  __hip_bfloat16* ebf  = (__hip_bfloat16*)alloc((size_t)NE * ED * 2);
  __hip_bfloat16* tbuf = (__hip_bfloat16*)alloc((size_t)NN * HIDc * 2);
  __hip_bfloat16* wvbuf= (__hip_bfloat16*)alloc((size_t)NE * 128 * 2);
  __hip_bfloat16* tailb= (__hip_bfloat16*)alloc((size_t)NE * 32 * 2);
  __hip_bfloat16* p1buf= (__hip_bfloat16*)alloc((size_t)NN * SD * 2);
  __hip_bfloat16* p2buf= (__hip_bfloat16*)alloc((size_t)NN * SD * 2);
  float* rnbuf = (float*)alloc((size_t)NE * 3 * 4);
  float* Hagg  = (float*)alloc((size_t)NN * SD * 4);
  float* vprev = (float*)alloc((size_t)NN * 192 * 4);
  float* mpbuf = (float*)alloc((size_t)NE * 3 * 4);
  float* zerobias = (float*)alloc(256 * 4);
  int*   rawcnt= (int*)alloc((size_t)NN * 4);
  int*   offb  = (int*)alloc((size_t)(NN + 1) * 4);
  int*   cursor= (int*)alloc((size_t)NN * 4);
  int*   eperm = (int*)alloc((size_t)NE * 4);
  __hip_bfloat16* W1aS = (__hip_bfloat16*)alloc((size_t)NL * T2 * 1024 * 8 * 2);
  __hip_bfloat16* W1bS = (__hip_bfloat16*)alloc((size_t)NL * T2 * 1024 * 8 * 2);
  __hip_bfloat16* W1eS = (__hip_bfloat16*)alloc((size_t)NL * TE * 1024 * 8 * 2);
  __hip_bfloat16* W2sS = (__hip_bfloat16*)alloc((size_t)NL * T2 * 1024 * 8 * 2);
  __hip_bfloat16* W2aS = (__hip_bfloat16*)alloc((size_t)NL * T2 * 1024 * 8 * 2);
  __hip_bfloat16* U1S  = (__hip_bfloat16*)alloc((size_t)NL * T2 * 1024 * 8 * 2);
  __hip_bfloat16* U2S  = (__hip_bfloat16*)alloc((size_t)NL * T2 * 1024 * 8 * 2);
  __hip_bfloat16* w384 = (__hip_bfloat16*)alloc((size_t)NL * HIDc * 2);

  hipMemcpyAsync(s_o, s_in, (size_t)NN * SD * 4, hipMemcpyDeviceToDevice, stream);
  hipMemcpyAsync(v_o, v_in, (size_t)NN * 192 * 4, hipMemcpyDeviceToDevice, stream);
  hipMemcpyAsync(p_o, p_in, (size_t)NN * 3 * 4, hipMemcpyDeviceToDevice, stream);

  prep_w1abs_k<<<(NL * T2 * 1024 + 255) / 256, 256, 0, stream>>>(W1, W1aS, W1bS);
  prep_w1es_k<<<(NL * TE * 1024 + 255) / 256, 256, 0, stream>>>(W1, W1eS);
  prep_w2s_k<<<(NL * T2 * 1024 + 255) / 256, 256, 0, stream>>>(W2, W2sS, W2aS);
  prep_uts_k<<<(NL * T2 * 1024 + 255) / 256, 256, 0, stream>>>(U1, U2, U1S, U2S);
  prep_w384_k<<<(NL * HIDc + 255) / 256, 256, 0, stream>>>(W2, w384);
  cvt_e_k<<<NE * ED / 8 / 256, 256, 0, stream>>>(e_in, ebf);
  zero_k<<<1, 256, 0, stream>>>(zerobias, 256);

  // ---- CSR build (once; edge_index layer-invariant)
  zero_k<<<(NN + 255) / 256, 256, 0, stream>>>((float*)rawcnt, NN);
  zero_k<<<(NN + 255) / 256, 256, 0, stream>>>((float*)cursor, NN);
  count_k<<<NE / 256, 256, 0, stream>>>(tgtp, rawcnt);
  scan_k<<<1, 256, 0, stream>>>(rawcnt, offb);
  scatter_k<<<NE / 256, 256, 0, stream>>>(tgtp, offb, cursor, eperm);

  for (int l = 0; l < NL; l++) {
    ln_k<<<NN / 4, 256, 0, stream>>>(s_o, ln_g + l * SD, ln_b + l * SD, s_ln);
    edge_attr_k<<<NE / 256, 256, 0, stream>>>(p_o, srcp, tgtp, rnbuf, tailb);

    // P1 = s_ln @ W1a + b1 ; P2 = s_ln @ W1b   (node GEMMs, K=256)
    GemmArgs gp1{};
    gp1.Wt = W1aS + (size_t)l * T2 * 1024 * 8; gp1.bias = b1 + l * HIDc;
    gp1.Abf = s_ln; gp1.bf_out = p1buf;
    gemm_k<MODE_LIN, SRC_BF16, 256><<<NN / 64, 256, 0, stream>>>(gp1);
    GemmArgs gp2{};
    gp2.Wt = W1bS + (size_t)l * T2 * 1024 * 8; gp2.bias = zerobias;
    gp2.Abf = s_ln; gp2.bf_out = p2buf;
    gemm_k<MODE_LIN, SRC_BF16, 256><<<NN / 64, 256, 0, stream>>>(gp2);

    // h = silu([e|tail] @ W1e + P1[src] + P2[tgt])   (edge GEMM, K=160)
    GemmArgs g1{};
    g1.Wt = W1eS + (size_t)l * TE * 1024 * 8; g1.bias = b1 + l * HIDc;
    g1.src = srcp; g1.tgt = tgtp; g1.e_bf = ebf; g1.tail = tailb;
    g1.p1 = p1buf; g1.p2 = p2buf; g1.bf_out = hbuf;
    gemm_k<MODE_HE, SRC_EDGE, KE><<<NE / 64, 256, 0, stream>>>(g1);

    GemmArgs g2{};
    g2.Wt = W2sS + (size_t)l * T2 * 1024 * 8; g2.bias = b2 + l * DOUTc;
    g2.Abf = hbuf; g2.wv_out = wvbuf; g2.e_bf_out = ebf; g2.e_f32_out = e_o;
    g2.w384 = w384 + l * HIDc; g2.rn = rnbuf; g2.mp = mpbuf;
    g2.write_e_f32 = (l == NL - 1) ? 1 : 0;
    gemm_k<MODE_OUT2, SRC_BF16, HIDc><<<NE / 64, 256, 0, stream>>>(g2);

    // pre-update v snapshot (messages read v[src] from BEFORE this layer's update)
    hipMemcpyAsync(vprev, v_o, (size_t)NN * 192 * 4, hipMemcpyDeviceToDevice, stream);

    agg_k<<<NN, 256, 0, stream>>>(offb, eperm, srcp, hbuf, wvbuf, mpbuf, rnbuf, vprev,
                                  Hagg, v_o, p_o, (l > 0) ? 1 : 0);

    GemmArgs g3{};
    g3.Wt = W2aS + (size_t)l * T2 * 1024 * 8; g3.bias = b2 + l * DOUTc;
    g3.Af32 = Hagg; g3.s_out = s_o; g3.rawcnt = rawcnt;
    gemm_k<MODE_SADD, SRC_F32, HIDc><<<NN / 64, 256, 0, stream>>>(g3);

    if (l < NL - 1) {
      GemmArgs g4{};
      g4.Wt = U1S + (size_t)l * T2 * 1024 * 8; g4.bias = bU1 + l * HIDc;
      g4.Af32 = s_o; g4.bf_out = tbuf;
      gemm_k<MODE_H, SRC_F32, HIDc><<<NN / 64, 256, 0, stream>>>(g4);

      GemmArgs g5{};
      g5.Wt = U2S + (size_t)l * T2 * 1024 * 8; g5.bias = bU2 + l * HIDc;
      g5.Abf = tbuf; g5.s_out = s_o;
      gemm_k<MODE_SADD2, SRC_BF16, HIDc><<<NN / 64, 256, 0, stream>>>(g5);
    }
  }
}

// Round 7
// 1606.390 us; speedup vs baseline: 2.2948x; 1.0447x over previous
//
#include <hip/hip_runtime.h>
#include <hip/hip_bf16.h>

namespace {

constexpr int NN   = 8192;    // nodes
constexpr int NE   = 131072;  // edges
constexpr int SD   = 256;     // SDIM
constexpr int ED   = 128;     // EDIM
constexpr int NL   = 5;       // layers
constexpr int DINc = 644;     // 2*SD + ED + 4
constexpr int KE   = 160;     // edge-GEMM K: 128 e + 4 scalars + pad
constexpr int TE   = 5;       // KE/32
constexpr int T2   = 8;       // 256/32
constexpr int DOUTc= 513;
constexpr int HIDc = 256;

typedef __bf16 bf16x8 __attribute__((ext_vector_type(8)));
typedef float  f32x4  __attribute__((ext_vector_type(4)));

__device__ __forceinline__ float siluf(float x) { return x / (1.0f + __expf(-x)); }

// async global->LDS, 16B/lane. LDS dest is wave-uniform base (+lane*16 in HW).
__device__ __forceinline__ void gl_lds16(const void* gsrc, void* lds_uniform_base) {
  __builtin_amdgcn_global_load_lds(
      (const __attribute__((address_space(1))) unsigned int*)gsrc,
      (__attribute__((address_space(3))) unsigned int*)lds_uniform_base, 16, 0, 0);
}

// bank-group swizzle: XOR set {0,5,2,7} -> write AND read phases are 8-permutations.
__device__ __host__ __forceinline__ int swz(int kc) { return (kc * 5) & 7; }
__device__ __forceinline__ int apos(int kc, int row) { return kc * 64  + (row ^ swz(kc)); }
__device__ __forceinline__ int bpos(int kc, int n)   { return kc * 256 + (n   ^ swz(kc)); }

enum { MODE_H = 0, MODE_SADD = 2, MODE_SADD2 = 3, MODE_LIN = 4 };
enum { SRC_BF16 = 1, SRC_F32 = 2 };

struct GemmArgs {
  const __hip_bfloat16* Wt;     // swizzled B stream: [T][1024 chunks][8 bf16]
  const float* bias;
  const __hip_bfloat16* Abf;    // SRC_BF16 source, [M][K]
  const float* Af32;            // SRC_F32 source, [M][K]
  __hip_bfloat16* bf_out;
  float* s_out;                 // d_out s region (RMW)
  const int* rawcnt;
  // dual-launch (MODE_LIN): second half of grid uses these
  const __hip_bfloat16* Wtb;
  const float* biasb;
  __hip_bfloat16* bf_outb;
  int dual;
};

__device__ __forceinline__ uint4 cvt8f(const float* p) {
  alignas(16) __hip_bfloat16 t8[8];
#pragma unroll
  for (int i = 0; i < 8; i++) t8[i] = __float2bfloat16(p[i]);
  return *(const uint4*)t8;
}

// BM=64, BN=256, BK=32, 4 waves, acc[4][4]. B via gl_lds dbuf from pre-swizzled stream.
template<int MODE, int SRC, int KTOT>
__global__ __launch_bounds__(256) void gemm_k(GemmArgs g) {
  constexpr int T = KTOT / 32;
  __shared__ alignas(16) unsigned short Ash[4 * 64 * 8];        // 4 KB
  __shared__ alignas(16) unsigned short Bsh[2][4 * 256 * 8];    // 32 KB
  const int tid = threadIdx.x, lane = tid & 63, wave = tid >> 6;
  const int l16 = lane & 15, lhi = lane >> 4;
  const __hip_bfloat16* wtp = g.Wt;
  const float* biasp = g.bias;
  __hip_bfloat16* outp = g.bf_out;
  int blk = blockIdx.x;
  if constexpr (MODE == MODE_LIN) {
    const int half = gridDim.x >> 1;
    if (g.dual && blk >= half) { blk -= half; wtp = g.Wtb; biasp = g.biasb; outp = g.bf_outb; }
  }
  const int row0 = blk * 64;
  const int ar = tid >> 2, aq = tid & 3;
  const int arow = row0 + ar;
  f32x4 acc[4][4] = {};

  auto loadA = [&](int t, uint4& o) {
    const int kq = t * 32 + aq * 8;
    if constexpr (SRC == SRC_BF16) {
      o = *(const uint4*)(g.Abf + (size_t)arow * KTOT + kq);
    } else {
      o = cvt8f(g.Af32 + (size_t)arow * KTOT + kq);
    }
  };
  auto issueB = [&](int t, int buf) {
    const __hip_bfloat16* src = wtp + (size_t)t * 1024 * 8;
    unsigned short* dst = &Bsh[buf][0];
#pragma unroll
    for (int i = 0; i < 4; i++)
      gl_lds16(src + (size_t)(i * 256 + wave * 64 + lane) * 8, dst + (i * 256 + wave * 64) * 8);
  };

  uint4 a;
  loadA(0, a);
  issueB(0, 0);
  int cur = 0;

  for (int t = 0; t < T; ++t) {
    *(uint4*)&Ash[apos(aq, ar) * 8] = a;
    __syncthreads();   // Ash visible; B[t] landed
    if (t + 1 < T) { issueB(t + 1, cur ^ 1); loadA(t + 1, a); }
    bf16x8 bfr[4];
#pragma unroll
    for (int fc = 0; fc < 4; fc++)
      bfr[fc] = *(const bf16x8*)&Bsh[cur][bpos(lhi, wave * 64 + fc * 16 + l16) * 8];
#pragma unroll
    for (int fr = 0; fr < 4; fr++) {
      const bf16x8 afr = *(const bf16x8*)&Ash[apos(lhi, fr * 16 + l16) * 8];
#pragma unroll
      for (int fc = 0; fc < 4; fc++)
        acc[fr][fc] = __builtin_amdgcn_mfma_f32_16x16x32_bf16(afr, bfr[fc], acc[fr][fc], 0, 0, 0);
    }
    __syncthreads();
    cur ^= 1;
  }

  // ---- epilogue: D[row = 4*(lane>>4)+r][col = lane&15] per 16x16 tile
#pragma unroll
  for (int fr = 0; fr < 4; fr++) {
#pragma unroll
    for (int fc = 0; fc < 4; fc++) {
      const int n = wave * 64 + fc * 16 + l16;
#pragma unroll
      for (int r = 0; r < 4; r++) {
        const int row = row0 + fr * 16 + lhi * 4 + r;
        const float valf = acc[fr][fc][r];
        if constexpr (MODE == MODE_H) {
          outp[(size_t)row * HIDc + n] = __float2bfloat16(siluf(valf + biasp[n]));
        } else if constexpr (MODE == MODE_LIN) {
          outp[(size_t)row * HIDc + n] = __float2bfloat16(valf + biasp[n]);
        } else if constexpr (MODE == MODE_SADD) {
          const float rc = (float)g.rawcnt[row];
          g.s_out[(size_t)row * SD + n] += valf + rc * biasp[n];
        } else {  // MODE_SADD2
          g.s_out[(size_t)row * SD + n] += valf + biasp[n];
        }
      }
    }
  }
}

// ==== fused edge kernel: h = silu([e|tail]@W1e + P1[src] + P2[tgt]); out2 = h@W2s ====
struct FusedArgs {
  const __hip_bfloat16* W1e;    // [TE][1024][8] swizzled stream
  const __hip_bfloat16* W2s;    // [T2][1024][8] swizzled stream
  const float* b2L;             // b2 + l*DOUT
  const int* src; const int* tgt;
  const __hip_bfloat16* e_bf;   // [NE][128]  (in; overwritten with new e in epilogue-2)
  const __hip_bfloat16* tail;   // [NE][32]
  const __hip_bfloat16* p1;     // [NN][256]
  const __hip_bfloat16* p2;     // [NN][256]
  const __hip_bfloat16* w384;   // [256]
  const float* rn;              // [NE][3]
  float* mp;                    // [NE][3] out
  __hip_bfloat16* h_out;        // [NE][256]
  __hip_bfloat16* wv_out;       // [NE][128]
  __hip_bfloat16* e_bf_out;     // [NE][128]
  float* e_f32_out;             // d_out e region
  int write_e_f32;
};

__global__ __launch_bounds__(256) void fused_k(FusedArgs g) {
  __shared__ alignas(16) unsigned short Ash[4 * 64 * 8];        // 4 KB (edge A)
  __shared__ alignas(16) unsigned short Bsh[2][4 * 256 * 8];    // 32 KB (W stream dbuf)
  __shared__ alignas(16) unsigned short Hsh[32 * 64 * 8];       // 32 KB (psum -> h)
  __shared__ float wps[4][64];
  const int tid = threadIdx.x, lane = tid & 63, wave = tid >> 6;
  const int l16 = lane & 15, lhi = lane >> 4;
  const int row0 = blockIdx.x * 64;
  const int ar = tid >> 2, aq = tid & 3;
  const int arow = row0 + ar;
  const int sn = g.src[arow], tn = g.tgt[arow];

  auto issueW = [&](const __hip_bfloat16* W, int t, int buf) {
    const __hip_bfloat16* src = W + (size_t)t * 1024 * 8;
    unsigned short* dst = &Bsh[buf][0];
#pragma unroll
    for (int i = 0; i < 4; i++)
      gl_lds16(src + (size_t)(i * 256 + wave * 64 + lane) * 8, dst + (i * 256 + wave * 64) * 8);
  };
  auto loadA = [&](int t, uint4& o) {
    const int kq = t * 32 + aq * 8;
    if (kq < 128) o = *(const uint4*)(g.e_bf + (size_t)arow * ED + kq);
    else          o = *(const uint4*)(g.tail + (size_t)arow * 32 + (kq - 128));
  };

  uint4 a;
  loadA(0, a);
  issueW(g.W1e, 0, 0);

  // ---- stage Psum = P1[sn] + P2[tn] into Hsh [32 kc][64 row][8] (kc&3-swizzled)
#pragma unroll
  for (int j = 0; j < 8; j++) {
    const int c = aq * 8 + j;            // k-chunk 0..31 ; c&3 == j&3
    uint4 r1 = *(const uint4*)(g.p1 + (size_t)sn * SD + c * 8);
    uint4 r2 = *(const uint4*)(g.p2 + (size_t)tn * SD + c * 8);
    const __hip_bfloat16* h1 = (const __hip_bfloat16*)&r1;
    const __hip_bfloat16* h2 = (const __hip_bfloat16*)&r2;
    alignas(16) __hip_bfloat16 o8[8];
#pragma unroll
    for (int m = 0; m < 8; m++)
      o8[m] = __float2bfloat16(__bfloat162float(h1[m]) + __bfloat162float(h2[m]));
    *(uint4*)&Hsh[(c * 64 + (ar ^ swz(c & 3))) * 8] = *(const uint4*)o8;
  }

  // ---- phase 1: SWAPPED operands -> D[n][row] (thread holds 4 consecutive n per row)
  f32x4 acc1[4][4] = {};
  int cur = 0;
  for (int t = 0; t < TE; ++t) {
    *(uint4*)&Ash[apos(aq, ar) * 8] = a;
    __syncthreads();
    if (t + 1 < TE) { issueW(g.W1e, t + 1, cur ^ 1); loadA(t + 1, a); }
    bf16x8 wfr[4], efr[4];
#pragma unroll
    for (int f = 0; f < 4; f++) {
      wfr[f] = *(const bf16x8*)&Bsh[cur][bpos(lhi, wave * 64 + f * 16 + l16) * 8];
      efr[f] = *(const bf16x8*)&Ash[apos(lhi, f * 16 + l16) * 8];
    }
#pragma unroll
    for (int fr = 0; fr < 4; fr++)
#pragma unroll
      for (int fc = 0; fc < 4; fc++)
        acc1[fr][fc] = __builtin_amdgcn_mfma_f32_16x16x32_bf16(wfr[fr], efr[fc], acc1[fr][fc], 0, 0, 0);
    __syncthreads();
    cur ^= 1;
  }

  issueW(g.W2s, 0, 0);   // prefetch phase-2 B step 0 under the epilogue

  // ---- epilogue-1: h = silu(acc1 + psum); Hsh in-place; global h; wp partials
  float pw[4] = {0.f, 0.f, 0.f, 0.f};
#pragma unroll
  for (int fr = 0; fr < 4; fr++) {
    const int nb = wave * 64 + fr * 16 + lhi * 4;   // n base (4-aligned)
    const int kc = nb >> 3, off = nb & 7;
    uint2 wr = *(const uint2*)(g.w384 + nb);
    const __hip_bfloat16* w4 = (const __hip_bfloat16*)&wr;
#pragma unroll
    for (int fc = 0; fc < 4; fc++) {
      const int row = fc * 16 + l16;
      unsigned short* slot = &Hsh[(kc * 64 + (row ^ swz(kc & 3))) * 8 + off];
      uint2 pr = *(const uint2*)slot;
      const __hip_bfloat16* ps = (const __hip_bfloat16*)&pr;
      alignas(8) __hip_bfloat16 hb[4];
#pragma unroll
      for (int r = 0; r < 4; r++) {
        const float hv = siluf(acc1[fr][fc][r] + __bfloat162float(ps[r]));
        hb[r] = __float2bfloat16(hv);
        pw[fc] += hv * __bfloat162float(w4[r]);
      }
      *(uint2*)slot = *(const uint2*)hb;
      *(uint2*)(g.h_out + (size_t)(row0 + row) * HIDc + nb) = *(const uint2*)hb;
    }
  }
  __syncthreads();   // h visible to all; W2s(0) landed

  // ---- wp reduce: sum over lhi (lanes +16,+32), then across waves via LDS
#pragma unroll
  for (int fc = 0; fc < 4; fc++) {
    pw[fc] += __shfl_xor(pw[fc], 16);
    pw[fc] += __shfl_xor(pw[fc], 32);
  }
  if (lane < 16) {
#pragma unroll
    for (int fc = 0; fc < 4; fc++) wps[wave][fc * 16 + lane] = pw[fc];
  }
  __syncthreads();
  if (tid < 64) {
    const float s = wps[0][tid] + wps[1][tid] + wps[2][tid] + wps[3][tid];
    const float wpt = tanhf(s + g.b2L[384]);
#pragma unroll
    for (int c = 0; c < 3; c++)
      g.mp[(size_t)(row0 + tid) * 3 + c] = wpt * g.rn[(size_t)(row0 + tid) * 3 + c];
  }

  // ---- phase 2: out2 = h @ W2s (A resident in Hsh; 1 barrier/step)
  f32x4 acc2[4][4] = {};
  cur = 0;
  for (int t = 0; t < T2; ++t) {
    if (t + 1 < T2) issueW(g.W2s, t + 1, cur ^ 1);
    bf16x8 afr[4], bfr[4];
#pragma unroll
    for (int f = 0; f < 4; f++) {
      const int kc = t * 4 + lhi;        // kc & 3 == lhi
      afr[f] = *(const bf16x8*)&Hsh[(kc * 64 + ((f * 16 + l16) ^ swz(lhi))) * 8];
      bfr[f] = *(const bf16x8*)&Bsh[cur][bpos(lhi, wave * 64 + f * 16 + l16) * 8];
    }
#pragma unroll
    for (int fr = 0; fr < 4; fr++)
#pragma unroll
      for (int fc = 0; fc < 4; fc++)
        acc2[fr][fc] = __builtin_amdgcn_mfma_f32_16x16x32_bf16(afr[fr], bfr[fc], acc2[fr][fc], 0, 0, 0);
    __syncthreads();   // drains W2s(t+1); frees Bsh[cur] reads
    cur ^= 1;
  }

  // ---- epilogue-2: wv | e_new
#pragma unroll
  for (int fr = 0; fr < 4; fr++) {
#pragma unroll
    for (int fc = 0; fc < 4; fc++) {
      const int n = wave * 64 + fc * 16 + l16;
#pragma unroll
      for (int r = 0; r < 4; r++) {
        const int row = row0 + fr * 16 + lhi * 4 + r;
        const float valf = acc2[fr][fc][r];
        if (n < 128) {
          g.wv_out[(size_t)row * 128 + n] = __float2bfloat16(valf + g.b2L[256 + n]);
        } else {
          const float sv = siluf(valf + g.b2L[257 + n]);   // e_new cols = W2 cols 385..512
          g.e_bf_out[(size_t)row * ED + (n - 128)] = __float2bfloat16(sv);
          if (g.write_e_f32) g.e_f32_out[(size_t)row * ED + (n - 128)] = sv;
        }
      }
    }
  }
}

// ---- LayerNorm. 4 nodes/block, wave per node.
__global__ __launch_bounds__(256) void ln_k(const float* __restrict__ s,
                                            const float* __restrict__ gl, const float* __restrict__ bl,
                                            __hip_bfloat16* __restrict__ s_ln) {
  const int wave = threadIdx.x >> 6, lane = threadIdx.x & 63;
  const int node = blockIdx.x * 4 + wave;
  const float* srow = s + (size_t)node * SD;
  float x[4], sum = 0.f, sq = 0.f;
#pragma unroll
  for (int i = 0; i < 4; i++) { x[i] = srow[lane * 4 + i]; sum += x[i]; sq += x[i] * x[i]; }
#pragma unroll
  for (int off = 1; off < 64; off <<= 1) { sum += __shfl_xor(sum, off); sq += __shfl_xor(sq, off); }
  const float mu = sum * (1.0f / SD);
  const float var = sq * (1.0f / SD) - mu * mu;
  const float rstd = rsqrtf(var + 1e-5f);
#pragma unroll
  for (int i = 0; i < 4; i++) {
    const int c = lane * 4 + i;
    s_ln[(size_t)node * SD + c] = __float2bfloat16(gl[c] * (x[i] - mu) * rstd + bl[c]);
  }
}

// ---- per-edge attrs: rn + bf16 tail block [NE][32] = {d,a,pn_src,pn_tgt,0,...}
__global__ void edge_attr_k(const float* __restrict__ p, const int* __restrict__ src, const int* __restrict__ tgt,
                            float* __restrict__ rn, __hip_bfloat16* __restrict__ tail) {
  const int e = blockIdx.x * blockDim.x + threadIdx.x;
  if (e >= NE) return;
  const int s_ = src[e], t_ = tgt[e];
  const float sx = p[s_ * 3], sy = p[s_ * 3 + 1], sz = p[s_ * 3 + 2];
  const float tx = p[t_ * 3], ty = p[t_ * 3 + 1], tz = p[t_ * 3 + 2];
  const float rx = tx - sx, ry = ty - sy, rz = tz - sz;
  const float a = tx * sx + ty * sy + tz * sz;
  const float rr = rx * rx + ry * ry + rz * rz;
  const float d = sqrtf(fmaxf(rr, 1e-6f));
  const float inv = 1.0f / (1.0f + d);
  rn[e * 3] = rx * inv; rn[e * 3 + 1] = ry * inv; rn[e * 3 + 2] = rz * inv;
  alignas(16) __hip_bfloat16 t8[8];
  t8[0] = __float2bfloat16(d);
  t8[1] = __float2bfloat16(a);
  t8[2] = __float2bfloat16(sqrtf(sx * sx + sy * sy + sz * sz));
  t8[3] = __float2bfloat16(sqrtf(tx * tx + ty * ty + tz * tz));
  t8[4] = t8[5] = t8[6] = t8[7] = __float2bfloat16(0.0f);
  __hip_bfloat16* tp = tail + (size_t)e * 32;
  uint4 z; z.x = z.y = z.z = z.w = 0;
  *(uint4*)tp = *(const uint4*)t8;
  *(uint4*)(tp + 8) = z;
  *(uint4*)(tp + 16) = z;
  *(uint4*)(tp + 24) = z;
}

__global__ void cvt_e_k(const float* __restrict__ e, __hip_bfloat16* __restrict__ ebf) {
  const int i = blockIdx.x * blockDim.x + threadIdx.x;
  const float* p = e + (size_t)i * 8;
  alignas(16) __hip_bfloat16 t8[8];
#pragma unroll
  for (int j = 0; j < 8; j++) t8[j] = __float2bfloat16(p[j]);
  *(uint4*)(ebf + (size_t)i * 8) = *(const uint4*)t8;
}

__global__ void count_k(const int* __restrict__ tgt, int* __restrict__ rawcnt) {
  const int e = blockIdx.x * blockDim.x + threadIdx.x;
  if (e < NE) atomicAdd(&rawcnt[tgt[e]], 1);
}

__global__ __launch_bounds__(256) void scan_k(const int* __restrict__ rawcnt, int* __restrict__ off) {
  __shared__ int ts[256];
  const int tid = threadIdx.x;
  const int base = tid * 32;
  int local[32];
  int s = 0;
#pragma unroll
  for (int i = 0; i < 32; i++) { local[i] = s; s += rawcnt[base + i]; }
  ts[tid] = s;
  __syncthreads();
  if (tid == 0) {
    int acc = 0;
    for (int i = 0; i < 256; i++) { int t = ts[i]; ts[i] = acc; acc += t; }
    off[NN] = acc;
  }
  __syncthreads();
  const int pre = ts[tid];
#pragma unroll
  for (int i = 0; i < 32; i++) off[base + i] = pre + local[i];
}

__global__ void scatter_k(const int* __restrict__ tgt, const int* __restrict__ off,
                          int* __restrict__ cursor, int* __restrict__ eperm) {
  const int e = blockIdx.x * blockDim.x + threadIdx.x;
  if (e < NE) {
    const int t = tgt[e];
    const int r = atomicAdd(&cursor[t], 1);
    eperm[off[t] + r] = e;
  }
}

// ---- CSR aggregation: one block (256 thr) per node. Zero atomics.
__global__ __launch_bounds__(256) void agg_k(const int* __restrict__ off, const int* __restrict__ eperm,
                                             const int* __restrict__ srcp,
                                             const __hip_bfloat16* __restrict__ h,
                                             const __hip_bfloat16* __restrict__ wv,
                                             const float* __restrict__ mp,
                                             const float* __restrict__ rn,
                                             const float* __restrict__ vprev,
                                             float* __restrict__ Hagg,
                                             float* __restrict__ v_o, float* __restrict__ p_o,
                                             int hasv) {
  const int n = blockIdx.x;
  const int c = threadIdx.x;
  const int e0 = off[n], e1 = off[n + 1];
  const int c3 = c >> 6, ln = c & 63;
  float hs = 0.f, vs = 0.f, ps = 0.f;
  for (int j = e0; j < e1; j++) {
    const int e = eperm[j];
    hs += __bfloat162float(h[(size_t)e * HIDc + c]);
    if (c < 192) {
      float mv = __bfloat162float(wv[(size_t)e * 128 + 64 + ln]) * rn[(size_t)e * 3 + c3];
      if (hasv) mv += __bfloat162float(wv[(size_t)e * 128 + ln]) * vprev[(size_t)srcp[e] * 192 + c];
      vs += mv;
    } else if (c < 195) {
      ps += mp[(size_t)e * 3 + (c - 192)];
    }
  }
  Hagg[(size_t)n * HIDc + c] = hs;
  const float inv = 1.0f / fmaxf((float)(e1 - e0), 1.0f);
  if (c < 192)      v_o[(size_t)n * 192 + c] += vs * inv;
  else if (c < 195) p_o[n * 3 + (c - 192)]   += ps * inv;
}

__global__ void zero_k(float* __restrict__ ptr, int n) {
  const int i = blockIdx.x * blockDim.x + threadIdx.x;
  if (i < n) ptr[i] = 0.f;
}

// ---- weight prep -> swizzled streams: chunk p of k-step t holds
// W^T[n][t*32 + kc*8 .. +8) with kc = p>>8, n = (p&255) ^ swz(kc).
__global__ void prep_w1abs_k(const float* __restrict__ W1, __hip_bfloat16* __restrict__ W1aS,
                             __hip_bfloat16* __restrict__ W1bS) {
  const int idx = blockIdx.x * blockDim.x + threadIdx.x;
  if (idx >= NL * T2 * 1024) return;
  const int p = idx & 1023, t = (idx >> 10) % T2, l = idx / (T2 * 1024);
  const int kc = p >> 8, n = (p & 255) ^ swz(kc);
  alignas(16) __hip_bfloat16 a8[8], b8[8];
#pragma unroll
  for (int j = 0; j < 8; j++) {
    const int k = t * 32 + kc * 8 + j;   // 0..255
    a8[j] = __float2bfloat16(W1[((size_t)l * DINc + k) * HIDc + n]);
    b8[j] = __float2bfloat16(W1[((size_t)l * DINc + 256 + k) * HIDc + n]);
  }
  *(uint4*)(W1aS + (size_t)idx * 8) = *(const uint4*)a8;
  *(uint4*)(W1bS + (size_t)idx * 8) = *(const uint4*)b8;
}

__global__ void prep_w1es_k(const float* __restrict__ W1, __hip_bfloat16* __restrict__ W1eS) {
  const int idx = blockIdx.x * blockDim.x + threadIdx.x;
  if (idx >= NL * TE * 1024) return;
  const int p = idx & 1023, t = (idx >> 10) % TE, l = idx / (TE * 1024);
  const int kc = p >> 8, n = (p & 255) ^ swz(kc);
  alignas(16) __hip_bfloat16 e8[8];
#pragma unroll
  for (int j = 0; j < 8; j++) {
    const int k = t * 32 + kc * 8 + j;   // 0..159
    const int row = (k < 128) ? (512 + k) : ((k < 132) ? (640 + (k - 128)) : -1);
    e8[j] = __float2bfloat16(row >= 0 ? W1[((size_t)l * DINc + row) * HIDc + n] : 0.f);
  }
  *(uint4*)(W1eS + (size_t)idx * 8) = *(const uint4*)e8;
}

__global__ void prep_w2s_k(const float* __restrict__ W2, __hip_bfloat16* __restrict__ W2sS,
                           __hip_bfloat16* __restrict__ W2aS) {
  const int idx = blockIdx.x * blockDim.x + threadIdx.x;
  if (idx >= NL * T2 * 1024) return;
  const int p = idx & 1023, t = (idx >> 10) & 7, l = idx >> 13;
  const int kc = p >> 8, n = (p & 255) ^ swz(kc);
  const float* W2l = W2 + (size_t)l * HIDc * DOUTc;
  const int cs = (n < 128) ? (256 + n) : (257 + n);  // wv1|wv2 then e_new (skip col 384)
  alignas(16) __hip_bfloat16 s8[8], a8[8];
#pragma unroll
  for (int j = 0; j < 8; j++) {
    const int k = t * 32 + kc * 8 + j;
    s8[j] = __float2bfloat16(W2l[(size_t)k * DOUTc + cs]);
    a8[j] = __float2bfloat16(W2l[(size_t)k * DOUTc + n]);
  }
  *(uint4*)(W2sS + (size_t)idx * 8) = *(const uint4*)s8;
  *(uint4*)(W2aS + (size_t)idx * 8) = *(const uint4*)a8;
}

__global__ void prep_uts_k(const float* __restrict__ U1, const float* __restrict__ U2,
                           __hip_bfloat16* __restrict__ U1S, __hip_bfloat16* __restrict__ U2S) {
  const int idx = blockIdx.x * blockDim.x + threadIdx.x;
  if (idx >= NL * T2 * 1024) return;
  const int p = idx & 1023, t = (idx >> 10) & 7, l = idx >> 13;
  const int kc = p >> 8, n = (p & 255) ^ swz(kc);
  alignas(16) __hip_bfloat16 u1[8], u2[8];
#pragma unroll
  for (int j = 0; j < 8; j++) {
    const int k = t * 32 + kc * 8 + j;
    u1[j] = __float2bfloat16(U1[((size_t)l * HIDc + k) * HIDc + n]);
    u2[j] = __float2bfloat16(U2[((size_t)l * HIDc + k) * HIDc + n]);
  }
  *(uint4*)(U1S + (size_t)idx * 8) = *(const uint4*)u1;
  *(uint4*)(U2S + (size_t)idx * 8) = *(const uint4*)u2;
}

__global__ void prep_w384_k(const float* __restrict__ W2, __hip_bfloat16* __restrict__ w384) {
  const int idx = blockIdx.x * blockDim.x + threadIdx.x;
  if (idx >= NL * HIDc) return;
  const int k = idx & 255, l = idx >> 8;
  w384[idx] = __float2bfloat16(W2[((size_t)l * HIDc + k) * DOUTc + 384]);
}

}  // namespace

extern "C" void kernel_launch(void* const* d_in, const int* in_sizes, int n_in,
                              void* d_out, int out_size, void* d_ws, size_t ws_size,
                              hipStream_t stream) {
  (void)in_sizes; (void)n_in; (void)out_size; (void)ws_size;
  const float* s_in = (const float*)d_in[0];
  const float* v_in = (const float*)d_in[1];
  const float* p_in = (const float*)d_in[2];
  const float* e_in = (const float*)d_in[3];
  const int*   ei   = (const int*)d_in[4];
  const float* ln_g = (const float*)d_in[5];
  const float* ln_b = (const float*)d_in[6];
  const float* W1   = (const float*)d_in[7];
  const float* b1   = (const float*)d_in[8];
  const float* W2   = (const float*)d_in[9];
  const float* b2   = (const float*)d_in[10];
  const float* U1   = (const float*)d_in[11];
  const float* bU1  = (const float*)d_in[12];
  const float* U2   = (const float*)d_in[13];
  const float* bU2  = (const float*)d_in[14];

  float* s_o = (float*)d_out;
  float* v_o = s_o + (size_t)NN * SD;
  float* e_o = v_o + (size_t)NN * 192;
  float* p_o = e_o + (size_t)NE * ED;

  const int* srcp = ei;
  const int* tgtp = ei + NE;

  char* wp = (char*)d_ws;
  auto alloc = [&](size_t bytes) -> char* {
    char* r = wp; wp += (bytes + 255) & ~(size_t)255; return r;
  };
  __hip_bfloat16* s_ln = (__hip_bfloat16*)alloc((size_t)NN * SD * 2);
  __hip_bfloat16* hbuf = (__hip_bfloat16*)alloc((size_t)NE * HIDc * 2);
  __hip_bfloat16* ebf  = (__hip_bfloat16*)alloc((size_t)NE * ED * 2);
  __hip_bfloat16* tbuf = (__hip_bfloat16*)alloc((size_t)NN * HIDc * 2);
  __hip_bfloat16* wvbuf= (__hip_bfloat16*)alloc((size_t)NE * 128 * 2);
  __hip_bfloat16* tailb= (__hip_bfloat16*)alloc((size_t)NE * 32 * 2);
  __hip_bfloat16* p1buf= (__hip_bfloat16*)alloc((size_t)NN * SD * 2);
  __hip_bfloat16* p2buf= (__hip_bfloat16*)alloc((size_t)NN * SD * 2);
  float* rnbuf = (float*)alloc((size_t)NE * 3 * 4);
  float* Hagg  = (float*)alloc((size_t)NN * SD * 4);
  float* vprev = (float*)alloc((size_t)NN * 192 * 4);
  float* mpbuf = (float*)alloc((size_t)NE * 3 * 4);
  float* zerobias = (float*)alloc(256 * 4);
  int*   rawcnt= (int*)alloc((size_t)NN * 4);
  int*   offb  = (int*)alloc((size_t)(NN + 1) * 4);
  int*   cursor= (int*)alloc((size_t)NN * 4);
  int*   eperm = (int*)alloc((size_t)NE * 4);
  __hip_bfloat16* W1aS = (__hip_bfloat16*)alloc((size_t)NL * T2 * 1024 * 8 * 2);
  __hip_bfloat16* W1bS = (__hip_bfloat16*)alloc((size_t)NL * T2 * 1024 * 8 * 2);
  __hip_bfloat16* W1eS = (__hip_bfloat16*)alloc((size_t)NL * TE * 1024 * 8 * 2);
  __hip_bfloat16* W2sS = (__hip_bfloat16*)alloc((size_t)NL * T2 * 1024 * 8 * 2);
  __hip_bfloat16* W2aS = (__hip_bfloat16*)alloc((size_t)NL * T2 * 1024 * 8 * 2);
  __hip_bfloat16* U1S  = (__hip_bfloat16*)alloc((size_t)NL * T2 * 1024 * 8 * 2);
  __hip_bfloat16* U2S  = (__hip_bfloat16*)alloc((size_t)NL * T2 * 1024 * 8 * 2);
  __hip_bfloat16* w384 = (__hip_bfloat16*)alloc((size_t)NL * HIDc * 2);

  hipMemcpyAsync(s_o, s_in, (size_t)NN * SD * 4, hipMemcpyDeviceToDevice, stream);
  hipMemcpyAsync(v_o, v_in, (size_t)NN * 192 * 4, hipMemcpyDeviceToDevice, stream);
  hipMemcpyAsync(p_o, p_in, (size_t)NN * 3 * 4, hipMemcpyDeviceToDevice, stream);

  prep_w1abs_k<<<(NL * T2 * 1024 + 255) / 256, 256, 0, stream>>>(W1, W1aS, W1bS);
  prep_w1es_k<<<(NL * TE * 1024 + 255) / 256, 256, 0, stream>>>(W1, W1eS);
  prep_w2s_k<<<(NL * T2 * 1024 + 255) / 256, 256, 0, stream>>>(W2, W2sS, W2aS);
  prep_uts_k<<<(NL * T2 * 1024 + 255) / 256, 256, 0, stream>>>(U1, U2, U1S, U2S);
  prep_w384_k<<<(NL * HIDc + 255) / 256, 256, 0, stream>>>(W2, w384);
  cvt_e_k<<<NE * ED / 8 / 256, 256, 0, stream>>>(e_in, ebf);
  zero_k<<<1, 256, 0, stream>>>(zerobias, 256);

  // ---- CSR build (once; edge_index layer-invariant)
  zero_k<<<(NN + 255) / 256, 256, 0, stream>>>((float*)rawcnt, NN);
  zero_k<<<(NN + 255) / 256, 256, 0, stream>>>((float*)cursor, NN);
  count_k<<<NE / 256, 256, 0, stream>>>(tgtp, rawcnt);
  scan_k<<<1, 256, 0, stream>>>(rawcnt, offb);
  scatter_k<<<NE / 256, 256, 0, stream>>>(tgtp, offb, cursor, eperm);

  for (int l = 0; l < NL; l++) {
    ln_k<<<NN / 4, 256, 0, stream>>>(s_o, ln_g + l * SD, ln_b + l * SD, s_ln);
    edge_attr_k<<<NE / 256, 256, 0, stream>>>(p_o, srcp, tgtp, rnbuf, tailb);

    // P1 = s_ln @ W1a + b1 ; P2 = s_ln @ W1b  (single dual launch, 256 blocks)
    GemmArgs gp{};
    gp.Wt = W1aS + (size_t)l * T2 * 1024 * 8; gp.bias = b1 + l * HIDc; gp.bf_out = p1buf;
    gp.Wtb = W1bS + (size_t)l * T2 * 1024 * 8; gp.biasb = zerobias; gp.bf_outb = p2buf;
    gp.Abf = s_ln; gp.dual = 1;
    gemm_k<MODE_LIN, SRC_BF16, 256><<<2 * NN / 64, 256, 0, stream>>>(gp);

    // fused edge kernel: h + out2
    FusedArgs gf{};
    gf.W1e = W1eS + (size_t)l * TE * 1024 * 8;
    gf.W2s = W2sS + (size_t)l * T2 * 1024 * 8;
    gf.b2L = b2 + l * DOUTc;
    gf.src = srcp; gf.tgt = tgtp; gf.e_bf = ebf; gf.tail = tailb;
    gf.p1 = p1buf; gf.p2 = p2buf; gf.w384 = w384 + l * HIDc;
    gf.rn = rnbuf; gf.mp = mpbuf;
    gf.h_out = hbuf; gf.wv_out = wvbuf; gf.e_bf_out = ebf; gf.e_f32_out = e_o;
    gf.write_e_f32 = (l == NL - 1) ? 1 : 0;
    fused_k<<<NE / 64, 256, 0, stream>>>(gf);

    // pre-update v snapshot (messages read v[src] from BEFORE this layer's update)
    hipMemcpyAsync(vprev, v_o, (size_t)NN * 192 * 4, hipMemcpyDeviceToDevice, stream);

    agg_k<<<NN, 256, 0, stream>>>(offb, eperm, srcp, hbuf, wvbuf, mpbuf, rnbuf, vprev,
                                  Hagg, v_o, p_o, (l > 0) ? 1 : 0);

    GemmArgs g3{};
    g3.Wt = W2aS + (size_t)l * T2 * 1024 * 8; g3.bias = b2 + l * DOUTc;
    g3.Af32 = Hagg; g3.s_out = s_o; g3.rawcnt = rawcnt;
    gemm_k<MODE_SADD, SRC_F32, 256><<<NN / 64, 256, 0, stream>>>(g3);

    if (l < NL - 1) {
      GemmArgs g4{};
      g4.Wt = U1S + (size_t)l * T2 * 1024 * 8; g4.bias = bU1 + l * HIDc;
      g4.Af32 = s_o; g4.bf_out = tbuf;
      gemm_k<MODE_H, SRC_F32, 256><<<NN / 64, 256, 0, stream>>>(g4);

      GemmArgs g5{};
      g5.Wt = U2S + (size_t)l * T2 * 1024 * 8; g5.bias = bU2 + l * HIDc;
      g5.Abf = tbuf; g5.s_out = s_o;
      gemm_k<MODE_SADD2, SRC_BF16, 256><<<NN / 64, 256, 0, stream>>>(g5);
    }
  }
}

// Round 8
// 1381.717 us; speedup vs baseline: 2.6679x; 1.1626x over previous
//
#include <hip/hip_runtime.h>
#include <hip/hip_bf16.h>

namespace {

constexpr int NN   = 8192;    // nodes
constexpr int NE   = 131072;  // edges
constexpr int SD   = 256;     // SDIM
constexpr int ED   = 128;     // EDIM
constexpr int NL   = 5;       // layers
constexpr int DINc = 644;     // 2*SD + ED + 4
constexpr int KE   = 160;     // edge-GEMM K: 128 e + 4 scalars + pad
constexpr int TE   = 5;       // KE/32
constexpr int T2   = 8;       // 256/32
constexpr int DOUTc= 513;
constexpr int HIDc = 256;

typedef __bf16 bf16x8 __attribute__((ext_vector_type(8)));
typedef float  f32x4  __attribute__((ext_vector_type(4)));

__device__ __forceinline__ float siluf(float x) { return x / (1.0f + __expf(-x)); }

// async global->LDS, 16B/lane. LDS dest is wave-uniform base (+lane*16 in HW).
__device__ __forceinline__ void gl_lds16(const void* gsrc, void* lds_uniform_base) {
  __builtin_amdgcn_global_load_lds(
      (const __attribute__((address_space(1))) unsigned int*)gsrc,
      (__attribute__((address_space(3))) unsigned int*)lds_uniform_base, 16, 0, 0);
}

// counted-vmcnt waits (immediates must be literal)
__device__ __forceinline__ void wait_vm4() {
  asm volatile("s_waitcnt vmcnt(4)" ::: "memory");
  __builtin_amdgcn_sched_barrier(0);
}
__device__ __forceinline__ void wait_vm0() {
  asm volatile("s_waitcnt vmcnt(0)" ::: "memory");
  __builtin_amdgcn_sched_barrier(0);
}

// bank-group swizzle: XOR set {0,5,2,7} -> write AND read phases conflict-light.
__device__ __host__ __forceinline__ int swz(int kc) { return (kc * 5) & 7; }
__device__ __forceinline__ int apos(int kc, int row) { return kc * 64  + (row ^ swz(kc)); }
__device__ __forceinline__ int bpos(int kc, int n)   { return kc * 256 + (n   ^ swz(kc)); }

enum { MODE_H = 0, MODE_SADD = 2, MODE_SADD2 = 3, MODE_LIN = 4 };
enum { SRC_BF16 = 1, SRC_F32 = 2 };

struct GemmArgs {
  const __hip_bfloat16* Wt;     // swizzled B stream: [T][1024 chunks][8 bf16]
  const float* bias;
  const __hip_bfloat16* Abf;    // SRC_BF16 source, [M][K]
  const float* Af32;            // SRC_F32 source, [M][K]
  __hip_bfloat16* bf_out;
  float* s_out;                 // d_out s region (RMW)
  const int* rawcnt;
  // dual-launch (MODE_LIN): second half of grid uses these
  const __hip_bfloat16* Wtb;
  const float* biasb;
  __hip_bfloat16* bf_outb;
  int dual;
};

__device__ __forceinline__ uint4 cvt8f(const float* p) {
  alignas(16) __hip_bfloat16 t8[8];
#pragma unroll
  for (int i = 0; i < 8; i++) t8[i] = __float2bfloat16(p[i]);
  return *(const uint4*)t8;
}

// BM=64, BN=256, 4 waves, acc[4][4]. A-panel staged ONCE (32KB), then a
// BARRIER-FREE K-loop: B stream is wave-private in LDS (each wave writes and
// reads only its own 64-chunk slice), so only per-wave counted vmcnt is needed.
template<int MODE, int SRC, int KTOT>
__global__ __launch_bounds__(256) void gemm_k(GemmArgs g) {
  constexpr int T = KTOT / 32;
  constexpr int NC = KTOT / 8;            // chunks per row (32 for K=256)
  __shared__ alignas(16) unsigned short Apan[NC * 64 * 8];      // 32 KB
  __shared__ alignas(16) unsigned short Bsh[2][4 * 256 * 8];    // 32 KB
  const int tid = threadIdx.x, lane = tid & 63, wave = tid >> 6;
  const int l16 = lane & 15, lhi = lane >> 4;
  const __hip_bfloat16* wtp = g.Wt;
  const float* biasp = g.bias;
  __hip_bfloat16* outp = g.bf_out;
  int blk = blockIdx.x;
  if constexpr (MODE == MODE_LIN) {
    const int half = gridDim.x >> 1;
    if (g.dual && blk >= half) { blk -= half; wtp = g.Wtb; biasp = g.biasb; outp = g.bf_outb; }
  }
  const int row0 = blk * 64;
  const int ar = tid >> 2, aq = tid & 3;
  const int arow = row0 + ar;
  f32x4 acc[4][4] = {};

  auto issueB = [&](int t, int buf) {
    const __hip_bfloat16* src = wtp + (size_t)t * 1024 * 8;
    unsigned short* dst = &Bsh[buf][0];
#pragma unroll
    for (int i = 0; i < 4; i++)
      gl_lds16(src + (size_t)(i * 256 + wave * 64 + lane) * 8, dst + (i * 256 + wave * 64) * 8);
  };

  issueB(0, 0);
  // ---- stage whole A panel once: chunk c = j*4+aq of row ar
#pragma unroll
  for (int j = 0; j < NC / 4; j++) {
    const int c = j * 4 + aq;
    uint4 o;
    if constexpr (SRC == SRC_BF16) o = *(const uint4*)(g.Abf + (size_t)arow * KTOT + c * 8);
    else                           o = cvt8f(g.Af32 + (size_t)arow * KTOT + c * 8);
    *(uint4*)&Apan[(c * 64 + (ar ^ swz(aq))) * 8] = o;
  }
  __syncthreads();   // A panel visible; B(0) landed (barrier drains vmcnt)

  int cur = 0;
  for (int t = 0; t < T; ++t) {
    if (t + 1 < T) { issueB(t + 1, cur ^ 1); wait_vm4(); }
    else           { wait_vm0(); }
    bf16x8 afr[4], bfr[4];
#pragma unroll
    for (int f = 0; f < 4; f++) {
      const int kc = t * 4 + lhi;          // kc & 3 == lhi
      afr[f] = *(const bf16x8*)&Apan[(kc * 64 + ((f * 16 + l16) ^ swz(lhi))) * 8];
      bfr[f] = *(const bf16x8*)&Bsh[cur][bpos(lhi, wave * 64 + f * 16 + l16) * 8];
    }
#pragma unroll
    for (int fr = 0; fr < 4; fr++)
#pragma unroll
      for (int fc = 0; fc < 4; fc++)
        acc[fr][fc] = __builtin_amdgcn_mfma_f32_16x16x32_bf16(afr[fr], bfr[fc], acc[fr][fc], 0, 0, 0);
    cur ^= 1;
  }

  // ---- epilogue: D[row = 4*(lane>>4)+r][col = lane&15] per 16x16 tile
#pragma unroll
  for (int fr = 0; fr < 4; fr++) {
#pragma unroll
    for (int fc = 0; fc < 4; fc++) {
      const int n = wave * 64 + fc * 16 + l16;
#pragma unroll
      for (int r = 0; r < 4; r++) {
        const int row = row0 + fr * 16 + lhi * 4 + r;
        const float valf = acc[fr][fc][r];
        if constexpr (MODE == MODE_H) {
          outp[(size_t)row * HIDc + n] = __float2bfloat16(siluf(valf + biasp[n]));
        } else if constexpr (MODE == MODE_LIN) {
          outp[(size_t)row * HIDc + n] = __float2bfloat16(valf + biasp[n]);
        } else if constexpr (MODE == MODE_SADD) {
          const float rc = (float)g.rawcnt[row];
          g.s_out[(size_t)row * SD + n] += valf + rc * biasp[n];
        } else {  // MODE_SADD2
          g.s_out[(size_t)row * SD + n] += valf + biasp[n];
        }
      }
    }
  }
}

// ==== fused edge kernel: h = silu([e|tail]@W1e + P1[src] + P2[tgt]); out2 = h@W2s ====
struct FusedArgs {
  const __hip_bfloat16* W1e;    // [TE][1024][8] swizzled stream
  const __hip_bfloat16* W2s;    // [T2][1024][8] swizzled stream
  const float* b2L;             // b2 + l*DOUT
  const int* src; const int* tgt;
  const __hip_bfloat16* e_bf;   // [NE][128]  (in; overwritten with new e in epilogue-2)
  const __hip_bfloat16* tail;   // [NE][32]
  const __hip_bfloat16* p1;     // [NN][256]
  const __hip_bfloat16* p2;     // [NN][256]
  const __hip_bfloat16* w384;   // [256]
  const float* rn;              // [NE][3]
  float* mp;                    // [NE][3] out
  __hip_bfloat16* h_out;        // [NE][256]
  __hip_bfloat16* wv_out;       // [NE][128]
  __hip_bfloat16* e_bf_out;     // [NE][128]
  float* e_f32_out;             // d_out e region
  int write_e_f32;
};

__global__ __launch_bounds__(256) void fused_k(FusedArgs g) {
  __shared__ alignas(16) unsigned short Ash[4 * 64 * 8];        // 4 KB (edge A)
  __shared__ alignas(16) unsigned short Bsh[2][4 * 256 * 8];    // 32 KB (W stream dbuf)
  __shared__ alignas(16) unsigned short Hsh[32 * 64 * 8];       // 32 KB (psum -> h)
  __shared__ float wps[4][64];
  const int tid = threadIdx.x, lane = tid & 63, wave = tid >> 6;
  const int l16 = lane & 15, lhi = lane >> 4;
  const int row0 = blockIdx.x * 64;
  const int ar = tid >> 2, aq = tid & 3;
  const int arow = row0 + ar;
  const int sn = g.src[arow], tn = g.tgt[arow];

  auto issueW = [&](const __hip_bfloat16* W, int t, int buf) {
    const __hip_bfloat16* src = W + (size_t)t * 1024 * 8;
    unsigned short* dst = &Bsh[buf][0];
#pragma unroll
    for (int i = 0; i < 4; i++)
      gl_lds16(src + (size_t)(i * 256 + wave * 64 + lane) * 8, dst + (i * 256 + wave * 64) * 8);
  };
  auto loadA = [&](int t, uint4& o) {
    const int kq = t * 32 + aq * 8;
    if (kq < 128) o = *(const uint4*)(g.e_bf + (size_t)arow * ED + kq);
    else          o = *(const uint4*)(g.tail + (size_t)arow * 32 + (kq - 128));
  };

  uint4 a;
  loadA(0, a);
  issueW(g.W1e, 0, 0);

  // ---- stage Psum = P1[sn] + P2[tn] into Hsh [32 kc][64 row][8]; chunk c = j*4+aq
#pragma unroll
  for (int j = 0; j < 8; j++) {
    const int c = j * 4 + aq;            // c & 3 == aq
    uint4 r1 = *(const uint4*)(g.p1 + (size_t)sn * SD + c * 8);
    uint4 r2 = *(const uint4*)(g.p2 + (size_t)tn * SD + c * 8);
    const __hip_bfloat16* h1 = (const __hip_bfloat16*)&r1;
    const __hip_bfloat16* h2 = (const __hip_bfloat16*)&r2;
    alignas(16) __hip_bfloat16 o8[8];
#pragma unroll
    for (int m = 0; m < 8; m++)
      o8[m] = __float2bfloat16(__bfloat162float(h1[m]) + __bfloat162float(h2[m]));
    *(uint4*)&Hsh[(c * 64 + (ar ^ swz(aq))) * 8] = *(const uint4*)o8;
  }

  // ---- phase 1: SWAPPED operands -> D[n][row] (thread holds 4 consecutive n per row)
  f32x4 acc1[4][4] = {};
  int cur = 0;
  for (int t = 0; t < TE; ++t) {
    *(uint4*)&Ash[apos(aq, ar) * 8] = a;
    __syncthreads();
    if (t + 1 < TE) { issueW(g.W1e, t + 1, cur ^ 1); loadA(t + 1, a); }
    bf16x8 wfr[4], efr[4];
#pragma unroll
    for (int f = 0; f < 4; f++) {
      wfr[f] = *(const bf16x8*)&Bsh[cur][bpos(lhi, wave * 64 + f * 16 + l16) * 8];
      efr[f] = *(const bf16x8*)&Ash[apos(lhi, f * 16 + l16) * 8];
    }
#pragma unroll
    for (int fr = 0; fr < 4; fr++)
#pragma unroll
      for (int fc = 0; fc < 4; fc++)
        acc1[fr][fc] = __builtin_amdgcn_mfma_f32_16x16x32_bf16(wfr[fr], efr[fc], acc1[fr][fc], 0, 0, 0);
    __syncthreads();
    cur ^= 1;
  }

  issueW(g.W2s, 0, 0);   // prefetch phase-2 B step 0 under the epilogue

  // ---- epilogue-1: h = silu(acc1 + psum); Hsh in-place; global h; wp partials
  float pw[4] = {0.f, 0.f, 0.f, 0.f};
#pragma unroll
  for (int fr = 0; fr < 4; fr++) {
    const int nb = wave * 64 + fr * 16 + lhi * 4;   // n base (4-aligned)
    const int kc = nb >> 3, off = nb & 7;
    uint2 wr = *(const uint2*)(g.w384 + nb);
    const __hip_bfloat16* w4 = (const __hip_bfloat16*)&wr;
#pragma unroll
    for (int fc = 0; fc < 4; fc++) {
      const int row = fc * 16 + l16;
      unsigned short* slot = &Hsh[(kc * 64 + (row ^ swz(kc & 3))) * 8 + off];
      uint2 pr = *(const uint2*)slot;
      const __hip_bfloat16* ps = (const __hip_bfloat16*)&pr;
      alignas(8) __hip_bfloat16 hb[4];
#pragma unroll
      for (int r = 0; r < 4; r++) {
        const float hv = siluf(acc1[fr][fc][r] + __bfloat162float(ps[r]));
        hb[r] = __float2bfloat16(hv);
        pw[fc] += hv * __bfloat162float(w4[r]);
      }
      *(uint2*)slot = *(const uint2*)hb;
      *(uint2*)(g.h_out + (size_t)(row0 + row) * HIDc + nb) = *(const uint2*)hb;
    }
  }
  __syncthreads();   // h visible to all

  // ---- wp reduce: sum over lhi (lanes +16,+32), then across waves via LDS
#pragma unroll
  for (int fc = 0; fc < 4; fc++) {
    pw[fc] += __shfl_xor(pw[fc], 16);
    pw[fc] += __shfl_xor(pw[fc], 32);
  }
  if (lane < 16) {
#pragma unroll
    for (int fc = 0; fc < 4; fc++) wps[wave][fc * 16 + lane] = pw[fc];
  }
  __syncthreads();
  if (tid < 64) {
    const float s = wps[0][tid] + wps[1][tid] + wps[2][tid] + wps[3][tid];
    const float wpt = tanhf(s + g.b2L[384]);
#pragma unroll
    for (int c = 0; c < 3; c++)
      g.mp[(size_t)(row0 + tid) * 3 + c] = wpt * g.rn[(size_t)(row0 + tid) * 3 + c];
  }

  // ---- phase 2: out2 = h @ W2s. BARRIER-FREE: Hsh static, B wave-private,
  // counted vmcnt keeps next step's loads in flight across the step.
  f32x4 acc2[4][4] = {};
  cur = 0;
  for (int t = 0; t < T2; ++t) {
    if (t + 1 < T2) { issueW(g.W2s, t + 1, cur ^ 1); wait_vm4(); }
    else            { wait_vm0(); }
    bf16x8 afr[4], bfr[4];
#pragma unroll
    for (int f = 0; f < 4; f++) {
      const int kc = t * 4 + lhi;        // kc & 3 == lhi
      afr[f] = *(const bf16x8*)&Hsh[(kc * 64 + ((f * 16 + l16) ^ swz(lhi))) * 8];
      bfr[f] = *(const bf16x8*)&Bsh[cur][bpos(lhi, wave * 64 + f * 16 + l16) * 8];
    }
#pragma unroll
    for (int fr = 0; fr < 4; fr++)
#pragma unroll
      for (int fc = 0; fc < 4; fc++)
        acc2[fr][fc] = __builtin_amdgcn_mfma_f32_16x16x32_bf16(afr[fr], bfr[fc], acc2[fr][fc], 0, 0, 0);
    cur ^= 1;
  }

  // ---- epilogue-2: wv | e_new
#pragma unroll
  for (int fr = 0; fr < 4; fr++) {
#pragma unroll
    for (int fc = 0; fc < 4; fc++) {
      const int n = wave * 64 + fc * 16 + l16;
#pragma unroll
      for (int r = 0; r < 4; r++) {
        const int row = row0 + fr * 16 + lhi * 4 + r;
        const float valf = acc2[fr][fc][r];
        if (n < 128) {
          g.wv_out[(size_t)row * 128 + n] = __float2bfloat16(valf + g.b2L[256 + n]);
        } else {
          const float sv = siluf(valf + g.b2L[257 + n]);   // e_new cols = W2 cols 385..512
          g.e_bf_out[(size_t)row * ED + (n - 128)] = __float2bfloat16(sv);
          if (g.write_e_f32) g.e_f32_out[(size_t)row * ED + (n - 128)] = sv;
        }
      }
    }
  }
}

// ---- LayerNorm. 4 nodes/block, wave per node.
__global__ __launch_bounds__(256) void ln_k(const float* __restrict__ s,
                                            const float* __restrict__ gl, const float* __restrict__ bl,
                                            __hip_bfloat16* __restrict__ s_ln) {
  const int wave = threadIdx.x >> 6, lane = threadIdx.x & 63;
  const int node = blockIdx.x * 4 + wave;
  const float* srow = s + (size_t)node * SD;
  float x[4], sum = 0.f, sq = 0.f;
#pragma unroll
  for (int i = 0; i < 4; i++) { x[i] = srow[lane * 4 + i]; sum += x[i]; sq += x[i] * x[i]; }
#pragma unroll
  for (int off = 1; off < 64; off <<= 1) { sum += __shfl_xor(sum, off); sq += __shfl_xor(sq, off); }
  const float mu = sum * (1.0f / SD);
  const float var = sq * (1.0f / SD) - mu * mu;
  const float rstd = rsqrtf(var + 1e-5f);
#pragma unroll
  for (int i = 0; i < 4; i++) {
    const int c = lane * 4 + i;
    s_ln[(size_t)node * SD + c] = __float2bfloat16(gl[c] * (x[i] - mu) * rstd + bl[c]);
  }
}

// ---- per-edge attrs: rn + bf16 tail block [NE][32] = {d,a,pn_src,pn_tgt,0,...}
__global__ void edge_attr_k(const float* __restrict__ p, const int* __restrict__ src, const int* __restrict__ tgt,
                            float* __restrict__ rn, __hip_bfloat16* __restrict__ tail) {
  const int e = blockIdx.x * blockDim.x + threadIdx.x;
  if (e >= NE) return;
  const int s_ = src[e], t_ = tgt[e];
  const float sx = p[s_ * 3], sy = p[s_ * 3 + 1], sz = p[s_ * 3 + 2];
  const float tx = p[t_ * 3], ty = p[t_ * 3 + 1], tz = p[t_ * 3 + 2];
  const float rx = tx - sx, ry = ty - sy, rz = tz - sz;
  const float a = tx * sx + ty * sy + tz * sz;
  const float rr = rx * rx + ry * ry + rz * rz;
  const float d = sqrtf(fmaxf(rr, 1e-6f));
  const float inv = 1.0f / (1.0f + d);
  rn[e * 3] = rx * inv; rn[e * 3 + 1] = ry * inv; rn[e * 3 + 2] = rz * inv;
  alignas(16) __hip_bfloat16 t8[8];
  t8[0] = __float2bfloat16(d);
  t8[1] = __float2bfloat16(a);
  t8[2] = __float2bfloat16(sqrtf(sx * sx + sy * sy + sz * sz));
  t8[3] = __float2bfloat16(sqrtf(tx * tx + ty * ty + tz * tz));
  t8[4] = t8[5] = t8[6] = t8[7] = __float2bfloat16(0.0f);
  __hip_bfloat16* tp = tail + (size_t)e * 32;
  uint4 z; z.x = z.y = z.z = z.w = 0;
  *(uint4*)tp = *(const uint4*)t8;
  *(uint4*)(tp + 8) = z;
  *(uint4*)(tp + 16) = z;
  *(uint4*)(tp + 24) = z;
}

__global__ void cvt_e_k(const float* __restrict__ e, __hip_bfloat16* __restrict__ ebf) {
  const int i = blockIdx.x * blockDim.x + threadIdx.x;
  const float* p = e + (size_t)i * 8;
  alignas(16) __hip_bfloat16 t8[8];
#pragma unroll
  for (int j = 0; j < 8; j++) t8[j] = __float2bfloat16(p[j]);
  *(uint4*)(ebf + (size_t)i * 8) = *(const uint4*)t8;
}

__global__ void count_k(const int* __restrict__ tgt, int* __restrict__ rawcnt) {
  const int e = blockIdx.x * blockDim.x + threadIdx.x;
  if (e < NE) atomicAdd(&rawcnt[tgt[e]], 1);
}

__global__ __launch_bounds__(256) void scan_k(const int* __restrict__ rawcnt, int* __restrict__ off) {
  __shared__ int ts[256];
  const int tid = threadIdx.x;
  const int base = tid * 32;
  int local[32];
  int s = 0;
#pragma unroll
  for (int i = 0; i < 32; i++) { local[i] = s; s += rawcnt[base + i]; }
  ts[tid] = s;
  __syncthreads();
  if (tid == 0) {
    int acc = 0;
    for (int i = 0; i < 256; i++) { int t = ts[i]; ts[i] = acc; acc += t; }
    off[NN] = acc;
  }
  __syncthreads();
  const int pre = ts[tid];
#pragma unroll
  for (int i = 0; i < 32; i++) off[base + i] = pre + local[i];
}

__global__ void scatter_k(const int* __restrict__ tgt, const int* __restrict__ off,
                          int* __restrict__ cursor, int* __restrict__ eperm) {
  const int e = blockIdx.x * blockDim.x + threadIdx.x;
  if (e < NE) {
    const int t = tgt[e];
    const int r = atomicAdd(&cursor[t], 1);
    eperm[off[t] + r] = e;
  }
}

// ---- CSR aggregation: one block (256 thr) per node. Zero atomics.
__global__ __launch_bounds__(256) void agg_k(const int* __restrict__ off, const int* __restrict__ eperm,
                                             const int* __restrict__ srcp,
                                             const __hip_bfloat16* __restrict__ h,
                                             const __hip_bfloat16* __restrict__ wv,
                                             const float* __restrict__ mp,
                                             const float* __restrict__ rn,
                                             const float* __restrict__ vprev,
                                             float* __restrict__ Hagg,
                                             float* __restrict__ v_o, float* __restrict__ p_o,
                                             int hasv) {
  const int n = blockIdx.x;
  const int c = threadIdx.x;
  const int e0 = off[n], e1 = off[n + 1];
  const int c3 = c >> 6, ln = c & 63;
  float hs = 0.f, vs = 0.f, ps = 0.f;
  for (int j = e0; j < e1; j++) {
    const int e = eperm[j];
    hs += __bfloat162float(h[(size_t)e * HIDc + c]);
    if (c < 192) {
      float mv = __bfloat162float(wv[(size_t)e * 128 + 64 + ln]) * rn[(size_t)e * 3 + c3];
      if (hasv) mv += __bfloat162float(wv[(size_t)e * 128 + ln]) * vprev[(size_t)srcp[e] * 192 + c];
      vs += mv;
    } else if (c < 195) {
      ps += mp[(size_t)e * 3 + (c - 192)];
    }
  }
  Hagg[(size_t)n * HIDc + c] = hs;
  const float inv = 1.0f / fmaxf((float)(e1 - e0), 1.0f);
  if (c < 192)      v_o[(size_t)n * 192 + c] += vs * inv;
  else if (c < 195) p_o[n * 3 + (c - 192)]   += ps * inv;
}

__global__ void zero_k(float* __restrict__ ptr, int n) {
  const int i = blockIdx.x * blockDim.x + threadIdx.x;
  if (i < n) ptr[i] = 0.f;
}

// ---- weight prep -> swizzled streams: chunk p of k-step t holds
// W^T[n][t*32 + kc*8 .. +8) with kc = p>>8, n = (p&255) ^ swz(kc).
__global__ void prep_w1abs_k(const float* __restrict__ W1, __hip_bfloat16* __restrict__ W1aS,
                             __hip_bfloat16* __restrict__ W1bS) {
  const int idx = blockIdx.x * blockDim.x + threadIdx.x;
  if (idx >= NL * T2 * 1024) return;
  const int p = idx & 1023, t = (idx >> 10) % T2, l = idx / (T2 * 1024);
  const int kc = p >> 8, n = (p & 255) ^ swz(kc);
  alignas(16) __hip_bfloat16 a8[8], b8[8];
#pragma unroll
  for (int j = 0; j < 8; j++) {
    const int k = t * 32 + kc * 8 + j;   // 0..255
    a8[j] = __float2bfloat16(W1[((size_t)l * DINc + k) * HIDc + n]);
    b8[j] = __float2bfloat16(W1[((size_t)l * DINc + 256 + k) * HIDc + n]);
  }
  *(uint4*)(W1aS + (size_t)idx * 8) = *(const uint4*)a8;
  *(uint4*)(W1bS + (size_t)idx * 8) = *(const uint4*)b8;
}

__global__ void prep_w1es_k(const float* __restrict__ W1, __hip_bfloat16* __restrict__ W1eS) {
  const int idx = blockIdx.x * blockDim.x + threadIdx.x;
  if (idx >= NL * TE * 1024) return;
  const int p = idx & 1023, t = (idx >> 10) % TE, l = idx / (TE * 1024);
  const int kc = p >> 8, n = (p & 255) ^ swz(kc);
  alignas(16) __hip_bfloat16 e8[8];
#pragma unroll
  for (int j = 0; j < 8; j++) {
    const int k = t * 32 + kc * 8 + j;   // 0..159
    const int row = (k < 128) ? (512 + k) : ((k < 132) ? (640 + (k - 128)) : -1);
    e8[j] = __float2bfloat16(row >= 0 ? W1[((size_t)l * DINc + row) * HIDc + n] : 0.f);
  }
  *(uint4*)(W1eS + (size_t)idx * 8) = *(const uint4*)e8;
}

__global__ void prep_w2s_k(const float* __restrict__ W2, __hip_bfloat16* __restrict__ W2sS,
                           __hip_bfloat16* __restrict__ W2aS) {
  const int idx = blockIdx.x * blockDim.x + threadIdx.x;
  if (idx >= NL * T2 * 1024) return;
  const int p = idx & 1023, t = (idx >> 10) & 7, l = idx >> 13;
  const int kc = p >> 8, n = (p & 255) ^ swz(kc);
  const float* W2l = W2 + (size_t)l * HIDc * DOUTc;
  const int cs = (n < 128) ? (256 + n) : (257 + n);  // wv1|wv2 then e_new (skip col 384)
  alignas(16) __hip_bfloat16 s8[8], a8[8];
#pragma unroll
  for (int j = 0; j < 8; j++) {
    const int k = t * 32 + kc * 8 + j;
    s8[j] = __float2bfloat16(W2l[(size_t)k * DOUTc + cs]);
    a8[j] = __float2bfloat16(W2l[(size_t)k * DOUTc + n]);
  }
  *(uint4*)(W2sS + (size_t)idx * 8) = *(const uint4*)s8;
  *(uint4*)(W2aS + (size_t)idx * 8) = *(const uint4*)a8;
}

__global__ void prep_uts_k(const float* __restrict__ U1, const float* __restrict__ U2,
                           __hip_bfloat16* __restrict__ U1S, __hip_bfloat16* __restrict__ U2S) {
  const int idx = blockIdx.x * blockDim.x + threadIdx.x;
  if (idx >= NL * T2 * 1024) return;
  const int p = idx & 1023, t = (idx >> 10) & 7, l = idx >> 13;
  const int kc = p >> 8, n = (p & 255) ^ swz(kc);
  alignas(16) __hip_bfloat16 u1[8], u2[8];
#pragma unroll
  for (int j = 0; j < 8; j++) {
    const int k = t * 32 + kc * 8 + j;
    u1[j] = __float2bfloat16(U1[((size_t)l * HIDc + k) * HIDc + n]);
    u2[j] = __float2bfloat16(U2[((size_t)l * HIDc + k) * HIDc + n]);
  }
  *(uint4*)(U1S + (size_t)idx * 8) = *(const uint4*)u1;
  *(uint4*)(U2S + (size_t)idx * 8) = *(const uint4*)u2;
}

__global__ void prep_w384_k(const float* __restrict__ W2, __hip_bfloat16* __restrict__ w384) {
  const int idx = blockIdx.x * blockDim.x + threadIdx.x;
  if (idx >= NL * HIDc) return;
  const int k = idx & 255, l = idx >> 8;
  w384[idx] = __float2bfloat16(W2[((size_t)l * HIDc + k) * DOUTc + 384]);
}

}  // namespace

extern "C" void kernel_launch(void* const* d_in, const int* in_sizes, int n_in,
                              void* d_out, int out_size, void* d_ws, size_t ws_size,
                              hipStream_t stream) {
  (void)in_sizes; (void)n_in; (void)out_size; (void)ws_size;
  const float* s_in = (const float*)d_in[0];
  const float* v_in = (const float*)d_in[1];
  const float* p_in = (const float*)d_in[2];
  const float* e_in = (const float*)d_in[3];
  const int*   ei   = (const int*)d_in[4];
  const float* ln_g = (const float*)d_in[5];
  const float* ln_b = (const float*)d_in[6];
  const float* W1   = (const float*)d_in[7];
  const float* b1   = (const float*)d_in[8];
  const float* W2   = (const float*)d_in[9];
  const float* b2   = (const float*)d_in[10];
  const float* U1   = (const float*)d_in[11];
  const float* bU1  = (const float*)d_in[12];
  const float* U2   = (const float*)d_in[13];
  const float* bU2  = (const float*)d_in[14];

  float* s_o = (float*)d_out;
  float* v_o = s_o + (size_t)NN * SD;
  float* e_o = v_o + (size_t)NN * 192;
  float* p_o = e_o + (size_t)NE * ED;

  const int* srcp = ei;
  const int* tgtp = ei + NE;

  char* wp = (char*)d_ws;
  auto alloc = [&](size_t bytes) -> char* {
    char* r = wp; wp += (bytes + 255) & ~(size_t)255; return r;
  };
  __hip_bfloat16* s_ln = (__hip_bfloat16*)alloc((size_t)NN * SD * 2);
  __hip_bfloat16* hbuf = (__hip_bfloat16*)alloc((size_t)NE * HIDc * 2);
  __hip_bfloat16* ebf  = (__hip_bfloat16*)alloc((size_t)NE * ED * 2);
  __hip_bfloat16* tbuf = (__hip_bfloat16*)alloc((size_t)NN * HIDc * 2);
  __hip_bfloat16* wvbuf= (__hip_bfloat16*)alloc((size_t)NE * 128 * 2);
  __hip_bfloat16* tailb= (__hip_bfloat16*)alloc((size_t)NE * 32 * 2);
  __hip_bfloat16* p1buf= (__hip_bfloat16*)alloc((size_t)NN * SD * 2);
  __hip_bfloat16* p2buf= (__hip_bfloat16*)alloc((size_t)NN * SD * 2);
  float* rnbuf = (float*)alloc((size_t)NE * 3 * 4);
  float* Hagg  = (float*)alloc((size_t)NN * SD * 4);
  float* vprev = (float*)alloc((size_t)NN * 192 * 4);
  float* mpbuf = (float*)alloc((size_t)NE * 3 * 4);
  float* zerobias = (float*)alloc(256 * 4);
  int*   rawcnt= (int*)alloc((size_t)NN * 4);
  int*   offb  = (int*)alloc((size_t)(NN + 1) * 4);
  int*   cursor= (int*)alloc((size_t)NN * 4);
  int*   eperm = (int*)alloc((size_t)NE * 4);
  __hip_bfloat16* W1aS = (__hip_bfloat16*)alloc((size_t)NL * T2 * 1024 * 8 * 2);
  __hip_bfloat16* W1bS = (__hip_bfloat16*)alloc((size_t)NL * T2 * 1024 * 8 * 2);
  __hip_bfloat16* W1eS = (__hip_bfloat16*)alloc((size_t)NL * TE * 1024 * 8 * 2);
  __hip_bfloat16* W2sS = (__hip_bfloat16*)alloc((size_t)NL * T2 * 1024 * 8 * 2);
  __hip_bfloat16* W2aS = (__hip_bfloat16*)alloc((size_t)NL * T2 * 1024 * 8 * 2);
  __hip_bfloat16* U1S  = (__hip_bfloat16*)alloc((size_t)NL * T2 * 1024 * 8 * 2);
  __hip_bfloat16* U2S  = (__hip_bfloat16*)alloc((size_t)NL * T2 * 1024 * 8 * 2);
  __hip_bfloat16* w384 = (__hip_bfloat16*)alloc((size_t)NL * HIDc * 2);

  hipMemcpyAsync(s_o, s_in, (size_t)NN * SD * 4, hipMemcpyDeviceToDevice, stream);
  hipMemcpyAsync(v_o, v_in, (size_t)NN * 192 * 4, hipMemcpyDeviceToDevice, stream);
  hipMemcpyAsync(p_o, p_in, (size_t)NN * 3 * 4, hipMemcpyDeviceToDevice, stream);

  prep_w1abs_k<<<(NL * T2 * 1024 + 255) / 256, 256, 0, stream>>>(W1, W1aS, W1bS);
  prep_w1es_k<<<(NL * TE * 1024 + 255) / 256, 256, 0, stream>>>(W1, W1eS);
  prep_w2s_k<<<(NL * T2 * 1024 + 255) / 256, 256, 0, stream>>>(W2, W2sS, W2aS);
  prep_uts_k<<<(NL * T2 * 1024 + 255) / 256, 256, 0, stream>>>(U1, U2, U1S, U2S);
  prep_w384_k<<<(NL * HIDc + 255) / 256, 256, 0, stream>>>(W2, w384);
  cvt_e_k<<<NE * ED / 8 / 256, 256, 0, stream>>>(e_in, ebf);
  zero_k<<<1, 256, 0, stream>>>(zerobias, 256);

  // ---- CSR build (once; edge_index layer-invariant)
  zero_k<<<(NN + 255) / 256, 256, 0, stream>>>((float*)rawcnt, NN);
  zero_k<<<(NN + 255) / 256, 256, 0, stream>>>((float*)cursor, NN);
  count_k<<<NE / 256, 256, 0, stream>>>(tgtp, rawcnt);
  scan_k<<<1, 256, 0, stream>>>(rawcnt, offb);
  scatter_k<<<NE / 256, 256, 0, stream>>>(tgtp, offb, cursor, eperm);

  for (int l = 0; l < NL; l++) {
    ln_k<<<NN / 4, 256, 0, stream>>>(s_o, ln_g + l * SD, ln_b + l * SD, s_ln);
    edge_attr_k<<<NE / 256, 256, 0, stream>>>(p_o, srcp, tgtp, rnbuf, tailb);

    // P1 = s_ln @ W1a + b1 ; P2 = s_ln @ W1b  (single dual launch, 256 blocks)
    GemmArgs gp{};
    gp.Wt = W1aS + (size_t)l * T2 * 1024 * 8; gp.bias = b1 + l * HIDc; gp.bf_out = p1buf;
    gp.Wtb = W1bS + (size_t)l * T2 * 1024 * 8; gp.biasb = zerobias; gp.bf_outb = p2buf;
    gp.Abf = s_ln; gp.dual = 1;
    gemm_k<MODE_LIN, SRC_BF16, 256><<<2 * NN / 64, 256, 0, stream>>>(gp);

    // fused edge kernel: h + out2
    FusedArgs gf{};
    gf.W1e = W1eS + (size_t)l * TE * 1024 * 8;
    gf.W2s = W2sS + (size_t)l * T2 * 1024 * 8;
    gf.b2L = b2 + l * DOUTc;
    gf.src = srcp; gf.tgt = tgtp; gf.e_bf = ebf; gf.tail = tailb;
    gf.p1 = p1buf; gf.p2 = p2buf; gf.w384 = w384 + l * HIDc;
    gf.rn = rnbuf; gf.mp = mpbuf;
    gf.h_out = hbuf; gf.wv_out = wvbuf; gf.e_bf_out = ebf; gf.e_f32_out = e_o;
    gf.write_e_f32 = (l == NL - 1) ? 1 : 0;
    fused_k<<<NE / 64, 256, 0, stream>>>(gf);

    // pre-update v snapshot (messages read v[src] from BEFORE this layer's update)
    hipMemcpyAsync(vprev, v_o, (size_t)NN * 192 * 4, hipMemcpyDeviceToDevice, stream);

    agg_k<<<NN, 256, 0, stream>>>(offb, eperm, srcp, hbuf, wvbuf, mpbuf, rnbuf, vprev,
                                  Hagg, v_o, p_o, (l > 0) ? 1 : 0);

    GemmArgs g3{};
    g3.Wt = W2aS + (size_t)l * T2 * 1024 * 8; g3.bias = b2 + l * DOUTc;
    g3.Af32 = Hagg; g3.s_out = s_o; g3.rawcnt = rawcnt;
    gemm_k<MODE_SADD, SRC_F32, 256><<<NN / 64, 256, 0, stream>>>(g3);

    if (l < NL - 1) {
      GemmArgs g4{};
      g4.Wt = U1S + (size_t)l * T2 * 1024 * 8; g4.bias = bU1 + l * HIDc;
      g4.Af32 = s_o; g4.bf_out = tbuf;
      gemm_k<MODE_H, SRC_F32, 256><<<NN / 64, 256, 0, stream>>>(g4);

      GemmArgs g5{};
      g5.Wt = U2S + (size_t)l * T2 * 1024 * 8; g5.bias = bU2 + l * HIDc;
      g5.Abf = tbuf; g5.s_out = s_o;
      gemm_k<MODE_SADD2, SRC_BF16, 256><<<NN / 64, 256, 0, stream>>>(g5);
    }
  }
}

// Round 9
// 1377.083 us; speedup vs baseline: 2.6769x; 1.0034x over previous
//
#include <hip/hip_runtime.h>
#include <hip/hip_bf16.h>

namespace {

constexpr int NN   = 8192;    // nodes
constexpr int NE   = 131072;  // edges
constexpr int SD   = 256;     // SDIM
constexpr int ED   = 128;     // EDIM
constexpr int NL   = 5;       // layers
constexpr int DINc = 644;     // 2*SD + ED + 4
constexpr int KE   = 160;     // edge-GEMM K: 128 e + 4 scalars + pad
constexpr int TE   = 5;       // KE/32
constexpr int T2   = 8;       // 256/32
constexpr int DOUTc= 513;
constexpr int HIDc = 256;

typedef __bf16 bf16x8 __attribute__((ext_vector_type(8)));
typedef float  f32x4  __attribute__((ext_vector_type(4)));

__device__ __forceinline__ float siluf(float x) { return x / (1.0f + __expf(-x)); }

// async global->LDS, 16B/lane. LDS dest is wave-uniform base (+lane*16 in HW).
__device__ __forceinline__ void gl_lds16(const void* gsrc, void* lds_uniform_base) {
  __builtin_amdgcn_global_load_lds(
      (const __attribute__((address_space(1))) unsigned int*)gsrc,
      (__attribute__((address_space(3))) unsigned int*)lds_uniform_base, 16, 0, 0);
}

__device__ __forceinline__ void wait_vm4() {
  asm volatile("s_waitcnt vmcnt(4)" ::: "memory");
  __builtin_amdgcn_sched_barrier(0);
}
__device__ __forceinline__ void wait_vm0() {
  asm volatile("s_waitcnt vmcnt(0)" ::: "memory");
  __builtin_amdgcn_sched_barrier(0);
}
__device__ __forceinline__ void wait_lgkm0() {
  asm volatile("s_waitcnt lgkmcnt(0)" ::: "memory");
  __builtin_amdgcn_sched_barrier(0);
}

// bank-group swizzle: (5x)&7 is a permutation on 0..7.
__device__ __host__ __forceinline__ int swz(int kc) { return (kc * 5) & 7; }
__device__ __forceinline__ int apos(int kc, int row) { return kc * 64  + (row ^ swz(kc)); }
__device__ __forceinline__ int bpos(int kc, int n)   { return kc * 256 + (n   ^ swz(kc)); }

enum { MODE_H = 0, MODE_SADD = 2, MODE_SADD2 = 3, MODE_LIN = 4 };
enum { SRC_BF16 = 1, SRC_F32 = 2 };

struct GemmArgs {
  const __hip_bfloat16* Wt;     // swizzled B stream: [T][1024 chunks][8 bf16]
  const float* bias;
  const __hip_bfloat16* Abf;    // SRC_BF16 source, [M][K]
  const float* Af32;            // SRC_F32 source, [M][K]
  __hip_bfloat16* bf_out;
  float* s_out;                 // d_out s region (RMW)
  const int* rawcnt;
  // dual-launch (MODE_LIN): second half of grid uses these
  const __hip_bfloat16* Wtb;
  const float* biasb;
  __hip_bfloat16* bf_outb;
  int dual;
};

__device__ __forceinline__ uint4 cvt8f(const float* p) {
  alignas(16) __hip_bfloat16 t8[8];
#pragma unroll
  for (int i = 0; i < 8; i++) t8[i] = __float2bfloat16(p[i]);
  return *(const uint4*)t8;
}

// BM rows/block, BN=256, 4 waves. A-panel staged once; barrier-free K-loop
// (B slices wave-private; counted vmcnt dbuf).
template<int MODE, int SRC, int KTOT, int BM>
__global__ __launch_bounds__(256) void gemm_k(GemmArgs g) {
  constexpr int T = KTOT / 32;
  constexpr int NC = KTOT / 8;            // chunks per row
  constexpr int RPT = 256 / BM;           // chunk-lanes per row (4 or 8)
  constexpr int RMASK = RPT - 1;
  __shared__ alignas(16) unsigned short Apan[NC * BM * 8];
  __shared__ alignas(16) unsigned short Bsh[2][4 * 256 * 8];    // 32 KB
  const int tid = threadIdx.x, lane = tid & 63, wave = tid >> 6;
  const int l16 = lane & 15, lhi = lane >> 4;
  const __hip_bfloat16* wtp = g.Wt;
  const float* biasp = g.bias;
  __hip_bfloat16* outp = g.bf_out;
  int blk = blockIdx.x;
  if constexpr (MODE == MODE_LIN) {
    const int half = gridDim.x >> 1;
    if (g.dual && blk >= half) { blk -= half; wtp = g.Wtb; biasp = g.biasb; outp = g.bf_outb; }
  }
  const int row0 = blk * BM;
  const int ar = tid / RPT, aq = tid % RPT;
  const int arow = row0 + ar;
  f32x4 acc[BM / 16][4] = {};

  auto issueB = [&](int t, int buf) {
    const __hip_bfloat16* src = wtp + (size_t)t * 1024 * 8;
    unsigned short* dst = &Bsh[buf][0];
#pragma unroll
    for (int i = 0; i < 4; i++)
      gl_lds16(src + (size_t)(i * 256 + wave * 64 + lane) * 8, dst + (i * 256 + wave * 64) * 8);
  };

  issueB(0, 0);
  // ---- stage whole A panel once: chunk c = j*RPT+aq of row ar
#pragma unroll
  for (int j = 0; j < NC / RPT; j++) {
    const int c = j * RPT + aq;
    uint4 o;
    if constexpr (SRC == SRC_BF16) o = *(const uint4*)(g.Abf + (size_t)arow * KTOT + c * 8);
    else                           o = cvt8f(g.Af32 + (size_t)arow * KTOT + c * 8);
    *(uint4*)&Apan[(c * BM + (ar ^ swz(aq))) * 8] = o;
  }
  __syncthreads();   // A panel visible; B(0) landed

  int cur = 0;
  for (int t = 0; t < T; ++t) {
    if (t + 1 < T) { issueB(t + 1, cur ^ 1); wait_vm4(); }
    else           { wait_vm0(); }
    bf16x8 bfr[4];
#pragma unroll
    for (int f = 0; f < 4; f++)
      bfr[f] = *(const bf16x8*)&Bsh[cur][bpos(lhi, wave * 64 + f * 16 + l16) * 8];
#pragma unroll
    for (int fr = 0; fr < BM / 16; fr++) {
      const int kc = t * 4 + lhi;
      const bf16x8 afr = *(const bf16x8*)&Apan[(kc * BM + ((fr * 16 + l16) ^ swz(kc & RMASK))) * 8];
#pragma unroll
      for (int fc = 0; fc < 4; fc++)
        acc[fr][fc] = __builtin_amdgcn_mfma_f32_16x16x32_bf16(afr, bfr[fc], acc[fr][fc], 0, 0, 0);
    }
    cur ^= 1;
  }

  // ---- epilogue
#pragma unroll
  for (int fr = 0; fr < BM / 16; fr++) {
#pragma unroll
    for (int fc = 0; fc < 4; fc++) {
      const int n = wave * 64 + fc * 16 + l16;
#pragma unroll
      for (int r = 0; r < 4; r++) {
        const int row = row0 + fr * 16 + lhi * 4 + r;
        const float valf = acc[fr][fc][r];
        if constexpr (MODE == MODE_H) {
          outp[(size_t)row * HIDc + n] = __float2bfloat16(siluf(valf + biasp[n]));
        } else if constexpr (MODE == MODE_LIN) {
          outp[(size_t)row * HIDc + n] = __float2bfloat16(valf + biasp[n]);
        } else if constexpr (MODE == MODE_SADD) {
          const float rc = (float)g.rawcnt[row];
          g.s_out[(size_t)row * SD + n] += valf + rc * biasp[n];
        } else {  // MODE_SADD2
          g.s_out[(size_t)row * SD + n] += valf + biasp[n];
        }
      }
    }
  }
}

// ==== fused edge kernel: h = silu([e|tail]@W1e + P1[src] + P2[tgt]); out2 = h@W2s ====
// LDS 52 KB -> 3 blocks/CU. Phase-1 dbuf borrows Hsh-lo; Psum preloaded in regs.
// Phase-2: single-buffer B with in-step reuse (read frags, lgkm0, overwrite-issue).
struct FusedArgs {
  const __hip_bfloat16* W1e;
  const __hip_bfloat16* W2s;
  const float* b2L;
  const int* src; const int* tgt;
  const __hip_bfloat16* e_bf;
  const __hip_bfloat16* tail;
  const __hip_bfloat16* p1;
  const __hip_bfloat16* p2;
  const __hip_bfloat16* w384;
  const float* rn;
  float* mp;
  __hip_bfloat16* h_out;
  __hip_bfloat16* wv_out;
  __hip_bfloat16* e_bf_out;
  float* e_f32_out;
  int write_e_f32;
};

__global__ __launch_bounds__(256, 3) void fused_k(FusedArgs g) {
  __shared__ alignas(16) unsigned short Bsh0[4 * 256 * 8];      // 16 KB
  __shared__ alignas(16) unsigned short Hsh[32 * 64 * 8];       // 32 KB (ph1 dbuf-lo -> psum/h)
  __shared__ alignas(16) unsigned short Ash[4 * 64 * 8];        // 4 KB (edge A; wps alias)
  const int tid = threadIdx.x, lane = tid & 63, wave = tid >> 6;
  const int l16 = lane & 15, lhi = lane >> 4;
  const int row0 = blockIdx.x * 64;
  const int ar = tid >> 2, aq = tid & 3;
  const int arow = row0 + ar;
  const int sn = g.src[arow], tn = g.tgt[arow];

  auto issueW = [&](const __hip_bfloat16* W, int t, unsigned short* dst) {
    const __hip_bfloat16* src = W + (size_t)t * 1024 * 8;
#pragma unroll
    for (int i = 0; i < 4; i++)
      gl_lds16(src + (size_t)(i * 256 + wave * 64 + lane) * 8, dst + (i * 256 + wave * 64) * 8);
  };
  auto loadA = [&](int t, uint4& o) {
    const int kq = t * 32 + aq * 8;
    if (kq < 128) o = *(const uint4*)(g.e_bf + (size_t)arow * ED + kq);
    else          o = *(const uint4*)(g.tail + (size_t)arow * 32 + (kq - 128));
  };

  uint4 a;
  loadA(0, a);
  issueW(g.W1e, 0, Bsh0);

  // ---- preload Psum = P1[sn]+P2[tn] into regs (chunks c = j*4+aq), 2 batches
  uint4 ps[8];
#pragma unroll
  for (int b = 0; b < 2; b++) {
    uint4 r1[4], r2[4];
#pragma unroll
    for (int j = 0; j < 4; j++) {
      const int c = (b * 4 + j) * 4 + aq;
      r1[j] = *(const uint4*)(g.p1 + (size_t)sn * SD + c * 8);
      r2[j] = *(const uint4*)(g.p2 + (size_t)tn * SD + c * 8);
    }
#pragma unroll
    for (int j = 0; j < 4; j++) {
      const __hip_bfloat16* h1 = (const __hip_bfloat16*)&r1[j];
      const __hip_bfloat16* h2 = (const __hip_bfloat16*)&r2[j];
      alignas(16) __hip_bfloat16 o8[8];
#pragma unroll
      for (int m = 0; m < 8; m++)
        o8[m] = __float2bfloat16(__bfloat162float(h1[m]) + __bfloat162float(h2[m]));
      ps[b * 4 + j] = *(const uint4*)o8;
    }
  }

  // ---- phase 1 (swapped operands -> D[n][row]); dbuf = {Bsh0, Hsh-lo}
  f32x4 acc1[4][4] = {};
  for (int t = 0; t < TE; ++t) {
    *(uint4*)&Ash[apos(aq, ar) * 8] = a;
    __syncthreads();   // Ash visible; W1e(t) landed (barrier drains vmcnt)
    unsigned short* curb = (t & 1) ? Hsh : Bsh0;
    if (t + 1 < TE) { issueW(g.W1e, t + 1, (t & 1) ? Bsh0 : Hsh); loadA(t + 1, a); }
    bf16x8 wfr[4], efr[4];
#pragma unroll
    for (int f = 0; f < 4; f++) {
      wfr[f] = *(const bf16x8*)&curb[bpos(lhi, wave * 64 + f * 16 + l16) * 8];
      efr[f] = *(const bf16x8*)&Ash[apos(lhi, f * 16 + l16) * 8];
    }
#pragma unroll
    for (int fr = 0; fr < 4; fr++)
#pragma unroll
      for (int fc = 0; fc < 4; fc++)
        acc1[fr][fc] = __builtin_amdgcn_mfma_f32_16x16x32_bf16(wfr[fr], efr[fc], acc1[fr][fc], 0, 0, 0);
    __syncthreads();
  }

  // ---- psum regs -> Hsh slots; prefetch W2s(0)
  issueW(g.W2s, 0, Bsh0);
#pragma unroll
  for (int j = 0; j < 8; j++) {
    const int c = j * 4 + aq;
    *(uint4*)&Hsh[(c * 64 + (ar ^ swz(aq))) * 8] = ps[j];
  }
  __syncthreads();   // psum visible; W2s(0) landed

  // ---- epilogue-1: h = silu(acc1 + psum); Hsh in-place; global h; wp partials
  float pw[4] = {0.f, 0.f, 0.f, 0.f};
#pragma unroll
  for (int fr = 0; fr < 4; fr++) {
    const int nb = wave * 64 + fr * 16 + lhi * 4;   // n base (4-aligned)
    const int kc = nb >> 3, off = nb & 7;
    uint2 wr = *(const uint2*)(g.w384 + nb);
    const __hip_bfloat16* w4 = (const __hip_bfloat16*)&wr;
#pragma unroll
    for (int fc = 0; fc < 4; fc++) {
      const int row = fc * 16 + l16;
      unsigned short* slot = &Hsh[(kc * 64 + (row ^ swz(kc & 3))) * 8 + off];
      uint2 pr = *(const uint2*)slot;
      const __hip_bfloat16* pp = (const __hip_bfloat16*)&pr;
      alignas(8) __hip_bfloat16 hb[4];
#pragma unroll
      for (int r = 0; r < 4; r++) {
        const float hv = siluf(acc1[fr][fc][r] + __bfloat162float(pp[r]));
        hb[r] = __float2bfloat16(hv);
        pw[fc] += hv * __bfloat162float(w4[r]);
      }
      *(uint2*)slot = *(const uint2*)hb;
      *(uint2*)(g.h_out + (size_t)(row0 + row) * HIDc + nb) = *(const uint2*)hb;
    }
  }

  // ---- wp reduce (wps aliased onto Ash)
  float (*wps)[64] = (float(*)[64])Ash;
#pragma unroll
  for (int fc = 0; fc < 4; fc++) {
    pw[fc] += __shfl_xor(pw[fc], 16);
    pw[fc] += __shfl_xor(pw[fc], 32);
  }
  if (lane < 16) {
#pragma unroll
    for (int fc = 0; fc < 4; fc++) wps[wave][fc * 16 + lane] = pw[fc];
  }
  __syncthreads();   // wps + Hsh h-writes visible
  if (tid < 64) {
    const float s = wps[0][tid] + wps[1][tid] + wps[2][tid] + wps[3][tid];
    const float wpt = tanhf(s + g.b2L[384]);
#pragma unroll
    for (int c = 0; c < 3; c++)
      g.mp[(size_t)(row0 + tid) * 3 + c] = wpt * g.rn[(size_t)(row0 + tid) * 3 + c];
  }

  // ---- phase 2: out2 = h @ W2s. Barrier-free; single-buffer B with in-step reuse.
  f32x4 acc2[4][4] = {};
  for (int t = 0; t < T2; ++t) {
    wait_vm0();        // W2s(t) landed (B slices wave-private)
    bf16x8 afr[4], bfr[4];
#pragma unroll
    for (int f = 0; f < 4; f++) {
      const int kc = t * 4 + lhi;        // kc & 3 == lhi
      afr[f] = *(const bf16x8*)&Hsh[(kc * 64 + ((f * 16 + l16) ^ swz(lhi))) * 8];
      bfr[f] = *(const bf16x8*)&Bsh0[bpos(lhi, wave * 64 + f * 16 + l16) * 8];
    }
    wait_lgkm0();      // frags in regs before overwrite
    if (t + 1 < T2) issueW(g.W2s, t + 1, Bsh0);
#pragma unroll
    for (int fr = 0; fr < 4; fr++)
#pragma unroll
      for (int fc = 0; fc < 4; fc++)
        acc2[fr][fc] = __builtin_amdgcn_mfma_f32_16x16x32_bf16(afr[fr], bfr[fc], acc2[fr][fc], 0, 0, 0);
  }

  // ---- epilogue-2: wv | e_new
#pragma unroll
  for (int fr = 0; fr < 4; fr++) {
#pragma unroll
    for (int fc = 0; fc < 4; fc++) {
      const int n = wave * 64 + fc * 16 + l16;
#pragma unroll
      for (int r = 0; r < 4; r++) {
        const int row = row0 + fr * 16 + lhi * 4 + r;
        const float valf = acc2[fr][fc][r];
        if (n < 128) {
          g.wv_out[(size_t)row * 128 + n] = __float2bfloat16(valf + g.b2L[256 + n]);
        } else {
          const float sv = siluf(valf + g.b2L[257 + n]);   // e_new cols = W2 cols 385..512
          g.e_bf_out[(size_t)row * ED + (n - 128)] = __float2bfloat16(sv);
          if (g.write_e_f32) g.e_f32_out[(size_t)row * ED + (n - 128)] = sv;
        }
      }
    }
  }
}

// ---- LayerNorm. 4 nodes/block, wave per node.
__global__ __launch_bounds__(256) void ln_k(const float* __restrict__ s,
                                            const float* __restrict__ gl, const float* __restrict__ bl,
                                            __hip_bfloat16* __restrict__ s_ln) {
  const int wave = threadIdx.x >> 6, lane = threadIdx.x & 63;
  const int node = blockIdx.x * 4 + wave;
  const float* srow = s + (size_t)node * SD;
  float x[4], sum = 0.f, sq = 0.f;
#pragma unroll
  for (int i = 0; i < 4; i++) { x[i] = srow[lane * 4 + i]; sum += x[i]; sq += x[i] * x[i]; }
#pragma unroll
  for (int off = 1; off < 64; off <<= 1) { sum += __shfl_xor(sum, off); sq += __shfl_xor(sq, off); }
  const float mu = sum * (1.0f / SD);
  const float var = sq * (1.0f / SD) - mu * mu;
  const float rstd = rsqrtf(var + 1e-5f);
#pragma unroll
  for (int i = 0; i < 4; i++) {
    const int c = lane * 4 + i;
    s_ln[(size_t)node * SD + c] = __float2bfloat16(gl[c] * (x[i] - mu) * rstd + bl[c]);
  }
}

// ---- per-edge attrs: rn + bf16 tail block [NE][32] = {d,a,pn_src,pn_tgt,0,...}
__global__ void edge_attr_k(const float* __restrict__ p, const int* __restrict__ src, const int* __restrict__ tgt,
                            float* __restrict__ rn, __hip_bfloat16* __restrict__ tail) {
  const int e = blockIdx.x * blockDim.x + threadIdx.x;
  if (e >= NE) return;
  const int s_ = src[e], t_ = tgt[e];
  const float sx = p[s_ * 3], sy = p[s_ * 3 + 1], sz = p[s_ * 3 + 2];
  const float tx = p[t_ * 3], ty = p[t_ * 3 + 1], tz = p[t_ * 3 + 2];
  const float rx = tx - sx, ry = ty - sy, rz = tz - sz;
  const float a = tx * sx + ty * sy + tz * sz;
  const float rr = rx * rx + ry * ry + rz * rz;
  const float d = sqrtf(fmaxf(rr, 1e-6f));
  const float inv = 1.0f / (1.0f + d);
  rn[e * 3] = rx * inv; rn[e * 3 + 1] = ry * inv; rn[e * 3 + 2] = rz * inv;
  alignas(16) __hip_bfloat16 t8[8];
  t8[0] = __float2bfloat16(d);
  t8[1] = __float2bfloat16(a);
  t8[2] = __float2bfloat16(sqrtf(sx * sx + sy * sy + sz * sz));
  t8[3] = __float2bfloat16(sqrtf(tx * tx + ty * ty + tz * tz));
  t8[4] = t8[5] = t8[6] = t8[7] = __float2bfloat16(0.0f);
  __hip_bfloat16* tp = tail + (size_t)e * 32;
  uint4 z; z.x = z.y = z.z = z.w = 0;
  *(uint4*)tp = *(const uint4*)t8;
  *(uint4*)(tp + 8) = z;
  *(uint4*)(tp + 16) = z;
  *(uint4*)(tp + 24) = z;
}

__global__ void cvt_e_k(const float* __restrict__ e, __hip_bfloat16* __restrict__ ebf) {
  const int i = blockIdx.x * blockDim.x + threadIdx.x;
  const float* p = e + (size_t)i * 8;
  alignas(16) __hip_bfloat16 t8[8];
#pragma unroll
  for (int j = 0; j < 8; j++) t8[j] = __float2bfloat16(p[j]);
  *(uint4*)(ebf + (size_t)i * 8) = *(const uint4*)t8;
}

__global__ void count_k(const int* __restrict__ tgt, int* __restrict__ rawcnt) {
  const int e = blockIdx.x * blockDim.x + threadIdx.x;
  if (e < NE) atomicAdd(&rawcnt[tgt[e]], 1);
}

__global__ __launch_bounds__(256) void scan_k(const int* __restrict__ rawcnt, int* __restrict__ off) {
  __shared__ int ts[256];
  const int tid = threadIdx.x;
  const int base = tid * 32;
  int local[32];
  int s = 0;
#pragma unroll
  for (int i = 0; i < 32; i++) { local[i] = s; s += rawcnt[base + i]; }
  ts[tid] = s;
  __syncthreads();
  if (tid == 0) {
    int acc = 0;
    for (int i = 0; i < 256; i++) { int t = ts[i]; ts[i] = acc; acc += t; }
    off[NN] = acc;
  }
  __syncthreads();
  const int pre = ts[tid];
#pragma unroll
  for (int i = 0; i < 32; i++) off[base + i] = pre + local[i];
}

__global__ void scatter_k(const int* __restrict__ tgt, const int* __restrict__ off,
                          int* __restrict__ cursor, int* __restrict__ eperm) {
  const int e = blockIdx.x * blockDim.x + threadIdx.x;
  if (e < NE) {
    const int t = tgt[e];
    const int r = atomicAdd(&cursor[t], 1);
    eperm[off[t] + r] = e;
  }
}

// ---- CSR aggregation: one block (256 thr) per node. v ping-pong (old -> new).
__global__ __launch_bounds__(256) void agg_k(const int* __restrict__ off, const int* __restrict__ eperm,
                                             const int* __restrict__ srcp,
                                             const __hip_bfloat16* __restrict__ h,
                                             const __hip_bfloat16* __restrict__ wv,
                                             const float* __restrict__ mp,
                                             const float* __restrict__ rn,
                                             const float* __restrict__ v_old,
                                             float* __restrict__ v_new,
                                             float* __restrict__ Hagg,
                                             float* __restrict__ p_o,
                                             int hasv) {
  const int n = blockIdx.x;
  const int c = threadIdx.x;
  const int e0 = off[n], e1 = off[n + 1];
  const int c3 = c >> 6, ln = c & 63;
  float hs = 0.f, vs = 0.f, ps = 0.f;
  for (int j = e0; j < e1; j++) {
    const int e = eperm[j];
    hs += __bfloat162float(h[(size_t)e * HIDc + c]);
    if (c < 192) {
      float mv = __bfloat162float(wv[(size_t)e * 128 + 64 + ln]) * rn[(size_t)e * 3 + c3];
      if (hasv) mv += __bfloat162float(wv[(size_t)e * 128 + ln]) * v_old[(size_t)srcp[e] * 192 + c];
      vs += mv;
    } else if (c < 195) {
      ps += mp[(size_t)e * 3 + (c - 192)];
    }
  }
  Hagg[(size_t)n * HIDc + c] = hs;
  const float inv = 1.0f / fmaxf((float)(e1 - e0), 1.0f);
  if (c < 192)      v_new[(size_t)n * 192 + c] = v_old[(size_t)n * 192 + c] + vs * inv;
  else if (c < 195) p_o[n * 3 + (c - 192)]    += ps * inv;
}

__global__ void zero_k(float* __restrict__ ptr, int n) {
  const int i = blockIdx.x * blockDim.x + threadIdx.x;
  if (i < n) ptr[i] = 0.f;
}

// ---- weight prep -> swizzled streams: chunk p of k-step t holds
// W^T[n][t*32 + kc*8 .. +8) with kc = p>>8, n = (p&255) ^ swz(kc).
__global__ void prep_w1abs_k(const float* __restrict__ W1, __hip_bfloat16* __restrict__ W1aS,
                             __hip_bfloat16* __restrict__ W1bS) {
  const int idx = blockIdx.x * blockDim.x + threadIdx.x;
  if (idx >= NL * T2 * 1024) return;
  const int p = idx & 1023, t = (idx >> 10) % T2, l = idx / (T2 * 1024);
  const int kc = p >> 8, n = (p & 255) ^ swz(kc);
  alignas(16) __hip_bfloat16 a8[8], b8[8];
#pragma unroll
  for (int j = 0; j < 8; j++) {
    const int k = t * 32 + kc * 8 + j;   // 0..255
    a8[j] = __float2bfloat16(W1[((size_t)l * DINc + k) * HIDc + n]);
    b8[j] = __float2bfloat16(W1[((size_t)l * DINc + 256 + k) * HIDc + n]);
  }
  *(uint4*)(W1aS + (size_t)idx * 8) = *(const uint4*)a8;
  *(uint4*)(W1bS + (size_t)idx * 8) = *(const uint4*)b8;
}

__global__ void prep_w1es_k(const float* __restrict__ W1, __hip_bfloat16* __restrict__ W1eS) {
  const int idx = blockIdx.x * blockDim.x + threadIdx.x;
  if (idx >= NL * TE * 1024) return;
  const int p = idx & 1023, t = (idx >> 10) % TE, l = idx / (TE * 1024);
  const int kc = p >> 8, n = (p & 255) ^ swz(kc);
  alignas(16) __hip_bfloat16 e8[8];
#pragma unroll
  for (int j = 0; j < 8; j++) {
    const int k = t * 32 + kc * 8 + j;   // 0..159
    const int row = (k < 128) ? (512 + k) : ((k < 132) ? (640 + (k - 128)) : -1);
    e8[j] = __float2bfloat16(row >= 0 ? W1[((size_t)l * DINc + row) * HIDc + n] : 0.f);
  }
  *(uint4*)(W1eS + (size_t)idx * 8) = *(const uint4*)e8;
}

__global__ void prep_w2s_k(const float* __restrict__ W2, __hip_bfloat16* __restrict__ W2sS,
                           __hip_bfloat16* __restrict__ W2aS) {
  const int idx = blockIdx.x * blockDim.x + threadIdx.x;
  if (idx >= NL * T2 * 1024) return;
  const int p = idx & 1023, t = (idx >> 10) & 7, l = idx >> 13;
  const int kc = p >> 8, n = (p & 255) ^ swz(kc);
  const float* W2l = W2 + (size_t)l * HIDc * DOUTc;
  const int cs = (n < 128) ? (256 + n) : (257 + n);  // wv1|wv2 then e_new (skip col 384)
  alignas(16) __hip_bfloat16 s8[8], a8[8];
#pragma unroll
  for (int j = 0; j < 8; j++) {
    const int k = t * 32 + kc * 8 + j;
    s8[j] = __float2bfloat16(W2l[(size_t)k * DOUTc + cs]);
    a8[j] = __float2bfloat16(W2l[(size_t)k * DOUTc + n]);
  }
  *(uint4*)(W2sS + (size_t)idx * 8) = *(const uint4*)s8;
  *(uint4*)(W2aS + (size_t)idx * 8) = *(const uint4*)a8;
}

__global__ void prep_uts_k(const float* __restrict__ U1, const float* __restrict__ U2,
                           __hip_bfloat16* __restrict__ U1S, __hip_bfloat16* __restrict__ U2S) {
  const int idx = blockIdx.x * blockDim.x + threadIdx.x;
  if (idx >= NL * T2 * 1024) return;
  const int p = idx & 1023, t = (idx >> 10) & 7, l = idx >> 13;
  const int kc = p >> 8, n = (p & 255) ^ swz(kc);
  alignas(16) __hip_bfloat16 u1[8], u2[8];
#pragma unroll
  for (int j = 0; j < 8; j++) {
    const int k = t * 32 + kc * 8 + j;
    u1[j] = __float2bfloat16(U1[((size_t)l * HIDc + k) * HIDc + n]);
    u2[j] = __float2bfloat16(U2[((size_t)l * HIDc + k) * HIDc + n]);
  }
  *(uint4*)(U1S + (size_t)idx * 8) = *(const uint4*)u1;
  *(uint4*)(U2S + (size_t)idx * 8) = *(const uint4*)u2;
}

__global__ void prep_w384_k(const float* __restrict__ W2, __hip_bfloat16* __restrict__ w384) {
  const int idx = blockIdx.x * blockDim.x + threadIdx.x;
  if (idx >= NL * HIDc) return;
  const int k = idx & 255, l = idx >> 8;
  w384[idx] = __float2bfloat16(W2[((size_t)l * HIDc + k) * DOUTc + 384]);
}

}  // namespace

extern "C" void kernel_launch(void* const* d_in, const int* in_sizes, int n_in,
                              void* d_out, int out_size, void* d_ws, size_t ws_size,
                              hipStream_t stream) {
  (void)in_sizes; (void)n_in; (void)out_size; (void)ws_size;
  const float* s_in = (const float*)d_in[0];
  const float* v_in = (const float*)d_in[1];
  const float* p_in = (const float*)d_in[2];
  const float* e_in = (const float*)d_in[3];
  const int*   ei   = (const int*)d_in[4];
  const float* ln_g = (const float*)d_in[5];
  const float* ln_b = (const float*)d_in[6];
  const float* W1   = (const float*)d_in[7];
  const float* b1   = (const float*)d_in[8];
  const float* W2   = (const float*)d_in[9];
  const float* b2   = (const float*)d_in[10];
  const float* U1   = (const float*)d_in[11];
  const float* bU1  = (const float*)d_in[12];
  const float* U2   = (const float*)d_in[13];
  const float* bU2  = (const float*)d_in[14];

  float* s_o = (float*)d_out;
  float* v_o = s_o + (size_t)NN * SD;
  float* e_o = v_o + (size_t)NN * 192;
  float* p_o = e_o + (size_t)NE * ED;

  const int* srcp = ei;
  const int* tgtp = ei + NE;

  char* wp = (char*)d_ws;
  auto alloc = [&](size_t bytes) -> char* {
    char* r = wp; wp += (bytes + 255) & ~(size_t)255; return r;
  };
  __hip_bfloat16* s_ln = (__hip_bfloat16*)alloc((size_t)NN * SD * 2);
  __hip_bfloat16* hbuf = (__hip_bfloat16*)alloc((size_t)NE * HIDc * 2);
  __hip_bfloat16* ebf  = (__hip_bfloat16*)alloc((size_t)NE * ED * 2);
  __hip_bfloat16* tbuf = (__hip_bfloat16*)alloc((size_t)NN * HIDc * 2);
  __hip_bfloat16* wvbuf= (__hip_bfloat16*)alloc((size_t)NE * 128 * 2);
  __hip_bfloat16* tailb= (__hip_bfloat16*)alloc((size_t)NE * 32 * 2);
  __hip_bfloat16* p1buf= (__hip_bfloat16*)alloc((size_t)NN * SD * 2);
  __hip_bfloat16* p2buf= (__hip_bfloat16*)alloc((size_t)NN * SD * 2);
  float* rnbuf = (float*)alloc((size_t)NE * 3 * 4);
  float* Hagg  = (float*)alloc((size_t)NN * SD * 4);
  float* vprev = (float*)alloc((size_t)NN * 192 * 4);
  float* mpbuf = (float*)alloc((size_t)NE * 3 * 4);
  float* zerobias = (float*)alloc(256 * 4);
  int*   rawcnt= (int*)alloc((size_t)NN * 4);
  int*   offb  = (int*)alloc((size_t)(NN + 1) * 4);
  int*   cursor= (int*)alloc((size_t)NN * 4);
  int*   eperm = (int*)alloc((size_t)NE * 4);
  __hip_bfloat16* W1aS = (__hip_bfloat16*)alloc((size_t)NL * T2 * 1024 * 8 * 2);
  __hip_bfloat16* W1bS = (__hip_bfloat16*)alloc((size_t)NL * T2 * 1024 * 8 * 2);
  __hip_bfloat16* W1eS = (__hip_bfloat16*)alloc((size_t)NL * TE * 1024 * 8 * 2);
  __hip_bfloat16* W2sS = (__hip_bfloat16*)alloc((size_t)NL * T2 * 1024 * 8 * 2);
  __hip_bfloat16* W2aS = (__hip_bfloat16*)alloc((size_t)NL * T2 * 1024 * 8 * 2);
  __hip_bfloat16* U1S  = (__hip_bfloat16*)alloc((size_t)NL * T2 * 1024 * 8 * 2);
  __hip_bfloat16* U2S  = (__hip_bfloat16*)alloc((size_t)NL * T2 * 1024 * 8 * 2);
  __hip_bfloat16* w384 = (__hip_bfloat16*)alloc((size_t)NL * HIDc * 2);

  hipMemcpyAsync(s_o, s_in, (size_t)NN * SD * 4, hipMemcpyDeviceToDevice, stream);
  hipMemcpyAsync(vprev, v_in, (size_t)NN * 192 * 4, hipMemcpyDeviceToDevice, stream);
  hipMemcpyAsync(p_o, p_in, (size_t)NN * 3 * 4, hipMemcpyDeviceToDevice, stream);

  prep_w1abs_k<<<(NL * T2 * 1024 + 255) / 256, 256, 0, stream>>>(W1, W1aS, W1bS);
  prep_w1es_k<<<(NL * TE * 1024 + 255) / 256, 256, 0, stream>>>(W1, W1eS);
  prep_w2s_k<<<(NL * T2 * 1024 + 255) / 256, 256, 0, stream>>>(W2, W2sS, W2aS);
  prep_uts_k<<<(NL * T2 * 1024 + 255) / 256, 256, 0, stream>>>(U1, U2, U1S, U2S);
  prep_w384_k<<<(NL * HIDc + 255) / 256, 256, 0, stream>>>(W2, w384);
  cvt_e_k<<<NE * ED / 8 / 256, 256, 0, stream>>>(e_in, ebf);
  zero_k<<<1, 256, 0, stream>>>(zerobias, 256);

  // ---- CSR build (once; edge_index layer-invariant)
  zero_k<<<(NN + 255) / 256, 256, 0, stream>>>((float*)rawcnt, NN);
  zero_k<<<(NN + 255) / 256, 256, 0, stream>>>((float*)cursor, NN);
  count_k<<<NE / 256, 256, 0, stream>>>(tgtp, rawcnt);
  scan_k<<<1, 256, 0, stream>>>(rawcnt, offb);
  scatter_k<<<NE / 256, 256, 0, stream>>>(tgtp, offb, cursor, eperm);

  for (int l = 0; l < NL; l++) {
    ln_k<<<NN / 4, 256, 0, stream>>>(s_o, ln_g + l * SD, ln_b + l * SD, s_ln);
    edge_attr_k<<<NE / 256, 256, 0, stream>>>(p_o, srcp, tgtp, rnbuf, tailb);

    // P1 = s_ln @ W1a + b1 ; P2 = s_ln @ W1b  (single dual launch, 256 blocks)
    GemmArgs gp{};
    gp.Wt = W1aS + (size_t)l * T2 * 1024 * 8; gp.bias = b1 + l * HIDc; gp.bf_out = p1buf;
    gp.Wtb = W1bS + (size_t)l * T2 * 1024 * 8; gp.biasb = zerobias; gp.bf_outb = p2buf;
    gp.Abf = s_ln; gp.dual = 1;
    gemm_k<MODE_LIN, SRC_BF16, 256, 64><<<2 * NN / 64, 256, 0, stream>>>(gp);

    // fused edge kernel: h + out2
    FusedArgs gf{};
    gf.W1e = W1eS + (size_t)l * TE * 1024 * 8;
    gf.W2s = W2sS + (size_t)l * T2 * 1024 * 8;
    gf.b2L = b2 + l * DOUTc;
    gf.src = srcp; gf.tgt = tgtp; gf.e_bf = ebf; gf.tail = tailb;
    gf.p1 = p1buf; gf.p2 = p2buf; gf.w384 = w384 + l * HIDc;
    gf.rn = rnbuf; gf.mp = mpbuf;
    gf.h_out = hbuf; gf.wv_out = wvbuf; gf.e_bf_out = ebf; gf.e_f32_out = e_o;
    gf.write_e_f32 = (l == NL - 1) ? 1 : 0;
    fused_k<<<NE / 64, 256, 0, stream>>>(gf);

    // v ping-pong: l even reads vprev writes v_o; l odd reads v_o writes vprev.
    // 5 layers -> final write lands in v_o.
    const float* vold = (l & 1) ? (const float*)v_o : (const float*)vprev;
    float* vnew = (l & 1) ? vprev : v_o;
    agg_k<<<NN, 256, 0, stream>>>(offb, eperm, srcp, hbuf, wvbuf, mpbuf, rnbuf,
                                  vold, vnew, Hagg, p_o, (l > 0) ? 1 : 0);

    GemmArgs g3{};
    g3.Wt = W2aS + (size_t)l * T2 * 1024 * 8; g3.bias = b2 + l * DOUTc;
    g3.Af32 = Hagg; g3.s_out = s_o; g3.rawcnt = rawcnt;
    gemm_k<MODE_SADD, SRC_F32, 256, 32><<<NN / 32, 256, 0, stream>>>(g3);

    if (l < NL - 1) {
      GemmArgs g4{};
      g4.Wt = U1S + (size_t)l * T2 * 1024 * 8; g4.bias = bU1 + l * HIDc;
      g4.Af32 = s_o; g4.bf_out = tbuf;
      gemm_k<MODE_H, SRC_F32, 256, 32><<<NN / 32, 256, 0, stream>>>(g4);

      GemmArgs g5{};
      g5.Wt = U2S + (size_t)l * T2 * 1024 * 8; g5.bias = bU2 + l * HIDc;
      g5.Abf = tbuf; g5.s_out = s_o;
      gemm_k<MODE_SADD2, SRC_BF16, 256, 32><<<NN / 32, 256, 0, stream>>>(g5);
    }
  }
}

// Round 10
// 1366.325 us; speedup vs baseline: 2.6980x; 1.0079x over previous
//
#include <hip/hip_runtime.h>
#include <hip/hip_bf16.h>

namespace {

constexpr int NN   = 8192;    // nodes
constexpr int NE   = 131072;  // edges
constexpr int SD   = 256;     // SDIM
constexpr int ED   = 128;     // EDIM
constexpr int NL   = 5;       // layers
constexpr int DINc = 644;     // 2*SD + ED + 4
constexpr int KE   = 160;     // edge-GEMM K: 128 e + 4 scalars + pad
constexpr int TE   = 5;       // KE/32
constexpr int T2   = 8;       // 256/32
constexpr int DOUTc= 513;
constexpr int HIDc = 256;

typedef __bf16 bf16x8 __attribute__((ext_vector_type(8)));
typedef float  f32x4  __attribute__((ext_vector_type(4)));

__device__ __forceinline__ float siluf(float x) { return x / (1.0f + __expf(-x)); }

// async global->LDS, 16B/lane. LDS dest is wave-uniform base (+lane*16 in HW).
__device__ __forceinline__ void gl_lds16(const void* gsrc, void* lds_uniform_base) {
  __builtin_amdgcn_global_load_lds(
      (const __attribute__((address_space(1))) unsigned int*)gsrc,
      (__attribute__((address_space(3))) unsigned int*)lds_uniform_base, 16, 0, 0);
}

__device__ __forceinline__ void wait_vm4() {
  asm volatile("s_waitcnt vmcnt(4)" ::: "memory");
  __builtin_amdgcn_sched_barrier(0);
}
__device__ __forceinline__ void wait_vm0() {
  asm volatile("s_waitcnt vmcnt(0)" ::: "memory");
  __builtin_amdgcn_sched_barrier(0);
}
__device__ __forceinline__ void wait_lgkm0() {
  asm volatile("s_waitcnt lgkmcnt(0)" ::: "memory");
  __builtin_amdgcn_sched_barrier(0);
}

// bank-group swizzle: (5x)&7 is a permutation on 0..7.
__device__ __host__ __forceinline__ int swz(int kc) { return (kc * 5) & 7; }
__device__ __forceinline__ int bpos(int kc, int n)   { return kc * 256 + (n   ^ swz(kc)); }

enum { MODE_H = 0, MODE_SADD = 2, MODE_SADD2 = 3, MODE_LIN = 4 };
enum { SRC_BF16 = 1, SRC_F32 = 2 };

struct GemmArgs {
  const __hip_bfloat16* Wt;     // swizzled B stream: [T][1024 chunks][8 bf16]
  const float* bias;
  const __hip_bfloat16* Abf;    // SRC_BF16 source, [M][K]
  const float* Af32;            // SRC_F32 source, [M][K]
  __hip_bfloat16* bf_out;
  float* s_out;                 // d_out s region (RMW)
  const int* rawcnt;
  // dual-launch (MODE_LIN): second half of grid uses these
  const __hip_bfloat16* Wtb;
  const float* biasb;
  __hip_bfloat16* bf_outb;
  int dual;
};

__device__ __forceinline__ uint4 cvt8f(const float* p) {
  alignas(16) __hip_bfloat16 t8[8];
#pragma unroll
  for (int i = 0; i < 8; i++) t8[i] = __float2bfloat16(p[i]);
  return *(const uint4*)t8;
}

// BM rows/block, BN=256, 4 waves. A-panel staged once; barrier-free K-loop
// (B slices wave-private; counted vmcnt dbuf).
template<int MODE, int SRC, int KTOT, int BM>
__global__ __launch_bounds__(256) void gemm_k(GemmArgs g) {
  constexpr int T = KTOT / 32;
  constexpr int NC = KTOT / 8;            // chunks per row
  constexpr int RPT = 256 / BM;           // chunk-lanes per row (4 or 8)
  constexpr int RMASK = RPT - 1;
  __shared__ alignas(16) unsigned short Apan[NC * BM * 8];
  __shared__ alignas(16) unsigned short Bsh[2][4 * 256 * 8];    // 32 KB
  const int tid = threadIdx.x, lane = tid & 63, wave = tid >> 6;
  const int l16 = lane & 15, lhi = lane >> 4;
  const __hip_bfloat16* wtp = g.Wt;
  const float* biasp = g.bias;
  __hip_bfloat16* outp = g.bf_out;
  int blk = blockIdx.x;
  if constexpr (MODE == MODE_LIN) {
    const int half = gridDim.x >> 1;
    if (g.dual && blk >= half) { blk -= half; wtp = g.Wtb; biasp = g.biasb; outp = g.bf_outb; }
  }
  const int row0 = blk * BM;
  const int ar = tid / RPT, aq = tid % RPT;
  const int arow = row0 + ar;
  f32x4 acc[BM / 16][4] = {};

  auto issueB = [&](int t, int buf) {
    const __hip_bfloat16* src = wtp + (size_t)t * 1024 * 8;
    unsigned short* dst = &Bsh[buf][0];
#pragma unroll
    for (int i = 0; i < 4; i++)
      gl_lds16(src + (size_t)(i * 256 + wave * 64 + lane) * 8, dst + (i * 256 + wave * 64) * 8);
  };

  issueB(0, 0);
  // ---- stage whole A panel once: chunk c = j*RPT+aq of row ar
#pragma unroll
  for (int j = 0; j < NC / RPT; j++) {
    const int c = j * RPT + aq;
    uint4 o;
    if constexpr (SRC == SRC_BF16) o = *(const uint4*)(g.Abf + (size_t)arow * KTOT + c * 8);
    else                           o = cvt8f(g.Af32 + (size_t)arow * KTOT + c * 8);
    *(uint4*)&Apan[(c * BM + (ar ^ swz(aq))) * 8] = o;
  }
  __syncthreads();   // A panel visible; B(0) landed

  int cur = 0;
  for (int t = 0; t < T; ++t) {
    if (t + 1 < T) { issueB(t + 1, cur ^ 1); wait_vm4(); }
    else           { wait_vm0(); }
    bf16x8 bfr[4];
#pragma unroll
    for (int f = 0; f < 4; f++)
      bfr[f] = *(const bf16x8*)&Bsh[cur][bpos(lhi, wave * 64 + f * 16 + l16) * 8];
#pragma unroll
    for (int fr = 0; fr < BM / 16; fr++) {
      const int kc = t * 4 + lhi;
      const bf16x8 afr = *(const bf16x8*)&Apan[(kc * BM + ((fr * 16 + l16) ^ swz(kc & RMASK))) * 8];
#pragma unroll
      for (int fc = 0; fc < 4; fc++)
        acc[fr][fc] = __builtin_amdgcn_mfma_f32_16x16x32_bf16(afr, bfr[fc], acc[fr][fc], 0, 0, 0);
    }
    cur ^= 1;
  }

  // ---- epilogue
#pragma unroll
  for (int fr = 0; fr < BM / 16; fr++) {
#pragma unroll
    for (int fc = 0; fc < 4; fc++) {
      const int n = wave * 64 + fc * 16 + l16;
#pragma unroll
      for (int r = 0; r < 4; r++) {
        const int row = row0 + fr * 16 + lhi * 4 + r;
        const float valf = acc[fr][fc][r];
        if constexpr (MODE == MODE_H) {
          outp[(size_t)row * HIDc + n] = __float2bfloat16(siluf(valf + biasp[n]));
        } else if constexpr (MODE == MODE_LIN) {
          outp[(size_t)row * HIDc + n] = __float2bfloat16(valf + biasp[n]);
        } else if constexpr (MODE == MODE_SADD) {
          const float rc = (float)g.rawcnt[row];
          g.s_out[(size_t)row * SD + n] += valf + rc * biasp[n];
        } else {  // MODE_SADD2
          g.s_out[(size_t)row * SD + n] += valf + biasp[n];
        }
      }
    }
  }
}

// ==== fused edge kernel ====
// h = silu([e|tail]@W1e + P1[src] + P2[tgt]); out2 = h@W2s.
// LDS 68 KB = Apan 20 (edge A panel; ph2 B-dbuf half; wps alias) + Bsh0 16 + Hsh 32.
// BOTH K-loops barrier-free: B slices wave-private, 2-ahead issue, counted vmcnt(4).
// Psum gathered directly in epilogue-1 (no LDS transit, no extra barrier).
struct FusedArgs {
  const __hip_bfloat16* W1e;
  const __hip_bfloat16* W2s;
  const float* b2L;
  const int* src; const int* tgt;
  const __hip_bfloat16* e_bf;
  const __hip_bfloat16* tail;
  const __hip_bfloat16* p1;
  const __hip_bfloat16* p2;
  const __hip_bfloat16* w384;
  const float* rn;
  float* mp;
  __hip_bfloat16* h_out;
  __hip_bfloat16* wv_out;
  __hip_bfloat16* e_bf_out;
  float* e_f32_out;
  int write_e_f32;
};

__global__ __launch_bounds__(256) void fused_k(FusedArgs g) {
  __shared__ alignas(16) unsigned short Apan[20 * 64 * 8];   // 20 KB
  __shared__ alignas(16) unsigned short Bsh0[4 * 256 * 8];   // 16 KB
  __shared__ alignas(16) unsigned short Hsh[32 * 64 * 8];    // 32 KB (ph1 B-dbuf-lo -> h)
  const int tid = threadIdx.x, lane = tid & 63, wave = tid >> 6;
  const int l16 = lane & 15, lhi = lane >> 4;
  const int row0 = blockIdx.x * 64;
  const int ar = tid >> 2, aq = tid & 3;
  const int arow = row0 + ar;

  auto issueW = [&](const __hip_bfloat16* W, int t, unsigned short* dst) {
    const __hip_bfloat16* src = W + (size_t)t * 1024 * 8;
#pragma unroll
    for (int i = 0; i < 4; i++)
      gl_lds16(src + (size_t)(i * 256 + wave * 64 + lane) * 8, dst + (i * 256 + wave * 64) * 8);
  };

  // ---- prologue: W1e(0)->Bsh0, W1e(1)->Hsh-lo; stage edge A panel (20 chunks/row)
  issueW(g.W1e, 0, Bsh0);
  issueW(g.W1e, 1, Hsh);
#pragma unroll
  for (int j = 0; j < 5; j++) {
    const int c = j * 4 + aq;          // 0..19, c&3 == aq
    const int kq = c * 8;
    uint4 o;
    if (kq < 128) o = *(const uint4*)(g.e_bf + (size_t)arow * ED + kq);
    else          o = *(const uint4*)(g.tail + (size_t)arow * 32 + (kq - 128));
    *(uint4*)&Apan[(c * 64 + (ar ^ swz(aq))) * 8] = o;
  }
  __syncthreads();   // Apan visible; W1e(0),(1) landed (barrier drains vmcnt)

  // ---- phase 1: SWAPPED operands -> D[n][row]; barrier-free dbuf {Bsh0, Hsh-lo}
  f32x4 acc1[4][4] = {};
  for (int t = 0; t < TE; ++t) {
    if (t + 1 < TE) wait_vm4(); else wait_vm0();
    unsigned short* curb = (t & 1) ? Hsh : Bsh0;
    bf16x8 wfr[4], efr[4];
#pragma unroll
    for (int f = 0; f < 4; f++) {
      wfr[f] = *(const bf16x8*)&curb[bpos(lhi, wave * 64 + f * 16 + l16) * 8];
      const int ck = t * 4 + lhi;      // ck&3 == lhi
      efr[f] = *(const bf16x8*)&Apan[(ck * 64 + ((f * 16 + l16) ^ swz(lhi))) * 8];
    }
    wait_lgkm0();                      // frags in regs before overwrite
    if (t + 2 < TE) issueW(g.W1e, t + 2, curb);
#pragma unroll
    for (int fr = 0; fr < 4; fr++)
#pragma unroll
      for (int fc = 0; fc < 4; fc++)
        acc1[fr][fc] = __builtin_amdgcn_mfma_f32_16x16x32_bf16(wfr[fr], efr[fc], acc1[fr][fc], 0, 0, 0);
  }
  __syncthreads();   // all waves done with Bsh0/Hsh-lo (B) and Apan (edge A)

  // ---- issue phase-2 B steps 0,1 early (flight hides under epilogue-1)
  issueW(g.W2s, 0, Bsh0);
  issueW(g.W2s, 1, Apan);

  // ---- epilogue-1: h = silu(acc1 + P1[src] + P2[tgt]); write Hsh + global h; wp partials
  float pw[4] = {0.f, 0.f, 0.f, 0.f};
#pragma unroll
  for (int fc = 0; fc < 4; fc++) {
    const int row = fc * 16 + l16;
    const int s2 = g.src[row0 + row], t2 = g.tgt[row0 + row];
#pragma unroll
    for (int fr = 0; fr < 4; fr++) {
      const int nb = wave * 64 + fr * 16 + lhi * 4;   // n base (4-aligned)
      const int kc = nb >> 3, off = nb & 7;
      uint2 q1 = *(const uint2*)(g.p1 + (size_t)s2 * SD + nb);
      uint2 q2 = *(const uint2*)(g.p2 + (size_t)t2 * SD + nb);
      uint2 wr = *(const uint2*)(g.w384 + nb);
      const __hip_bfloat16* c1 = (const __hip_bfloat16*)&q1;
      const __hip_bfloat16* c2 = (const __hip_bfloat16*)&q2;
      const __hip_bfloat16* w4 = (const __hip_bfloat16*)&wr;
      alignas(8) __hip_bfloat16 hb[4];
#pragma unroll
      for (int r = 0; r < 4; r++) {
        const float hv = siluf(acc1[fr][fc][r] + __bfloat162float(c1[r]) + __bfloat162float(c2[r]));
        hb[r] = __float2bfloat16(hv);
        pw[fc] += hv * __bfloat162float(w4[r]);
      }
      *(uint2*)&Hsh[(kc * 64 + (row ^ swz(kc & 3))) * 8 + off] = *(const uint2*)hb;
      *(uint2*)(g.h_out + (size_t)(row0 + row) * HIDc + nb) = *(const uint2*)hb;
    }
  }

  // ---- wp reduce (wps aliased at Apan+16KB, above phase-2 B-dbuf region)
  float (*wps)[64] = (float(*)[64])&Apan[8192];
#pragma unroll
  for (int fc = 0; fc < 4; fc++) {
    pw[fc] += __shfl_xor(pw[fc], 16);
    pw[fc] += __shfl_xor(pw[fc], 32);
  }
  if (lane < 16) {
#pragma unroll
    for (int fc = 0; fc < 4; fc++) wps[wave][fc * 16 + lane] = pw[fc];
  }
  __syncthreads();   // h + wps visible; W2s(0),(1) landed
  if (tid < 64) {
    const float s = wps[0][tid] + wps[1][tid] + wps[2][tid] + wps[3][tid];
    const float wpt = tanhf(s + g.b2L[384]);
#pragma unroll
    for (int c = 0; c < 3; c++)
      g.mp[(size_t)(row0 + tid) * 3 + c] = wpt * g.rn[(size_t)(row0 + tid) * 3 + c];
  }

  // ---- phase 2: out2 = h @ W2s; barrier-free dbuf {Bsh0, Apan-lo}, 2-ahead
  f32x4 acc2[4][4] = {};
  for (int t = 0; t < T2; ++t) {
    if (t + 1 < T2) wait_vm4(); else wait_vm0();
    unsigned short* curb = (t & 1) ? Apan : Bsh0;
    bf16x8 afr[4], bfr[4];
#pragma unroll
    for (int f = 0; f < 4; f++) {
      const int kc = t * 4 + lhi;        // kc & 3 == lhi
      afr[f] = *(const bf16x8*)&Hsh[(kc * 64 + ((f * 16 + l16) ^ swz(lhi))) * 8];
      bfr[f] = *(const bf16x8*)&curb[bpos(lhi, wave * 64 + f * 16 + l16) * 8];
    }
    wait_lgkm0();                      // frags in regs before overwrite
    if (t + 2 < T2) issueW(g.W2s, t + 2, curb);
#pragma unroll
    for (int fr = 0; fr < 4; fr++)
#pragma unroll
      for (int fc = 0; fc < 4; fc++)
        acc2[fr][fc] = __builtin_amdgcn_mfma_f32_16x16x32_bf16(afr[fr], bfr[fc], acc2[fr][fc], 0, 0, 0);
  }

  // ---- epilogue-2: wv | e_new
#pragma unroll
  for (int fr = 0; fr < 4; fr++) {
#pragma unroll
    for (int fc = 0; fc < 4; fc++) {
      const int n = wave * 64 + fc * 16 + l16;
#pragma unroll
      for (int r = 0; r < 4; r++) {
        const int row = row0 + fr * 16 + lhi * 4 + r;
        const float valf = acc2[fr][fc][r];
        if (n < 128) {
          g.wv_out[(size_t)row * 128 + n] = __float2bfloat16(valf + g.b2L[256 + n]);
        } else {
          const float sv = siluf(valf + g.b2L[257 + n]);   // e_new cols = W2 cols 385..512
          g.e_bf_out[(size_t)row * ED + (n - 128)] = __float2bfloat16(sv);
          if (g.write_e_f32) g.e_f32_out[(size_t)row * ED + (n - 128)] = sv;
        }
      }
    }
  }
}

// ---- LayerNorm. 4 nodes/block, wave per node.
__global__ __launch_bounds__(256) void ln_k(const float* __restrict__ s,
                                            const float* __restrict__ gl, const float* __restrict__ bl,
                                            __hip_bfloat16* __restrict__ s_ln) {
  const int wave = threadIdx.x >> 6, lane = threadIdx.x & 63;
  const int node = blockIdx.x * 4 + wave;
  const float* srow = s + (size_t)node * SD;
  float x[4], sum = 0.f, sq = 0.f;
#pragma unroll
  for (int i = 0; i < 4; i++) { x[i] = srow[lane * 4 + i]; sum += x[i]; sq += x[i] * x[i]; }
#pragma unroll
  for (int off = 1; off < 64; off <<= 1) { sum += __shfl_xor(sum, off); sq += __shfl_xor(sq, off); }
  const float mu = sum * (1.0f / SD);
  const float var = sq * (1.0f / SD) - mu * mu;
  const float rstd = rsqrtf(var + 1e-5f);
#pragma unroll
  for (int i = 0; i < 4; i++) {
    const int c = lane * 4 + i;
    s_ln[(size_t)node * SD + c] = __float2bfloat16(gl[c] * (x[i] - mu) * rstd + bl[c]);
  }
}

// ---- per-edge attrs: rn + bf16 tail block [NE][32] = {d,a,pn_src,pn_tgt,0,...}
__global__ void edge_attr_k(const float* __restrict__ p, const int* __restrict__ src, const int* __restrict__ tgt,
                            float* __restrict__ rn, __hip_bfloat16* __restrict__ tail) {
  const int e = blockIdx.x * blockDim.x + threadIdx.x;
  if (e >= NE) return;
  const int s_ = src[e], t_ = tgt[e];
  const float sx = p[s_ * 3], sy = p[s_ * 3 + 1], sz = p[s_ * 3 + 2];
  const float tx = p[t_ * 3], ty = p[t_ * 3 + 1], tz = p[t_ * 3 + 2];
  const float rx = tx - sx, ry = ty - sy, rz = tz - sz;
  const float a = tx * sx + ty * sy + tz * sz;
  const float rr = rx * rx + ry * ry + rz * rz;
  const float d = sqrtf(fmaxf(rr, 1e-6f));
  const float inv = 1.0f / (1.0f + d);
  rn[e * 3] = rx * inv; rn[e * 3 + 1] = ry * inv; rn[e * 3 + 2] = rz * inv;
  alignas(16) __hip_bfloat16 t8[8];
  t8[0] = __float2bfloat16(d);
  t8[1] = __float2bfloat16(a);
  t8[2] = __float2bfloat16(sqrtf(sx * sx + sy * sy + sz * sz));
  t8[3] = __float2bfloat16(sqrtf(tx * tx + ty * ty + tz * tz));
  t8[4] = t8[5] = t8[6] = t8[7] = __float2bfloat16(0.0f);
  __hip_bfloat16* tp = tail + (size_t)e * 32;
  uint4 z; z.x = z.y = z.z = z.w = 0;
  *(uint4*)tp = *(const uint4*)t8;
  *(uint4*)(tp + 8) = z;
  *(uint4*)(tp + 16) = z;
  *(uint4*)(tp + 24) = z;
}

__global__ void cvt_e_k(const float* __restrict__ e, __hip_bfloat16* __restrict__ ebf) {
  const int i = blockIdx.x * blockDim.x + threadIdx.x;
  const float* p = e + (size_t)i * 8;
  alignas(16) __hip_bfloat16 t8[8];
#pragma unroll
  for (int j = 0; j < 8; j++) t8[j] = __float2bfloat16(p[j]);
  *(uint4*)(ebf + (size_t)i * 8) = *(const uint4*)t8;
}

__global__ void count_k(const int* __restrict__ tgt, int* __restrict__ rawcnt) {
  const int e = blockIdx.x * blockDim.x + threadIdx.x;
  if (e < NE) atomicAdd(&rawcnt[tgt[e]], 1);
}

__global__ __launch_bounds__(256) void scan_k(const int* __restrict__ rawcnt, int* __restrict__ off) {
  __shared__ int ts[256];
  const int tid = threadIdx.x;
  const int base = tid * 32;
  int local[32];
  int s = 0;
#pragma unroll
  for (int i = 0; i < 32; i++) { local[i] = s; s += rawcnt[base + i]; }
  ts[tid] = s;
  __syncthreads();
  if (tid == 0) {
    int acc = 0;
    for (int i = 0; i < 256; i++) { int t = ts[i]; ts[i] = acc; acc += t; }
    off[NN] = acc;
  }
  __syncthreads();
  const int pre = ts[tid];
#pragma unroll
  for (int i = 0; i < 32; i++) off[base + i] = pre + local[i];
}

__global__ void scatter_k(const int* __restrict__ tgt, const int* __restrict__ off,
                          int* __restrict__ cursor, int* __restrict__ eperm) {
  const int e = blockIdx.x * blockDim.x + threadIdx.x;
  if (e < NE) {
    const int t = tgt[e];
    const int r = atomicAdd(&cursor[t], 1);
    eperm[off[t] + r] = e;
  }
}

// ---- CSR aggregation: one block (256 thr) per node. v ping-pong (old -> new).
__global__ __launch_bounds__(256) void agg_k(const int* __restrict__ off, const int* __restrict__ eperm,
                                             const int* __restrict__ srcp,
                                             const __hip_bfloat16* __restrict__ h,
                                             const __hip_bfloat16* __restrict__ wv,
                                             const float* __restrict__ mp,
                                             const float* __restrict__ rn,
                                             const float* __restrict__ v_old,
                                             float* __restrict__ v_new,
                                             float* __restrict__ Hagg,
                                             float* __restrict__ p_o,
                                             int hasv) {
  const int n = blockIdx.x;
  const int c = threadIdx.x;
  const int e0 = off[n], e1 = off[n + 1];
  const int c3 = c >> 6, ln = c & 63;
  float hs = 0.f, vs = 0.f, ps = 0.f;
  for (int j = e0; j < e1; j++) {
    const int e = eperm[j];
    hs += __bfloat162float(h[(size_t)e * HIDc + c]);
    if (c < 192) {
      float mv = __bfloat162float(wv[(size_t)e * 128 + 64 + ln]) * rn[(size_t)e * 3 + c3];
      if (hasv) mv += __bfloat162float(wv[(size_t)e * 128 + ln]) * v_old[(size_t)srcp[e] * 192 + c];
      vs += mv;
    } else if (c < 195) {
      ps += mp[(size_t)e * 3 + (c - 192)];
    }
  }
  Hagg[(size_t)n * HIDc + c] = hs;
  const float inv = 1.0f / fmaxf((float)(e1 - e0), 1.0f);
  if (c < 192)      v_new[(size_t)n * 192 + c] = v_old[(size_t)n * 192 + c] + vs * inv;
  else if (c < 195) p_o[n * 3 + (c - 192)]    += ps * inv;
}

__global__ void zero_k(float* __restrict__ ptr, int n) {
  const int i = blockIdx.x * blockDim.x + threadIdx.x;
  if (i < n) ptr[i] = 0.f;
}

// ---- weight prep -> swizzled streams: chunk p of k-step t holds
// W^T[n][t*32 + kc*8 .. +8) with kc = p>>8, n = (p&255) ^ swz(kc).
__global__ void prep_w1abs_k(const float* __restrict__ W1, __hip_bfloat16* __restrict__ W1aS,
                             __hip_bfloat16* __restrict__ W1bS) {
  const int idx = blockIdx.x * blockDim.x + threadIdx.x;
  if (idx >= NL * T2 * 1024) return;
  const int p = idx & 1023, t = (idx >> 10) % T2, l = idx / (T2 * 1024);
  const int kc = p >> 8, n = (p & 255) ^ swz(kc);
  alignas(16) __hip_bfloat16 a8[8], b8[8];
#pragma unroll
  for (int j = 0; j < 8; j++) {
    const int k = t * 32 + kc * 8 + j;   // 0..255
    a8[j] = __float2bfloat16(W1[((size_t)l * DINc + k) * HIDc + n]);
    b8[j] = __float2bfloat16(W1[((size_t)l * DINc + 256 + k) * HIDc + n]);
  }
  *(uint4*)(W1aS + (size_t)idx * 8) = *(const uint4*)a8;
  *(uint4*)(W1bS + (size_t)idx * 8) = *(const uint4*)b8;
}

__global__ void prep_w1es_k(const float* __restrict__ W1, __hip_bfloat16* __restrict__ W1eS) {
  const int idx = blockIdx.x * blockDim.x + threadIdx.x;
  if (idx >= NL * TE * 1024) return;
  const int p = idx & 1023, t = (idx >> 10) % TE, l = idx / (TE * 1024);
  const int kc = p >> 8, n = (p & 255) ^ swz(kc);
  alignas(16) __hip_bfloat16 e8[8];
#pragma unroll
  for (int j = 0; j < 8; j++) {
    const int k = t * 32 + kc * 8 + j;   // 0..159
    const int row = (k < 128) ? (512 + k) : ((k < 132) ? (640 + (k - 128)) : -1);
    e8[j] = __float2bfloat16(row >= 0 ? W1[((size_t)l * DINc + row) * HIDc + n] : 0.f);
  }
  *(uint4*)(W1eS + (size_t)idx * 8) = *(const uint4*)e8;
}

__global__ void prep_w2s_k(const float* __restrict__ W2, __hip_bfloat16* __restrict__ W2sS,
                           __hip_bfloat16* __restrict__ W2aS) {
  const int idx = blockIdx.x * blockDim.x + threadIdx.x;
  if (idx >= NL * T2 * 1024) return;
  const int p = idx & 1023, t = (idx >> 10) & 7, l = idx >> 13;
  const int kc = p >> 8, n = (p & 255) ^ swz(kc);
  const float* W2l = W2 + (size_t)l * HIDc * DOUTc;
  const int cs = (n < 128) ? (256 + n) : (257 + n);  // wv1|wv2 then e_new (skip col 384)
  alignas(16) __hip_bfloat16 s8[8], a8[8];
#pragma unroll
  for (int j = 0; j < 8; j++) {
    const int k = t * 32 + kc * 8 + j;
    s8[j] = __float2bfloat16(W2l[(size_t)k * DOUTc + cs]);
    a8[j] = __float2bfloat16(W2l[(size_t)k * DOUTc + n]);
  }
  *(uint4*)(W2sS + (size_t)idx * 8) = *(const uint4*)s8;
  *(uint4*)(W2aS + (size_t)idx * 8) = *(const uint4*)a8;
}

__global__ void prep_uts_k(const float* __restrict__ U1, const float* __restrict__ U2,
                           __hip_bfloat16* __restrict__ U1S, __hip_bfloat16* __restrict__ U2S) {
  const int idx = blockIdx.x * blockDim.x + threadIdx.x;
  if (idx >= NL * T2 * 1024) return;
  const int p = idx & 1023, t = (idx >> 10) & 7, l = idx >> 13;
  const int kc = p >> 8, n = (p & 255) ^ swz(kc);
  alignas(16) __hip_bfloat16 u1[8], u2[8];
#pragma unroll
  for (int j = 0; j < 8; j++) {
    const int k = t * 32 + kc * 8 + j;
    u1[j] = __float2bfloat16(U1[((size_t)l * HIDc + k) * HIDc + n]);
    u2[j] = __float2bfloat16(U2[((size_t)l * HIDc + k) * HIDc + n]);
  }
  *(uint4*)(U1S + (size_t)idx * 8) = *(const uint4*)u1;
  *(uint4*)(U2S + (size_t)idx * 8) = *(const uint4*)u2;
}

__global__ void prep_w384_k(const float* __restrict__ W2, __hip_bfloat16* __restrict__ w384) {
  const int idx = blockIdx.x * blockDim.x + threadIdx.x;
  if (idx >= NL * HIDc) return;
  const int k = idx & 255, l = idx >> 8;
  w384[idx] = __float2bfloat16(W2[((size_t)l * HIDc + k) * DOUTc + 384]);
}

}  // namespace

extern "C" void kernel_launch(void* const* d_in, const int* in_sizes, int n_in,
                              void* d_out, int out_size, void* d_ws, size_t ws_size,
                              hipStream_t stream) {
  (void)in_sizes; (void)n_in; (void)out_size; (void)ws_size;
  const float* s_in = (const float*)d_in[0];
  const float* v_in = (const float*)d_in[1];
  const float* p_in = (const float*)d_in[2];
  const float* e_in = (const float*)d_in[3];
  const int*   ei   = (const int*)d_in[4];
  const float* ln_g = (const float*)d_in[5];
  const float* ln_b = (const float*)d_in[6];
  const float* W1   = (const float*)d_in[7];
  const float* b1   = (const float*)d_in[8];
  const float* W2   = (const float*)d_in[9];
  const float* b2   = (const float*)d_in[10];
  const float* U1   = (const float*)d_in[11];
  const float* bU1  = (const float*)d_in[12];
  const float* U2   = (const float*)d_in[13];
  const float* bU2  = (const float*)d_in[14];

  float* s_o = (float*)d_out;
  float* v_o = s_o + (size_t)NN * SD;
  float* e_o = v_o + (size_t)NN * 192;
  float* p_o = e_o + (size_t)NE * ED;

  const int* srcp = ei;
  const int* tgtp = ei + NE;

  char* wp = (char*)d_ws;
  auto alloc = [&](size_t bytes) -> char* {
    char* r = wp; wp += (bytes + 255) & ~(size_t)255; return r;
  };
  __hip_bfloat16* s_ln = (__hip_bfloat16*)alloc((size_t)NN * SD * 2);
  __hip_bfloat16* hbuf = (__hip_bfloat16*)alloc((size_t)NE * HIDc * 2);
  __hip_bfloat16* ebf  = (__hip_bfloat16*)alloc((size_t)NE * ED * 2);
  __hip_bfloat16* tbuf = (__hip_bfloat16*)alloc((size_t)NN * HIDc * 2);
  __hip_bfloat16* wvbuf= (__hip_bfloat16*)alloc((size_t)NE * 128 * 2);
  __hip_bfloat16* tailb= (__hip_bfloat16*)alloc((size_t)NE * 32 * 2);
  __hip_bfloat16* p1buf= (__hip_bfloat16*)alloc((size_t)NN * SD * 2);
  __hip_bfloat16* p2buf= (__hip_bfloat16*)alloc((size_t)NN * SD * 2);
  float* rnbuf = (float*)alloc((size_t)NE * 3 * 4);
  float* Hagg  = (float*)alloc((size_t)NN * SD * 4);
  float* vprev = (float*)alloc((size_t)NN * 192 * 4);
  float* mpbuf = (float*)alloc((size_t)NE * 3 * 4);
  float* zerobias = (float*)alloc(256 * 4);
  int*   rawcnt= (int*)alloc((size_t)NN * 4);
  int*   offb  = (int*)alloc((size_t)(NN + 1) * 4);
  int*   cursor= (int*)alloc((size_t)NN * 4);
  int*   eperm = (int*)alloc((size_t)NE * 4);
  __hip_bfloat16* W1aS = (__hip_bfloat16*)alloc((size_t)NL * T2 * 1024 * 8 * 2);
  __hip_bfloat16* W1bS = (__hip_bfloat16*)alloc((size_t)NL * T2 * 1024 * 8 * 2);
  __hip_bfloat16* W1eS = (__hip_bfloat16*)alloc((size_t)NL * TE * 1024 * 8 * 2);
  __hip_bfloat16* W2sS = (__hip_bfloat16*)alloc((size_t)NL * T2 * 1024 * 8 * 2);
  __hip_bfloat16* W2aS = (__hip_bfloat16*)alloc((size_t)NL * T2 * 1024 * 8 * 2);
  __hip_bfloat16* U1S  = (__hip_bfloat16*)alloc((size_t)NL * T2 * 1024 * 8 * 2);
  __hip_bfloat16* U2S  = (__hip_bfloat16*)alloc((size_t)NL * T2 * 1024 * 8 * 2);
  __hip_bfloat16* w384 = (__hip_bfloat16*)alloc((size_t)NL * HIDc * 2);

  hipMemcpyAsync(s_o, s_in, (size_t)NN * SD * 4, hipMemcpyDeviceToDevice, stream);
  hipMemcpyAsync(vprev, v_in, (size_t)NN * 192 * 4, hipMemcpyDeviceToDevice, stream);
  hipMemcpyAsync(p_o, p_in, (size_t)NN * 3 * 4, hipMemcpyDeviceToDevice, stream);

  prep_w1abs_k<<<(NL * T2 * 1024 + 255) / 256, 256, 0, stream>>>(W1, W1aS, W1bS);
  prep_w1es_k<<<(NL * TE * 1024 + 255) / 256, 256, 0, stream>>>(W1, W1eS);
  prep_w2s_k<<<(NL * T2 * 1024 + 255) / 256, 256, 0, stream>>>(W2, W2sS, W2aS);
  prep_uts_k<<<(NL * T2 * 1024 + 255) / 256, 256, 0, stream>>>(U1, U2, U1S, U2S);
  prep_w384_k<<<(NL * HIDc + 255) / 256, 256, 0, stream>>>(W2, w384);
  cvt_e_k<<<NE * ED / 8 / 256, 256, 0, stream>>>(e_in, ebf);
  zero_k<<<1, 256, 0, stream>>>(zerobias, 256);

  // ---- CSR build (once; edge_index layer-invariant)
  zero_k<<<(NN + 255) / 256, 256, 0, stream>>>((float*)rawcnt, NN);
  zero_k<<<(NN + 255) / 256, 256, 0, stream>>>((float*)cursor, NN);
  count_k<<<NE / 256, 256, 0, stream>>>(tgtp, rawcnt);
  scan_k<<<1, 256, 0, stream>>>(rawcnt, offb);
  scatter_k<<<NE / 256, 256, 0, stream>>>(tgtp, offb, cursor, eperm);

  for (int l = 0; l < NL; l++) {
    ln_k<<<NN / 4, 256, 0, stream>>>(s_o, ln_g + l * SD, ln_b + l * SD, s_ln);
    edge_attr_k<<<NE / 256, 256, 0, stream>>>(p_o, srcp, tgtp, rnbuf, tailb);

    // P1 = s_ln @ W1a + b1 ; P2 = s_ln @ W1b  (single dual launch, 256 blocks)
    GemmArgs gp{};
    gp.Wt = W1aS + (size_t)l * T2 * 1024 * 8; gp.bias = b1 + l * HIDc; gp.bf_out = p1buf;
    gp.Wtb = W1bS + (size_t)l * T2 * 1024 * 8; gp.biasb = zerobias; gp.bf_outb = p2buf;
    gp.Abf = s_ln; gp.dual = 1;
    gemm_k<MODE_LIN, SRC_BF16, 256, 64><<<2 * NN / 64, 256, 0, stream>>>(gp);

    // fused edge kernel: h + out2
    FusedArgs gf{};
    gf.W1e = W1eS + (size_t)l * TE * 1024 * 8;
    gf.W2s = W2sS + (size_t)l * T2 * 1024 * 8;
    gf.b2L = b2 + l * DOUTc;
    gf.src = srcp; gf.tgt = tgtp; gf.e_bf = ebf; gf.tail = tailb;
    gf.p1 = p1buf; gf.p2 = p2buf; gf.w384 = w384 + l * HIDc;
    gf.rn = rnbuf; gf.mp = mpbuf;
    gf.h_out = hbuf; gf.wv_out = wvbuf; gf.e_bf_out = ebf; gf.e_f32_out = e_o;
    gf.write_e_f32 = (l == NL - 1) ? 1 : 0;
    fused_k<<<NE / 64, 256, 0, stream>>>(gf);

    // v ping-pong: l even reads vprev writes v_o; l odd reads v_o writes vprev.
    // 5 layers -> final write lands in v_o.
    const float* vold = (l & 1) ? (const float*)v_o : (const float*)vprev;
    float* vnew = (l & 1) ? vprev : v_o;
    agg_k<<<NN, 256, 0, stream>>>(offb, eperm, srcp, hbuf, wvbuf, mpbuf, rnbuf,
                                  vold, vnew, Hagg, p_o, (l > 0) ? 1 : 0);

    GemmArgs g3{};
    g3.Wt = W2aS + (size_t)l * T2 * 1024 * 8; g3.bias = b2 + l * DOUTc;
    g3.Af32 = Hagg; g3.s_out = s_o; g3.rawcnt = rawcnt;
    gemm_k<MODE_SADD, SRC_F32, 256, 32><<<NN / 32, 256, 0, stream>>>(g3);

    if (l < NL - 1) {
      GemmArgs g4{};
      g4.Wt = U1S + (size_t)l * T2 * 1024 * 8; g4.bias = bU1 + l * HIDc;
      g4.Af32 = s_o; g4.bf_out = tbuf;
      gemm_k<MODE_H, SRC_F32, 256, 32><<<NN / 32, 256, 0, stream>>>(g4);

      GemmArgs g5{};
      g5.Wt = U2S + (size_t)l * T2 * 1024 * 8; g5.bias = bU2 + l * HIDc;
      g5.Abf = tbuf; g5.s_out = s_o;
      gemm_k<MODE_SADD2, SRC_BF16, 256, 32><<<NN / 32, 256, 0, stream>>>(g5);
    }
  }
}

// Round 11
// 1148.485 us; speedup vs baseline: 3.2097x; 1.1897x over previous
//
#include <hip/hip_runtime.h>
#include <hip/hip_bf16.h>

namespace {

constexpr int NN   = 8192;    // nodes
constexpr int NE   = 131072;  // edges
constexpr int SD   = 256;     // SDIM
constexpr int ED   = 128;     // EDIM
constexpr int NL   = 5;       // layers
constexpr int DINc = 644;     // 2*SD + ED + 4
constexpr int KE   = 160;     // edge-GEMM K: 128 e + 4 scalars + pad
constexpr int TE   = 5;       // KE/32
constexpr int T2   = 8;       // 256/32
constexpr int DOUTc= 513;
constexpr int HIDc = 256;

typedef __bf16 bf16x8 __attribute__((ext_vector_type(8)));
typedef float  f32x4  __attribute__((ext_vector_type(4)));

__device__ __forceinline__ float siluf(float x) { return x / (1.0f + __expf(-x)); }

// async global->LDS, 16B/lane. LDS dest is wave-uniform base (+lane*16 in HW).
__device__ __forceinline__ void gl_lds16(const void* gsrc, void* lds_uniform_base) {
  __builtin_amdgcn_global_load_lds(
      (const __attribute__((address_space(1))) unsigned int*)gsrc,
      (__attribute__((address_space(3))) unsigned int*)lds_uniform_base, 16, 0, 0);
}

__device__ __forceinline__ void wait_vm4() {
  asm volatile("s_waitcnt vmcnt(4)" ::: "memory");
  __builtin_amdgcn_sched_barrier(0);
}
__device__ __forceinline__ void wait_vm0() {
  asm volatile("s_waitcnt vmcnt(0)" ::: "memory");
  __builtin_amdgcn_sched_barrier(0);
}

// bank-group swizzle: (5x)&7 is a permutation on 0..7.
__device__ __host__ __forceinline__ int swz(int kc) { return (kc * 5) & 7; }
__device__ __forceinline__ int apos(int kc, int row) { return kc * 64  + (row ^ swz(kc)); }
__device__ __forceinline__ int bpos(int kc, int n)   { return kc * 256 + (n   ^ swz(kc)); }

enum { MODE_H = 0, MODE_SADD = 2, MODE_SADD2 = 3, MODE_LIN = 4 };
enum { SRC_BF16 = 1, SRC_F32 = 2 };

struct GemmArgs {
  const __hip_bfloat16* Wt;     // swizzled B stream: [T][1024 chunks][8 bf16]
  const float* bias;
  const __hip_bfloat16* Abf;    // SRC_BF16 source, [M][K]
  const float* Af32;            // SRC_F32 source, [M][K]
  __hip_bfloat16* bf_out;
  float* s_out;                 // d_out s region (RMW)
  const int* rawcnt;
  // dual-launch (MODE_LIN): second half of grid uses these
  const __hip_bfloat16* Wtb;
  const float* biasb;
  __hip_bfloat16* bf_outb;
  int dual;
};

__device__ __forceinline__ uint4 cvt8f(const float* p) {
  alignas(16) __hip_bfloat16 t8[8];
#pragma unroll
  for (int i = 0; i < 8; i++) t8[i] = __float2bfloat16(p[i]);
  return *(const uint4*)t8;
}

__device__ __forceinline__ float dot8u(const uint4& a, const __hip_bfloat16* w) {
  const __hip_bfloat16* ap = (const __hip_bfloat16*)&a;
  float s = 0.f;
#pragma unroll
  for (int j = 0; j < 8; j++) s += __bfloat162float(ap[j]) * __bfloat162float(w[j]);
  return s;
}

// BM rows/block, BN=256, 4 waves. A-panel staged once; barrier-free K-loop
// (B slices wave-private; counted vmcnt dbuf).
template<int MODE, int SRC, int KTOT, int BM>
__global__ __launch_bounds__(256) void gemm_k(GemmArgs g) {
  constexpr int T = KTOT / 32;
  constexpr int NC = KTOT / 8;            // chunks per row
  constexpr int RPT = 256 / BM;           // chunk-lanes per row (4 or 8)
  constexpr int RMASK = RPT - 1;
  __shared__ alignas(16) unsigned short Apan[NC * BM * 8];
  __shared__ alignas(16) unsigned short Bsh[2][4 * 256 * 8];    // 32 KB
  const int tid = threadIdx.x, lane = tid & 63, wave = tid >> 6;
  const int l16 = lane & 15, lhi = lane >> 4;
  const __hip_bfloat16* wtp = g.Wt;
  const float* biasp = g.bias;
  __hip_bfloat16* outp = g.bf_out;
  int blk = blockIdx.x;
  if constexpr (MODE == MODE_LIN) {
    const int half = gridDim.x >> 1;
    if (g.dual && blk >= half) { blk -= half; wtp = g.Wtb; biasp = g.biasb; outp = g.bf_outb; }
  }
  const int row0 = blk * BM;
  const int ar = tid / RPT, aq = tid % RPT;
  const int arow = row0 + ar;
  f32x4 acc[BM / 16][4] = {};

  auto issueB = [&](int t, int buf) {
    const __hip_bfloat16* src = wtp + (size_t)t * 1024 * 8;
    unsigned short* dst = &Bsh[buf][0];
#pragma unroll
    for (int i = 0; i < 4; i++)
      gl_lds16(src + (size_t)(i * 256 + wave * 64 + lane) * 8, dst + (i * 256 + wave * 64) * 8);
  };

  issueB(0, 0);
  // ---- stage whole A panel once: chunk c = j*RPT+aq of row ar
#pragma unroll
  for (int j = 0; j < NC / RPT; j++) {
    const int c = j * RPT + aq;
    uint4 o;
    if constexpr (SRC == SRC_BF16) o = *(const uint4*)(g.Abf + (size_t)arow * KTOT + c * 8);
    else                           o = cvt8f(g.Af32 + (size_t)arow * KTOT + c * 8);
    *(uint4*)&Apan[(c * BM + (ar ^ swz(aq))) * 8] = o;
  }
  __syncthreads();   // A panel visible; B(0) landed

  int cur = 0;
  for (int t = 0; t < T; ++t) {
    if (t + 1 < T) { issueB(t + 1, cur ^ 1); wait_vm4(); }
    else           { wait_vm0(); }
    bf16x8 bfr[4];
#pragma unroll
    for (int f = 0; f < 4; f++)
      bfr[f] = *(const bf16x8*)&Bsh[cur][bpos(lhi, wave * 64 + f * 16 + l16) * 8];
#pragma unroll
    for (int fr = 0; fr < BM / 16; fr++) {
      const int kc = t * 4 + lhi;
      const bf16x8 afr = *(const bf16x8*)&Apan[(kc * BM + ((fr * 16 + l16) ^ swz(kc & RMASK))) * 8];
#pragma unroll
      for (int fc = 0; fc < 4; fc++)
        acc[fr][fc] = __builtin_amdgcn_mfma_f32_16x16x32_bf16(afr, bfr[fc], acc[fr][fc], 0, 0, 0);
    }
    cur ^= 1;
  }

  // ---- epilogue
#pragma unroll
  for (int fr = 0; fr < BM / 16; fr++) {
#pragma unroll
    for (int fc = 0; fc < 4; fc++) {
      const int n = wave * 64 + fc * 16 + l16;
#pragma unroll
      for (int r = 0; r < 4; r++) {
        const int row = row0 + fr * 16 + lhi * 4 + r;
        const float valf = acc[fr][fc][r];
        if constexpr (MODE == MODE_H) {
          outp[(size_t)row * HIDc + n] = __float2bfloat16(siluf(valf + biasp[n]));
        } else if constexpr (MODE == MODE_LIN) {
          outp[(size_t)row * HIDc + n] = __float2bfloat16(valf + biasp[n]);
        } else if constexpr (MODE == MODE_SADD) {
          const float rc = (float)g.rawcnt[row];
          g.s_out[(size_t)row * SD + n] += valf + rc * biasp[n];
        } else {  // MODE_SADD2
          g.s_out[(size_t)row * SD + n] += valf + biasp[n];
        }
      }
    }
  }
}

// ==== fused edge kernel (R8 structure — measured best at 133us) ====
// h = silu([e|tail]@W1e + P1[src] + P2[tgt]); out2 = h@W2s.
// Phase-1: per-step barriers, Bsh[2] dbuf; psum preloaded to regs -> Hsh.
// Phase-2: barrier-free, Bsh[2] dbuf, counted vmcnt(4).
// h/wv/mp written at rank[e] (CSR position) so agg_k reads are sequential.
struct FusedArgs {
  const __hip_bfloat16* W1e;
  const __hip_bfloat16* W2s;
  const float* b2L;
  const int* src; const int* tgt;
  const int* rank;              // [NE] CSR position of edge e
  const __hip_bfloat16* e_bf;
  const __hip_bfloat16* tail;
  const __hip_bfloat16* p1;
  const __hip_bfloat16* p2;
  const __hip_bfloat16* w384;
  const float* rn;
  float* mp;                    // [NE][3] out, PERMUTED
  __hip_bfloat16* h_out;        // [NE][256], PERMUTED
  __hip_bfloat16* wv_out;       // [NE][128], PERMUTED
  __hip_bfloat16* e_bf_out;     // [NE][128], edge order
  float* e_f32_out;             // d_out e region, edge order
  int write_e_f32;
};

__global__ __launch_bounds__(256) void fused_k(FusedArgs g) {
  __shared__ alignas(16) unsigned short Ash[4 * 64 * 8];        // 4 KB (edge A)
  __shared__ alignas(16) unsigned short Bsh[2][4 * 256 * 8];    // 32 KB (W stream dbuf)
  __shared__ alignas(16) unsigned short Hsh[32 * 64 * 8];       // 32 KB (psum -> h)
  __shared__ float wps[4][64];
  __shared__ int Rk[64];
  const int tid = threadIdx.x, lane = tid & 63, wave = tid >> 6;
  const int l16 = lane & 15, lhi = lane >> 4;
  const int row0 = blockIdx.x * 64;
  const int ar = tid >> 2, aq = tid & 3;
  const int arow = row0 + ar;
  const int sn = g.src[arow], tn = g.tgt[arow];

  auto issueW = [&](const __hip_bfloat16* W, int t, int buf) {
    const __hip_bfloat16* src = W + (size_t)t * 1024 * 8;
    unsigned short* dst = &Bsh[buf][0];
#pragma unroll
    for (int i = 0; i < 4; i++)
      gl_lds16(src + (size_t)(i * 256 + wave * 64 + lane) * 8, dst + (i * 256 + wave * 64) * 8);
  };
  auto loadA = [&](int t, uint4& o) {
    const int kq = t * 32 + aq * 8;
    if (kq < 128) o = *(const uint4*)(g.e_bf + (size_t)arow * ED + kq);
    else          o = *(const uint4*)(g.tail + (size_t)arow * 32 + (kq - 128));
  };

  uint4 a;
  loadA(0, a);
  issueW(g.W1e, 0, 0);
  if (tid < 64) Rk[tid] = g.rank[row0 + tid];

  // ---- stage Psum = P1[sn] + P2[tn] into Hsh [32 kc][64 row][8]; chunk c = j*4+aq
#pragma unroll
  for (int j = 0; j < 8; j++) {
    const int c = j * 4 + aq;            // c & 3 == aq
    uint4 r1 = *(const uint4*)(g.p1 + (size_t)sn * SD + c * 8);
    uint4 r2 = *(const uint4*)(g.p2 + (size_t)tn * SD + c * 8);
    const __hip_bfloat16* h1 = (const __hip_bfloat16*)&r1;
    const __hip_bfloat16* h2 = (const __hip_bfloat16*)&r2;
    alignas(16) __hip_bfloat16 o8[8];
#pragma unroll
    for (int m = 0; m < 8; m++)
      o8[m] = __float2bfloat16(__bfloat162float(h1[m]) + __bfloat162float(h2[m]));
    *(uint4*)&Hsh[(c * 64 + (ar ^ swz(aq))) * 8] = *(const uint4*)o8;
  }

  // ---- phase 1: SWAPPED operands -> D[n][row] (thread holds 4 consecutive n per row)
  f32x4 acc1[4][4] = {};
  int cur = 0;
  for (int t = 0; t < TE; ++t) {
    *(uint4*)&Ash[apos(aq, ar) * 8] = a;
    __syncthreads();
    if (t + 1 < TE) { issueW(g.W1e, t + 1, cur ^ 1); loadA(t + 1, a); }
    bf16x8 wfr[4], efr[4];
#pragma unroll
    for (int f = 0; f < 4; f++) {
      wfr[f] = *(const bf16x8*)&Bsh[cur][bpos(lhi, wave * 64 + f * 16 + l16) * 8];
      efr[f] = *(const bf16x8*)&Ash[apos(lhi, f * 16 + l16) * 8];
    }
#pragma unroll
    for (int fr = 0; fr < 4; fr++)
#pragma unroll
      for (int fc = 0; fc < 4; fc++)
        acc1[fr][fc] = __builtin_amdgcn_mfma_f32_16x16x32_bf16(wfr[fr], efr[fc], acc1[fr][fc], 0, 0, 0);
    __syncthreads();
    cur ^= 1;
  }

  issueW(g.W2s, 0, 0);   // prefetch phase-2 B step 0 under the epilogue

  // ---- epilogue-1: h = silu(acc1 + psum); Hsh in-place; global h (PERMUTED); wp partials
  float pw[4] = {0.f, 0.f, 0.f, 0.f};
#pragma unroll
  for (int fr = 0; fr < 4; fr++) {
    const int nb = wave * 64 + fr * 16 + lhi * 4;   // n base (4-aligned)
    const int kc = nb >> 3, off = nb & 7;
    uint2 wr = *(const uint2*)(g.w384 + nb);
    const __hip_bfloat16* w4 = (const __hip_bfloat16*)&wr;
#pragma unroll
    for (int fc = 0; fc < 4; fc++) {
      const int row = fc * 16 + l16;
      unsigned short* slot = &Hsh[(kc * 64 + (row ^ swz(kc & 3))) * 8 + off];
      uint2 pr = *(const uint2*)slot;
      const __hip_bfloat16* pp = (const __hip_bfloat16*)&pr;
      alignas(8) __hip_bfloat16 hb[4];
#pragma unroll
      for (int r = 0; r < 4; r++) {
        const float hv = siluf(acc1[fr][fc][r] + __bfloat162float(pp[r]));
        hb[r] = __float2bfloat16(hv);
        pw[fc] += hv * __bfloat162float(w4[r]);
      }
      *(uint2*)slot = *(const uint2*)hb;
      *(uint2*)(g.h_out + (size_t)Rk[row] * HIDc + nb) = *(const uint2*)hb;
    }
  }

  // ---- wp reduce: sum over lhi (lanes +16,+32), then across waves via LDS
#pragma unroll
  for (int fc = 0; fc < 4; fc++) {
    pw[fc] += __shfl_xor(pw[fc], 16);
    pw[fc] += __shfl_xor(pw[fc], 32);
  }
  if (lane < 16) {
#pragma unroll
    for (int fc = 0; fc < 4; fc++) wps[wave][fc * 16 + lane] = pw[fc];
  }
  __syncthreads();   // h in Hsh visible; wps visible; W2s(0) landed
  if (tid < 64) {
    const float s = wps[0][tid] + wps[1][tid] + wps[2][tid] + wps[3][tid];
    const float wpt = tanhf(s + g.b2L[384]);
    const int rk = Rk[tid];
#pragma unroll
    for (int c = 0; c < 3; c++)
      g.mp[(size_t)rk * 3 + c] = wpt * g.rn[(size_t)(row0 + tid) * 3 + c];
  }

  // ---- phase 2: out2 = h @ W2s. Barrier-free; Bsh[2] dbuf, counted vmcnt(4).
  f32x4 acc2[4][4] = {};
  cur = 0;
  for (int t = 0; t < T2; ++t) {
    if (t + 1 < T2) { issueW(g.W2s, t + 1, cur ^ 1); wait_vm4(); }
    else            { wait_vm0(); }
    bf16x8 afr[4], bfr[4];
#pragma unroll
    for (int f = 0; f < 4; f++) {
      const int kc = t * 4 + lhi;        // kc & 3 == lhi
      afr[f] = *(const bf16x8*)&Hsh[(kc * 64 + ((f * 16 + l16) ^ swz(lhi))) * 8];
      bfr[f] = *(const bf16x8*)&Bsh[cur][bpos(lhi, wave * 64 + f * 16 + l16) * 8];
    }
#pragma unroll
    for (int fr = 0; fr < 4; fr++)
#pragma unroll
      for (int fc = 0; fc < 4; fc++)
        acc2[fr][fc] = __builtin_amdgcn_mfma_f32_16x16x32_bf16(afr[fr], bfr[fc], acc2[fr][fc], 0, 0, 0);
    cur ^= 1;
  }

  // ---- epilogue-2: wv (PERMUTED) | e_new (edge order)
#pragma unroll
  for (int fr = 0; fr < 4; fr++) {
#pragma unroll
    for (int fc = 0; fc < 4; fc++) {
      const int n = wave * 64 + fc * 16 + l16;
#pragma unroll
      for (int r = 0; r < 4; r++) {
        const int lr = fr * 16 + lhi * 4 + r;
        const int row = row0 + lr;
        const float valf = acc2[fr][fc][r];
        if (n < 128) {
          g.wv_out[(size_t)Rk[lr] * 128 + n] = __float2bfloat16(valf + g.b2L[256 + n]);
        } else {
          const float sv = siluf(valf + g.b2L[257 + n]);   // e_new cols = W2 cols 385..512
          g.e_bf_out[(size_t)row * ED + (n - 128)] = __float2bfloat16(sv);
          if (g.write_e_f32) g.e_f32_out[(size_t)row * ED + (n - 128)] = sv;
        }
      }
    }
  }
}

// ---- LayerNorm. 4 nodes/block, wave per node.
__global__ __launch_bounds__(256) void ln_k(const float* __restrict__ s,
                                            const float* __restrict__ gl, const float* __restrict__ bl,
                                            __hip_bfloat16* __restrict__ s_ln) {
  const int wave = threadIdx.x >> 6, lane = threadIdx.x & 63;
  const int node = blockIdx.x * 4 + wave;
  const float* srow = s + (size_t)node * SD;
  float x[4], sum = 0.f, sq = 0.f;
#pragma unroll
  for (int i = 0; i < 4; i++) { x[i] = srow[lane * 4 + i]; sum += x[i]; sq += x[i] * x[i]; }
#pragma unroll
  for (int off = 1; off < 64; off <<= 1) { sum += __shfl_xor(sum, off); sq += __shfl_xor(sq, off); }
  const float mu = sum * (1.0f / SD);
  const float var = sq * (1.0f / SD) - mu * mu;
  const float rstd = rsqrtf(var + 1e-5f);
#pragma unroll
  for (int i = 0; i < 4; i++) {
    const int c = lane * 4 + i;
    s_ln[(size_t)node * SD + c] = __float2bfloat16(gl[c] * (x[i] - mu) * rstd + bl[c]);
  }
}

// ---- per-edge attrs: rn (edge order) + rnp (permuted) + bf16 tail [NE][32]
__global__ void edge_attr_k(const float* __restrict__ p, const int* __restrict__ src, const int* __restrict__ tgt,
                            const int* __restrict__ rank,
                            float* __restrict__ rn, float* __restrict__ rnp,
                            __hip_bfloat16* __restrict__ tail) {
  const int e = blockIdx.x * blockDim.x + threadIdx.x;
  if (e >= NE) return;
  const int s_ = src[e], t_ = tgt[e];
  const float sx = p[s_ * 3], sy = p[s_ * 3 + 1], sz = p[s_ * 3 + 2];
  const float tx = p[t_ * 3], ty = p[t_ * 3 + 1], tz = p[t_ * 3 + 2];
  const float rx = tx - sx, ry = ty - sy, rz = tz - sz;
  const float a = tx * sx + ty * sy + tz * sz;
  const float rr = rx * rx + ry * ry + rz * rz;
  const float d = sqrtf(fmaxf(rr, 1e-6f));
  const float inv = 1.0f / (1.0f + d);
  const float r0 = rx * inv, r1 = ry * inv, r2 = rz * inv;
  rn[e * 3] = r0; rn[e * 3 + 1] = r1; rn[e * 3 + 2] = r2;
  const int rk = rank[e];
  rnp[rk * 3] = r0; rnp[rk * 3 + 1] = r1; rnp[rk * 3 + 2] = r2;
  alignas(16) __hip_bfloat16 t8[8];
  t8[0] = __float2bfloat16(d);
  t8[1] = __float2bfloat16(a);
  t8[2] = __float2bfloat16(sqrtf(sx * sx + sy * sy + sz * sz));
  t8[3] = __float2bfloat16(sqrtf(tx * tx + ty * ty + tz * tz));
  t8[4] = t8[5] = t8[6] = t8[7] = __float2bfloat16(0.0f);
  __hip_bfloat16* tp = tail + (size_t)e * 32;
  uint4 z; z.x = z.y = z.z = z.w = 0;
  *(uint4*)tp = *(const uint4*)t8;
  *(uint4*)(tp + 8) = z;
  *(uint4*)(tp + 16) = z;
  *(uint4*)(tp + 24) = z;
}

__global__ void cvt_e_k(const float* __restrict__ e, __hip_bfloat16* __restrict__ ebf) {
  const int i = blockIdx.x * blockDim.x + threadIdx.x;
  const float* p = e + (size_t)i * 8;
  alignas(16) __hip_bfloat16 t8[8];
#pragma unroll
  for (int j = 0; j < 8; j++) t8[j] = __float2bfloat16(p[j]);
  *(uint4*)(ebf + (size_t)i * 8) = *(const uint4*)t8;
}

__global__ void count_k(const int* __restrict__ tgt, int* __restrict__ rawcnt) {
  const int e = blockIdx.x * blockDim.x + threadIdx.x;
  if (e < NE) atomicAdd(&rawcnt[tgt[e]], 1);
}

__global__ __launch_bounds__(256) void scan_k(const int* __restrict__ rawcnt, int* __restrict__ off) {
  __shared__ int ts[256];
  const int tid = threadIdx.x;
  const int base = tid * 32;
  int local[32];
  int s = 0;
#pragma unroll
  for (int i = 0; i < 32; i++) { local[i] = s; s += rawcnt[base + i]; }
  ts[tid] = s;
  __syncthreads();
  if (tid == 0) {
    int acc = 0;
    for (int i = 0; i < 256; i++) { int t = ts[i]; ts[i] = acc; acc += t; }
    off[NN] = acc;
  }
  __syncthreads();
  const int pre = ts[tid];
#pragma unroll
  for (int i = 0; i < 32; i++) off[base + i] = pre + local[i];
}

// ---- scatter: rank[e] = CSR position; psrc[pos] = src[e]
__global__ void scatter_k(const int* __restrict__ tgt, const int* __restrict__ srcp,
                          const int* __restrict__ off,
                          int* __restrict__ cursor, int* __restrict__ rank, int* __restrict__ psrc) {
  const int e = blockIdx.x * blockDim.x + threadIdx.x;
  if (e < NE) {
    const int t = tgt[e];
    const int pos = off[t] + atomicAdd(&cursor[t], 1);
    rank[e] = pos;
    psrc[pos] = srcp[e];
  }
}

// ---- CSR aggregation: one block (256 thr) per node. All edge-payload reads
// (h, wv, mp, rnp) are SEQUENTIAL (producers wrote at rank[e]); only the
// v_old[psrc[j]] gather remains. 2-way unrolled for ILP.
__global__ __launch_bounds__(256) void agg_k(const int* __restrict__ off, const int* __restrict__ psrc,
                                             const __hip_bfloat16* __restrict__ h,
                                             const __hip_bfloat16* __restrict__ wv,
                                             const float* __restrict__ mp,
                                             const float* __restrict__ rnp,
                                             const float* __restrict__ v_old,
                                             float* __restrict__ v_new,
                                             float* __restrict__ Hagg,
                                             float* __restrict__ p_o,
                                             int hasv) {
  const int n = blockIdx.x;
  const int c = threadIdx.x;
  const int e0 = off[n], e1 = off[n + 1];
  const int c3 = c >> 6, ln = c & 63;
  float hs = 0.f, vs = 0.f, ps = 0.f;
  int j = e0;
  for (; j + 2 <= e1; j += 2) {
    const float h0 = __bfloat162float(h[(size_t)j * HIDc + c]);
    const float h1 = __bfloat162float(h[(size_t)(j + 1) * HIDc + c]);
    hs += h0 + h1;
    if (c < 192) {
      const int s0 = psrc[j], s1 = psrc[j + 1];
      float m0 = __bfloat162float(wv[(size_t)j * 128 + 64 + ln]) * rnp[j * 3 + c3];
      float m1 = __bfloat162float(wv[(size_t)(j + 1) * 128 + 64 + ln]) * rnp[(j + 1) * 3 + c3];
      if (hasv) {
        m0 += __bfloat162float(wv[(size_t)j * 128 + ln]) * v_old[(size_t)s0 * 192 + c];
        m1 += __bfloat162float(wv[(size_t)(j + 1) * 128 + ln]) * v_old[(size_t)s1 * 192 + c];
      }
      vs += m0 + m1;
    } else if (c < 195) {
      ps += mp[j * 3 + (c - 192)] + mp[(j + 1) * 3 + (c - 192)];
    }
  }
  for (; j < e1; j++) {
    hs += __bfloat162float(h[(size_t)j * HIDc + c]);
    if (c < 192) {
      float mv = __bfloat162float(wv[(size_t)j * 128 + 64 + ln]) * rnp[j * 3 + c3];
      if (hasv) mv += __bfloat162float(wv[(size_t)j * 128 + ln]) * v_old[(size_t)psrc[j] * 192 + c];
      vs += mv;
    } else if (c < 195) {
      ps += mp[j * 3 + (c - 192)];
    }
  }
  Hagg[(size_t)n * HIDc + c] = hs;
  const float inv = 1.0f / fmaxf((float)(e1 - e0), 1.0f);
  if (c < 192)      v_new[(size_t)n * 192 + c] = v_old[(size_t)n * 192 + c] + vs * inv;
  else if (c < 195) p_o[n * 3 + (c - 192)]    += ps * inv;
}

__global__ void zero_k(float* __restrict__ ptr, int n) {
  const int i = blockIdx.x * blockDim.x + threadIdx.x;
  if (i < n) ptr[i] = 0.f;
}

// ---- weight prep -> swizzled streams: chunk p of k-step t holds
// W^T[n][t*32 + kc*8 .. +8) with kc = p>>8, n = (p&255) ^ swz(kc).
__global__ void prep_w1abs_k(const float* __restrict__ W1, __hip_bfloat16* __restrict__ W1aS,
                             __hip_bfloat16* __restrict__ W1bS) {
  const int idx = blockIdx.x * blockDim.x + threadIdx.x;
  if (idx >= NL * T2 * 1024) return;
  const int p = idx & 1023, t = (idx >> 10) % T2, l = idx / (T2 * 1024);
  const int kc = p >> 8, n = (p & 255) ^ swz(kc);
  alignas(16) __hip_bfloat16 a8[8], b8[8];
#pragma unroll
  for (int j = 0; j < 8; j++) {
    const int k = t * 32 + kc * 8 + j;   // 0..255
    a8[j] = __float2bfloat16(W1[((size_t)l * DINc + k) * HIDc + n]);
    b8[j] = __float2bfloat16(W1[((size_t)l * DINc + 256 + k) * HIDc + n]);
  }
  *(uint4*)(W1aS + (size_t)idx * 8) = *(const uint4*)a8;
  *(uint4*)(W1bS + (size_t)idx * 8) = *(const uint4*)b8;
}

__global__ void prep_w1es_k(const float* __restrict__ W1, __hip_bfloat16* __restrict__ W1eS) {
  const int idx = blockIdx.x * blockDim.x + threadIdx.x;
  if (idx >= NL * TE * 1024) return;
  const int p = idx & 1023, t = (idx >> 10) % TE, l = idx / (TE * 1024);
  const int kc = p >> 8, n = (p & 255) ^ swz(kc);
  alignas(16) __hip_bfloat16 e8[8];
#pragma unroll
  for (int j = 0; j < 8; j++) {
    const int k = t * 32 + kc * 8 + j;   // 0..159
    const int row = (k < 128) ? (512 + k) : ((k < 132) ? (640 + (k - 128)) : -1);
    e8[j] = __float2bfloat16(row >= 0 ? W1[((size_t)l * DINc + row) * HIDc + n] : 0.f);
  }
  *(uint4*)(W1eS + (size_t)idx * 8) = *(const uint4*)e8;
}

__global__ void prep_w2s_k(const float* __restrict__ W2, __hip_bfloat16* __restrict__ W2sS,
                           __hip_bfloat16* __restrict__ W2aS) {
  const int idx = blockIdx.x * blockDim.x + threadIdx.x;
  if (idx >= NL * T2 * 1024) return;
  const int p = idx & 1023, t = (idx >> 10) & 7, l = idx >> 13;
  const int kc = p >> 8, n = (p & 255) ^ swz(kc);
  const float* W2l = W2 + (size_t)l * HIDc * DOUTc;
  const int cs = (n < 128) ? (256 + n) : (257 + n);  // wv1|wv2 then e_new (skip col 384)
  alignas(16) __hip_bfloat16 s8[8], a8[8];
#pragma unroll
  for (int j = 0; j < 8; j++) {
    const int k = t * 32 + kc * 8 + j;
    s8[j] = __float2bfloat16(W2l[(size_t)k * DOUTc + cs]);
    a8[j] = __float2bfloat16(W2l[(size_t)k * DOUTc + n]);
  }
  *(uint4*)(W2sS + (size_t)idx * 8) = *(const uint4*)s8;
  *(uint4*)(W2aS + (size_t)idx * 8) = *(const uint4*)a8;
}

__global__ void prep_uts_k(const float* __restrict__ U1, const float* __restrict__ U2,
                           __hip_bfloat16* __restrict__ U1S, __hip_bfloat16* __restrict__ U2S) {
  const int idx = blockIdx.x * blockDim.x + threadIdx.x;
  if (idx >= NL * T2 * 1024) return;
  const int p = idx & 1023, t = (idx >> 10) & 7, l = idx >> 13;
  const int kc = p >> 8, n = (p & 255) ^ swz(kc);
  alignas(16) __hip_bfloat16 u1[8], u2[8];
#pragma unroll
  for (int j = 0; j < 8; j++) {
    const int k = t * 32 + kc * 8 + j;
    u1[j] = __float2bfloat16(U1[((size_t)l * HIDc + k) * HIDc + n]);
    u2[j] = __float2bfloat16(U2[((size_t)l * HIDc + k) * HIDc + n]);
  }
  *(uint4*)(U1S + (size_t)idx * 8) = *(const uint4*)u1;
  *(uint4*)(U2S + (size_t)idx * 8) = *(const uint4*)u2;
}

__global__ void prep_w384_k(const float* __restrict__ W2, __hip_bfloat16* __restrict__ w384) {
  const int idx = blockIdx.x * blockDim.x + threadIdx.x;
  if (idx >= NL * HIDc) return;
  const int k = idx & 255, l = idx >> 8;
  w384[idx] = __float2bfloat16(W2[((size_t)l * HIDc + k) * DOUTc + 384]);
}

}  // namespace

extern "C" void kernel_launch(void* const* d_in, const int* in_sizes, int n_in,
                              void* d_out, int out_size, void* d_ws, size_t ws_size,
                              hipStream_t stream) {
  (void)in_sizes; (void)n_in; (void)out_size; (void)ws_size;
  const float* s_in = (const float*)d_in[0];
  const float* v_in = (const float*)d_in[1];
  const float* p_in = (const float*)d_in[2];
  const float* e_in = (const float*)d_in[3];
  const int*   ei   = (const int*)d_in[4];
  const float* ln_g = (const float*)d_in[5];
  const float* ln_b = (const float*)d_in[6];
  const float* W1   = (const float*)d_in[7];
  const float* b1   = (const float*)d_in[8];
  const float* W2   = (const float*)d_in[9];
  const float* b2   = (const float*)d_in[10];
  const float* U1   = (const float*)d_in[11];
  const float* bU1  = (const float*)d_in[12];
  const float* U2   = (const float*)d_in[13];
  const float* bU2  = (const float*)d_in[14];

  float* s_o = (float*)d_out;
  float* v_o = s_o + (size_t)NN * SD;
  float* e_o = v_o + (size_t)NN * 192;
  float* p_o = e_o + (size_t)NE * ED;

  const int* srcp = ei;
  const int* tgtp = ei + NE;

  char* wp = (char*)d_ws;
  auto alloc = [&](size_t bytes) -> char* {
    char* r = wp; wp += (bytes + 255) & ~(size_t)255; return r;
  };
  __hip_bfloat16* s_ln = (__hip_bfloat16*)alloc((size_t)NN * SD * 2);
  __hip_bfloat16* hbuf = (__hip_bfloat16*)alloc((size_t)NE * HIDc * 2);
  __hip_bfloat16* ebf  = (__hip_bfloat16*)alloc((size_t)NE * ED * 2);
  __hip_bfloat16* tbuf = (__hip_bfloat16*)alloc((size_t)NN * HIDc * 2);
  __hip_bfloat16* wvbuf= (__hip_bfloat16*)alloc((size_t)NE * 128 * 2);
  __hip_bfloat16* tailb= (__hip_bfloat16*)alloc((size_t)NE * 32 * 2);
  __hip_bfloat16* p1buf= (__hip_bfloat16*)alloc((size_t)NN * SD * 2);
  __hip_bfloat16* p2buf= (__hip_bfloat16*)alloc((size_t)NN * SD * 2);
  float* rnbuf = (float*)alloc((size_t)NE * 3 * 4);
  float* rnpbuf= (float*)alloc((size_t)NE * 3 * 4);
  float* Hagg  = (float*)alloc((size_t)NN * SD * 4);
  float* vprev = (float*)alloc((size_t)NN * 192 * 4);
  float* mpbuf = (float*)alloc((size_t)NE * 3 * 4);
  float* zerobias = (float*)alloc(256 * 4);
  int*   rawcnt= (int*)alloc((size_t)NN * 4);
  int*   offb  = (int*)alloc((size_t)(NN + 1) * 4);
  int*   cursor= (int*)alloc((size_t)NN * 4);
  int*   rankb = (int*)alloc((size_t)NE * 4);
  int*   psrcb = (int*)alloc((size_t)NE * 4);
  __hip_bfloat16* W1aS = (__hip_bfloat16*)alloc((size_t)NL * T2 * 1024 * 8 * 2);
  __hip_bfloat16* W1bS = (__hip_bfloat16*)alloc((size_t)NL * T2 * 1024 * 8 * 2);
  __hip_bfloat16* W1eS = (__hip_bfloat16*)alloc((size_t)NL * TE * 1024 * 8 * 2);
  __hip_bfloat16* W2sS = (__hip_bfloat16*)alloc((size_t)NL * T2 * 1024 * 8 * 2);
  __hip_bfloat16* W2aS = (__hip_bfloat16*)alloc((size_t)NL * T2 * 1024 * 8 * 2);
  __hip_bfloat16* U1S  = (__hip_bfloat16*)alloc((size_t)NL * T2 * 1024 * 8 * 2);
  __hip_bfloat16* U2S  = (__hip_bfloat16*)alloc((size_t)NL * T2 * 1024 * 8 * 2);
  __hip_bfloat16* w384 = (__hip_bfloat16*)alloc((size_t)NL * HIDc * 2);

  hipMemcpyAsync(s_o, s_in, (size_t)NN * SD * 4, hipMemcpyDeviceToDevice, stream);
  hipMemcpyAsync(vprev, v_in, (size_t)NN * 192 * 4, hipMemcpyDeviceToDevice, stream);
  hipMemcpyAsync(p_o, p_in, (size_t)NN * 3 * 4, hipMemcpyDeviceToDevice, stream);

  prep_w1abs_k<<<(NL * T2 * 1024 + 255) / 256, 256, 0, stream>>>(W1, W1aS, W1bS);
  prep_w1es_k<<<(NL * TE * 1024 + 255) / 256, 256, 0, stream>>>(W1, W1eS);
  prep_w2s_k<<<(NL * T2 * 1024 + 255) / 256, 256, 0, stream>>>(W2, W2sS, W2aS);
  prep_uts_k<<<(NL * T2 * 1024 + 255) / 256, 256, 0, stream>>>(U1, U2, U1S, U2S);
  prep_w384_k<<<(NL * HIDc + 255) / 256, 256, 0, stream>>>(W2, w384);
  cvt_e_k<<<NE * ED / 8 / 256, 256, 0, stream>>>(e_in, ebf);
  zero_k<<<1, 256, 0, stream>>>(zerobias, 256);

  // ---- CSR build (once; edge_index layer-invariant)
  zero_k<<<(NN + 255) / 256, 256, 0, stream>>>((float*)rawcnt, NN);
  zero_k<<<(NN + 255) / 256, 256, 0, stream>>>((float*)cursor, NN);
  count_k<<<NE / 256, 256, 0, stream>>>(tgtp, rawcnt);
  scan_k<<<1, 256, 0, stream>>>(rawcnt, offb);
  scatter_k<<<NE / 256, 256, 0, stream>>>(tgtp, srcp, offb, cursor, rankb, psrcb);

  for (int l = 0; l < NL; l++) {
    ln_k<<<NN / 4, 256, 0, stream>>>(s_o, ln_g + l * SD, ln_b + l * SD, s_ln);
    edge_attr_k<<<NE / 256, 256, 0, stream>>>(p_o, srcp, tgtp, rankb, rnbuf, rnpbuf, tailb);

    // P1 = s_ln @ W1a + b1 ; P2 = s_ln @ W1b  (single dual launch, 256 blocks)
    GemmArgs gp{};
    gp.Wt = W1aS + (size_t)l * T2 * 1024 * 8; gp.bias = b1 + l * HIDc; gp.bf_out = p1buf;
    gp.Wtb = W1bS + (size_t)l * T2 * 1024 * 8; gp.biasb = zerobias; gp.bf_outb = p2buf;
    gp.Abf = s_ln; gp.dual = 1;
    gemm_k<MODE_LIN, SRC_BF16, 256, 64><<<2 * NN / 64, 256, 0, stream>>>(gp);

    // fused edge kernel: h + out2 (h/wv/mp written at rank[e])
    FusedArgs gf{};
    gf.W1e = W1eS + (size_t)l * TE * 1024 * 8;
    gf.W2s = W2sS + (size_t)l * T2 * 1024 * 8;
    gf.b2L = b2 + l * DOUTc;
    gf.src = srcp; gf.tgt = tgtp; gf.rank = rankb;
    gf.e_bf = ebf; gf.tail = tailb;
    gf.p1 = p1buf; gf.p2 = p2buf; gf.w384 = w384 + l * HIDc;
    gf.rn = rnbuf; gf.mp = mpbuf;
    gf.h_out = hbuf; gf.wv_out = wvbuf; gf.e_bf_out = ebf; gf.e_f32_out = e_o;
    gf.write_e_f32 = (l == NL - 1) ? 1 : 0;
    fused_k<<<NE / 64, 256, 0, stream>>>(gf);

    // v ping-pong: l even reads vprev writes v_o; l odd reads v_o writes vprev.
    // 5 layers -> final write lands in v_o.
    const float* vold = (l & 1) ? (const float*)v_o : (const float*)vprev;
    float* vnew = (l & 1) ? vprev : v_o;
    agg_k<<<NN, 256, 0, stream>>>(offb, psrcb, hbuf, wvbuf, mpbuf, rnpbuf,
                                  vold, vnew, Hagg, p_o, (l > 0) ? 1 : 0);

    GemmArgs g3{};
    g3.Wt = W2aS + (size_t)l * T2 * 1024 * 8; g3.bias = b2 + l * DOUTc;
    g3.Af32 = Hagg; g3.s_out = s_o; g3.rawcnt = rawcnt;
    gemm_k<MODE_SADD, SRC_F32, 256, 32><<<NN / 32, 256, 0, stream>>>(g3);

    if (l < NL - 1) {
      GemmArgs g4{};
      g4.Wt = U1S + (size_t)l * T2 * 1024 * 8; g4.bias = bU1 + l * HIDc;
      g4.Af32 = s_o; g4.bf_out = tbuf;
      gemm_k<MODE_H, SRC_F32, 256, 32><<<NN / 32, 256, 0, stream>>>(g4);

      GemmArgs g5{};
      g5.Wt = U2S + (size_t)l * T2 * 1024 * 8; g5.bias = bU2 + l * HIDc;
      g5.Abf = tbuf; g5.s_out = s_o;
      gemm_k<MODE_SADD2, SRC_BF16, 256, 32><<<NN / 32, 256, 0, stream>>>(g5);
    }
  }
}

// Round 12
// 1091.731 us; speedup vs baseline: 3.3766x; 1.0520x over previous
//
#include <hip/hip_runtime.h>
#include <hip/hip_bf16.h>

namespace {

constexpr int NN   = 8192;    // nodes
constexpr int NE   = 131072;  // edges
constexpr int SD   = 256;     // SDIM
constexpr int ED   = 128;     // EDIM
constexpr int NL   = 5;       // layers
constexpr int DINc = 644;     // 2*SD + ED + 4
constexpr int KE   = 160;     // edge-GEMM K: 128 e + 4 scalars + pad
constexpr int TE   = 5;       // KE/32
constexpr int T2   = 8;       // 256/32
constexpr int DOUTc= 513;
constexpr int HIDc = 256;

typedef __bf16 bf16x8 __attribute__((ext_vector_type(8)));
typedef float  f32x4  __attribute__((ext_vector_type(4)));

__device__ __forceinline__ float siluf(float x) { return x / (1.0f + __expf(-x)); }

// async global->LDS, 16B/lane. LDS dest is wave-uniform base (+lane*16 in HW).
__device__ __forceinline__ void gl_lds16(const void* gsrc, void* lds_uniform_base) {
  __builtin_amdgcn_global_load_lds(
      (const __attribute__((address_space(1))) unsigned int*)gsrc,
      (__attribute__((address_space(3))) unsigned int*)lds_uniform_base, 16, 0, 0);
}

__device__ __forceinline__ void wait_vm4() {
  asm volatile("s_waitcnt vmcnt(4)" ::: "memory");
  __builtin_amdgcn_sched_barrier(0);
}
__device__ __forceinline__ void wait_vm0() {
  asm volatile("s_waitcnt vmcnt(0)" ::: "memory");
  __builtin_amdgcn_sched_barrier(0);
}

// bank-group swizzle: (5x)&7 is a permutation on 0..7.
__device__ __host__ __forceinline__ int swz(int kc) { return (kc * 5) & 7; }
__device__ __forceinline__ int apos(int kc, int row) { return kc * 64  + (row ^ swz(kc)); }
__device__ __forceinline__ int bpos(int kc, int n)   { return kc * 256 + (n   ^ swz(kc)); }

enum { MODE_LIN = 4 };
enum { SRC_BF16 = 1, SRC_F32 = 2 };

struct GemmArgs {
  const __hip_bfloat16* Wt;     // swizzled B stream: [T][1024 chunks][8 bf16]
  const float* bias;
  const __hip_bfloat16* Abf;    // SRC_BF16 source, [M][K]
  const float* Af32;            // SRC_F32 source, [M][K]
  __hip_bfloat16* bf_out;
  // dual-launch: second half of grid uses these
  const __hip_bfloat16* Wtb;
  const float* biasb;
  __hip_bfloat16* bf_outb;
  int dual;
};

__device__ __forceinline__ uint4 cvt8f(const float* p) {
  alignas(16) __hip_bfloat16 t8[8];
#pragma unroll
  for (int i = 0; i < 8; i++) t8[i] = __float2bfloat16(p[i]);
  return *(const uint4*)t8;
}

// BM rows/block, BN=256, 4 waves. A-panel staged once; barrier-free K-loop
// (B slices wave-private; counted vmcnt dbuf). Used for P1/P2 (MODE_LIN).
template<int MODE, int SRC, int KTOT, int BM>
__global__ __launch_bounds__(256) void gemm_k(GemmArgs g) {
  constexpr int T = KTOT / 32;
  constexpr int NC = KTOT / 8;            // chunks per row
  constexpr int RPT = 256 / BM;           // chunk-lanes per row
  constexpr int RMASK = RPT - 1;
  __shared__ alignas(16) unsigned short Apan[NC * BM * 8];
  __shared__ alignas(16) unsigned short Bsh[2][4 * 256 * 8];    // 32 KB
  const int tid = threadIdx.x, lane = tid & 63, wave = tid >> 6;
  const int l16 = lane & 15, lhi = lane >> 4;
  const __hip_bfloat16* wtp = g.Wt;
  const float* biasp = g.bias;
  __hip_bfloat16* outp = g.bf_out;
  int blk = blockIdx.x;
  {
    const int half = gridDim.x >> 1;
    if (g.dual && blk >= half) { blk -= half; wtp = g.Wtb; biasp = g.biasb; outp = g.bf_outb; }
  }
  const int row0 = blk * BM;
  const int ar = tid / RPT, aq = tid % RPT;
  const int arow = row0 + ar;
  f32x4 acc[BM / 16][4] = {};

  auto issueB = [&](int t, int buf) {
    const __hip_bfloat16* src = wtp + (size_t)t * 1024 * 8;
    unsigned short* dst = &Bsh[buf][0];
#pragma unroll
    for (int i = 0; i < 4; i++)
      gl_lds16(src + (size_t)(i * 256 + wave * 64 + lane) * 8, dst + (i * 256 + wave * 64) * 8);
  };

  issueB(0, 0);
#pragma unroll
  for (int j = 0; j < NC / RPT; j++) {
    const int c = j * RPT + aq;
    uint4 o;
    if constexpr (SRC == SRC_BF16) o = *(const uint4*)(g.Abf + (size_t)arow * KTOT + c * 8);
    else                           o = cvt8f(g.Af32 + (size_t)arow * KTOT + c * 8);
    *(uint4*)&Apan[(c * BM + (ar ^ swz(aq))) * 8] = o;
  }
  __syncthreads();   // A panel visible; B(0) landed

  int cur = 0;
  for (int t = 0; t < T; ++t) {
    if (t + 1 < T) { issueB(t + 1, cur ^ 1); wait_vm4(); }
    else           { wait_vm0(); }
    bf16x8 bfr[4];
#pragma unroll
    for (int f = 0; f < 4; f++)
      bfr[f] = *(const bf16x8*)&Bsh[cur][bpos(lhi, wave * 64 + f * 16 + l16) * 8];
#pragma unroll
    for (int fr = 0; fr < BM / 16; fr++) {
      const int kc = t * 4 + lhi;
      const bf16x8 afr = *(const bf16x8*)&Apan[(kc * BM + ((fr * 16 + l16) ^ swz(kc & RMASK))) * 8];
#pragma unroll
      for (int fc = 0; fc < 4; fc++)
        acc[fr][fc] = __builtin_amdgcn_mfma_f32_16x16x32_bf16(afr, bfr[fc], acc[fr][fc], 0, 0, 0);
    }
    cur ^= 1;
  }

#pragma unroll
  for (int fr = 0; fr < BM / 16; fr++) {
#pragma unroll
    for (int fc = 0; fc < 4; fc++) {
      const int n = wave * 64 + fc * 16 + l16;
#pragma unroll
      for (int r = 0; r < 4; r++) {
        const int row = row0 + fr * 16 + lhi * 4 + r;
        outp[(size_t)row * HIDc + n] = __float2bfloat16(acc[fr][fc][r] + biasp[n]);
      }
    }
  }
}

// ==== fused node-MLP kernel: 3 chained K=256 GEMMs, BM=32, swapped operands ====
// s1 = s_old + Hagg@W2a + cnt*b2 ; t = silu(s1@U1 + bU1) ; s2 = s1 + t@U2 + bU2.
// A-panel rebuilt in LDS between streams (thread owns 4 consecutive n per row).
struct Node3Args {
  const __hip_bfloat16* W2a;    // [8][1024][8] swizzled streams
  const __hip_bfloat16* U1s;
  const __hip_bfloat16* U2s;
  const float* b2L;             // b2 + l*DOUT (cols 0..255 = m_s)
  const float* bU1;
  const float* bU2;
  const float* Hagg;            // [NN][256] f32
  const int* rawcnt;
  float* s_out;                 // d_out s region (RMW)
};

template<int LAST>
__global__ __launch_bounds__(256) void node3_k(Node3Args g) {
  constexpr int BM = 32, RPT = 8, NC = 32, T = 8;
  __shared__ alignas(16) unsigned short Apan[NC * BM * 8];      // 16 KB
  __shared__ alignas(16) unsigned short Bsh[2][4 * 256 * 8];    // 32 KB
  const int tid = threadIdx.x, lane = tid & 63, wave = tid >> 6;
  const int l16 = lane & 15, lhi = lane >> 4;
  const int row0 = blockIdx.x * BM;
  const int ar = tid >> 3, aq = tid & 7;   // staging: row ar (0..31), chunk-lane aq

  auto issueB = [&](const __hip_bfloat16* W, int t, int buf) {
    const __hip_bfloat16* src = W + (size_t)t * 1024 * 8;
    unsigned short* dst = &Bsh[buf][0];
#pragma unroll
    for (int i = 0; i < 4; i++)
      gl_lds16(src + (size_t)(i * 256 + wave * 64 + lane) * 8, dst + (i * 256 + wave * 64) * 8);
  };

  // SWAPPED K-loop: acc[fr=n-blk][fc=row-blk]; D[n][row].
  f32x4 acc[4][2];
  auto kloop = [&](const __hip_bfloat16* W) {
#pragma unroll
    for (int i = 0; i < 4; i++)
#pragma unroll
      for (int j = 0; j < 2; j++) acc[i][j] = f32x4{0.f, 0.f, 0.f, 0.f};
    int cur = 0;
    for (int t = 0; t < T; ++t) {
      if (t + 1 < T) { issueB(W, t + 1, cur ^ 1); wait_vm4(); }
      else           { wait_vm0(); }
      bf16x8 wfr[4], afr[2];
#pragma unroll
      for (int f = 0; f < 4; f++)
        wfr[f] = *(const bf16x8*)&Bsh[cur][bpos(lhi, wave * 64 + f * 16 + l16) * 8];
#pragma unroll
      for (int f = 0; f < 2; f++) {
        const int kc = t * 4 + lhi;
        afr[f] = *(const bf16x8*)&Apan[(kc * BM + ((f * 16 + l16) ^ swz(kc & 7))) * 8];
      }
#pragma unroll
      for (int fr = 0; fr < 4; fr++)
#pragma unroll
        for (int fc = 0; fc < 2; fc++)
          acc[fr][fc] = __builtin_amdgcn_mfma_f32_16x16x32_bf16(wfr[fr], afr[fc], acc[fr][fc], 0, 0, 0);
      cur ^= 1;
    }
  };

  // ---- stage Hagg panel (f32 -> bf16), chunk c = j*8+aq
  issueB(g.W2a, 0, 0);
#pragma unroll
  for (int j = 0; j < NC / RPT; j++) {
    const int c = j * RPT + aq;
    uint4 o = cvt8f(g.Hagg + (size_t)(row0 + ar) * SD + c * 8);
    *(uint4*)&Apan[(c * BM + (ar ^ swz(aq))) * 8] = o;
  }
  __syncthreads();   // Apan visible; W2a(0) landed

  // ---- step A: acc = (Hagg @ W2a)[n][row]
  kloop(g.W2a);
  __syncthreads();   // all reads of Apan done -> safe to overwrite
  if constexpr (!LAST) issueB(g.U1s, 0, 0);

  // ---- epilogue A: s1 = s_old + acc + rc*b2 ; write s_o (f32x4) + Apan (bf16)
#pragma unroll
  for (int fr = 0; fr < 4; fr++) {
    const int nb = wave * 64 + fr * 16 + lhi * 4;
    const int kc = nb >> 3, off = nb & 7;
    const f32x4 b4 = *(const f32x4*)(g.b2L + nb);
#pragma unroll
    for (int fc = 0; fc < 2; fc++) {
      const int row = fc * 16 + l16;
      const float rc = (float)g.rawcnt[row0 + row];
      float* sp = g.s_out + (size_t)(row0 + row) * SD + nb;
      f32x4 sold = *(const f32x4*)sp;
      alignas(8) __hip_bfloat16 hb[4];
      f32x4 s1;
#pragma unroll
      for (int r = 0; r < 4; r++) {
        s1[r] = sold[r] + acc[fr][fc][r] + rc * b4[r];
        hb[r] = __float2bfloat16(s1[r]);
      }
      *(f32x4*)sp = s1;
      if constexpr (!LAST)
        *(uint2*)&Apan[(kc * BM + (row ^ swz(kc & 7))) * 8 + off] = *(const uint2*)hb;
    }
  }
  if constexpr (LAST) return;

  __syncthreads();   // s1 panel visible; U1(0) landed

  // ---- step B: acc = (s1 @ U1)[n][row]; t = silu(acc + bU1) -> Apan
  kloop(g.U1s);
  __syncthreads();
  issueB(g.U2s, 0, 0);
#pragma unroll
  for (int fr = 0; fr < 4; fr++) {
    const int nb = wave * 64 + fr * 16 + lhi * 4;
    const int kc = nb >> 3, off = nb & 7;
    const f32x4 b4 = *(const f32x4*)(g.bU1 + nb);
#pragma unroll
    for (int fc = 0; fc < 2; fc++) {
      const int row = fc * 16 + l16;
      alignas(8) __hip_bfloat16 hb[4];
#pragma unroll
      for (int r = 0; r < 4; r++)
        hb[r] = __float2bfloat16(siluf(acc[fr][fc][r] + b4[r]));
      *(uint2*)&Apan[(kc * BM + (row ^ swz(kc & 7))) * 8 + off] = *(const uint2*)hb;
    }
  }
  __syncthreads();   // t panel visible; U2(0) landed

  // ---- step C: acc = (t @ U2)[n][row]; s2 = s1 + acc + bU2 (s_o RMW)
  kloop(g.U2s);
#pragma unroll
  for (int fr = 0; fr < 4; fr++) {
    const int nb = wave * 64 + fr * 16 + lhi * 4;
    const f32x4 b4 = *(const f32x4*)(g.bU2 + nb);
#pragma unroll
    for (int fc = 0; fc < 2; fc++) {
      const int row = fc * 16 + l16;
      float* sp = g.s_out + (size_t)(row0 + row) * SD + nb;
      f32x4 s1 = *(const f32x4*)sp;
#pragma unroll
      for (int r = 0; r < 4; r++) s1[r] += acc[fr][fc][r] + b4[r];
      *(f32x4*)sp = s1;
    }
  }
}

// ==== fused edge kernel (R8 structure — measured best) ====
struct FusedArgs {
  const __hip_bfloat16* W1e;
  const __hip_bfloat16* W2s;
  const float* b2L;
  const int* src; const int* tgt;
  const int* rank;              // [NE] CSR position of edge e
  const __hip_bfloat16* e_bf;
  const __hip_bfloat16* tail;
  const __hip_bfloat16* p1;
  const __hip_bfloat16* p2;
  const __hip_bfloat16* w384;
  const float* rn;
  float* mp;                    // [NE][3] out, PERMUTED
  __hip_bfloat16* h_out;        // [NE][256], PERMUTED
  __hip_bfloat16* wv_out;       // [NE][128], PERMUTED
  __hip_bfloat16* e_bf_out;     // [NE][128], edge order
  float* e_f32_out;             // d_out e region, edge order
  int write_e_f32;
};

__global__ __launch_bounds__(256) void fused_k(FusedArgs g) {
  __shared__ alignas(16) unsigned short Ash[4 * 64 * 8];        // 4 KB (edge A)
  __shared__ alignas(16) unsigned short Bsh[2][4 * 256 * 8];    // 32 KB (W stream dbuf)
  __shared__ alignas(16) unsigned short Hsh[32 * 64 * 8];       // 32 KB (psum -> h)
  __shared__ float wps[4][64];
  __shared__ int Rk[64];
  const int tid = threadIdx.x, lane = tid & 63, wave = tid >> 6;
  const int l16 = lane & 15, lhi = lane >> 4;
  const int row0 = blockIdx.x * 64;
  const int ar = tid >> 2, aq = tid & 3;
  const int arow = row0 + ar;
  const int sn = g.src[arow], tn = g.tgt[arow];

  auto issueW = [&](const __hip_bfloat16* W, int t, int buf) {
    const __hip_bfloat16* src = W + (size_t)t * 1024 * 8;
    unsigned short* dst = &Bsh[buf][0];
#pragma unroll
    for (int i = 0; i < 4; i++)
      gl_lds16(src + (size_t)(i * 256 + wave * 64 + lane) * 8, dst + (i * 256 + wave * 64) * 8);
  };
  auto loadA = [&](int t, uint4& o) {
    const int kq = t * 32 + aq * 8;
    if (kq < 128) o = *(const uint4*)(g.e_bf + (size_t)arow * ED + kq);
    else          o = *(const uint4*)(g.tail + (size_t)arow * 32 + (kq - 128));
  };

  uint4 a;
  loadA(0, a);
  issueW(g.W1e, 0, 0);
  if (tid < 64) Rk[tid] = g.rank[row0 + tid];

  // ---- stage Psum = P1[sn] + P2[tn] into Hsh [32 kc][64 row][8]; chunk c = j*4+aq
#pragma unroll
  for (int j = 0; j < 8; j++) {
    const int c = j * 4 + aq;            // c & 3 == aq
    uint4 r1 = *(const uint4*)(g.p1 + (size_t)sn * SD + c * 8);
    uint4 r2 = *(const uint4*)(g.p2 + (size_t)tn * SD + c * 8);
    const __hip_bfloat16* h1 = (const __hip_bfloat16*)&r1;
    const __hip_bfloat16* h2 = (const __hip_bfloat16*)&r2;
    alignas(16) __hip_bfloat16 o8[8];
#pragma unroll
    for (int m = 0; m < 8; m++)
      o8[m] = __float2bfloat16(__bfloat162float(h1[m]) + __bfloat162float(h2[m]));
    *(uint4*)&Hsh[(c * 64 + (ar ^ swz(aq))) * 8] = *(const uint4*)o8;
  }

  // ---- phase 1: SWAPPED operands -> D[n][row]
  f32x4 acc1[4][4] = {};
  int cur = 0;
  for (int t = 0; t < TE; ++t) {
    *(uint4*)&Ash[apos(aq, ar) * 8] = a;
    __syncthreads();
    if (t + 1 < TE) { issueW(g.W1e, t + 1, cur ^ 1); loadA(t + 1, a); }
    bf16x8 wfr[4], efr[4];
#pragma unroll
    for (int f = 0; f < 4; f++) {
      wfr[f] = *(const bf16x8*)&Bsh[cur][bpos(lhi, wave * 64 + f * 16 + l16) * 8];
      efr[f] = *(const bf16x8*)&Ash[apos(lhi, f * 16 + l16) * 8];
    }
#pragma unroll
    for (int fr = 0; fr < 4; fr++)
#pragma unroll
      for (int fc = 0; fc < 4; fc++)
        acc1[fr][fc] = __builtin_amdgcn_mfma_f32_16x16x32_bf16(wfr[fr], efr[fc], acc1[fr][fc], 0, 0, 0);
    __syncthreads();
    cur ^= 1;
  }

  issueW(g.W2s, 0, 0);   // prefetch phase-2 B step 0 under the epilogue

  // ---- epilogue-1: h = silu(acc1 + psum); Hsh in-place; global h (PERMUTED); wp partials
  float pw[4] = {0.f, 0.f, 0.f, 0.f};
#pragma unroll
  for (int fr = 0; fr < 4; fr++) {
    const int nb = wave * 64 + fr * 16 + lhi * 4;   // n base (4-aligned)
    const int kc = nb >> 3, off = nb & 7;
    uint2 wr = *(const uint2*)(g.w384 + nb);
    const __hip_bfloat16* w4 = (const __hip_bfloat16*)&wr;
#pragma unroll
    for (int fc = 0; fc < 4; fc++) {
      const int row = fc * 16 + l16;
      unsigned short* slot = &Hsh[(kc * 64 + (row ^ swz(kc & 3))) * 8 + off];
      uint2 pr = *(const uint2*)slot;
      const __hip_bfloat16* pp = (const __hip_bfloat16*)&pr;
      alignas(8) __hip_bfloat16 hb[4];
#pragma unroll
      for (int r = 0; r < 4; r++) {
        const float hv = siluf(acc1[fr][fc][r] + __bfloat162float(pp[r]));
        hb[r] = __float2bfloat16(hv);
        pw[fc] += hv * __bfloat162float(w4[r]);
      }
      *(uint2*)slot = *(const uint2*)hb;
      *(uint2*)(g.h_out + (size_t)Rk[row] * HIDc + nb) = *(const uint2*)hb;
    }
  }

  // ---- wp reduce
#pragma unroll
  for (int fc = 0; fc < 4; fc++) {
    pw[fc] += __shfl_xor(pw[fc], 16);
    pw[fc] += __shfl_xor(pw[fc], 32);
  }
  if (lane < 16) {
#pragma unroll
    for (int fc = 0; fc < 4; fc++) wps[wave][fc * 16 + lane] = pw[fc];
  }
  __syncthreads();   // h in Hsh visible; wps visible; W2s(0) landed
  if (tid < 64) {
    const float s = wps[0][tid] + wps[1][tid] + wps[2][tid] + wps[3][tid];
    const float wpt = tanhf(s + g.b2L[384]);
    const int rk = Rk[tid];
#pragma unroll
    for (int c = 0; c < 3; c++)
      g.mp[(size_t)rk * 3 + c] = wpt * g.rn[(size_t)(row0 + tid) * 3 + c];
  }

  // ---- phase 2: out2 = h @ W2s. Barrier-free; Bsh[2] dbuf, counted vmcnt(4).
  f32x4 acc2[4][4] = {};
  cur = 0;
  for (int t = 0; t < T2; ++t) {
    if (t + 1 < T2) { issueW(g.W2s, t + 1, cur ^ 1); wait_vm4(); }
    else            { wait_vm0(); }
    bf16x8 afr[4], bfr[4];
#pragma unroll
    for (int f = 0; f < 4; f++) {
      const int kc = t * 4 + lhi;        // kc & 3 == lhi
      afr[f] = *(const bf16x8*)&Hsh[(kc * 64 + ((f * 16 + l16) ^ swz(lhi))) * 8];
      bfr[f] = *(const bf16x8*)&Bsh[cur][bpos(lhi, wave * 64 + f * 16 + l16) * 8];
    }
#pragma unroll
    for (int fr = 0; fr < 4; fr++)
#pragma unroll
      for (int fc = 0; fc < 4; fc++)
        acc2[fr][fc] = __builtin_amdgcn_mfma_f32_16x16x32_bf16(afr[fr], bfr[fc], acc2[fr][fc], 0, 0, 0);
    cur ^= 1;
  }

  // ---- epilogue-2: wv (PERMUTED) | e_new (edge order)
#pragma unroll
  for (int fr = 0; fr < 4; fr++) {
#pragma unroll
    for (int fc = 0; fc < 4; fc++) {
      const int n = wave * 64 + fc * 16 + l16;
#pragma unroll
      for (int r = 0; r < 4; r++) {
        const int lr = fr * 16 + lhi * 4 + r;
        const int row = row0 + lr;
        const float valf = acc2[fr][fc][r];
        if (n < 128) {
          g.wv_out[(size_t)Rk[lr] * 128 + n] = __float2bfloat16(valf + g.b2L[256 + n]);
        } else {
          const float sv = siluf(valf + g.b2L[257 + n]);   // e_new cols = W2 cols 385..512
          g.e_bf_out[(size_t)row * ED + (n - 128)] = __float2bfloat16(sv);
          if (g.write_e_f32) g.e_f32_out[(size_t)row * ED + (n - 128)] = sv;
        }
      }
    }
  }
}

// ---- LayerNorm. 4 nodes/block, wave per node.
__global__ __launch_bounds__(256) void ln_k(const float* __restrict__ s,
                                            const float* __restrict__ gl, const float* __restrict__ bl,
                                            __hip_bfloat16* __restrict__ s_ln) {
  const int wave = threadIdx.x >> 6, lane = threadIdx.x & 63;
  const int node = blockIdx.x * 4 + wave;
  const float* srow = s + (size_t)node * SD;
  float x[4], sum = 0.f, sq = 0.f;
#pragma unroll
  for (int i = 0; i < 4; i++) { x[i] = srow[lane * 4 + i]; sum += x[i]; sq += x[i] * x[i]; }
#pragma unroll
  for (int off = 1; off < 64; off <<= 1) { sum += __shfl_xor(sum, off); sq += __shfl_xor(sq, off); }
  const float mu = sum * (1.0f / SD);
  const float var = sq * (1.0f / SD) - mu * mu;
  const float rstd = rsqrtf(var + 1e-5f);
#pragma unroll
  for (int i = 0; i < 4; i++) {
    const int c = lane * 4 + i;
    s_ln[(size_t)node * SD + c] = __float2bfloat16(gl[c] * (x[i] - mu) * rstd + bl[c]);
  }
}

// ---- per-edge attrs: rn (edge order) + rnp (permuted) + bf16 tail [NE][32]
__global__ void edge_attr_k(const float* __restrict__ p, const int* __restrict__ src, const int* __restrict__ tgt,
                            const int* __restrict__ rank,
                            float* __restrict__ rn, float* __restrict__ rnp,
                            __hip_bfloat16* __restrict__ tail) {
  const int e = blockIdx.x * blockDim.x + threadIdx.x;
  if (e >= NE) return;
  const int s_ = src[e], t_ = tgt[e];
  const float sx = p[s_ * 3], sy = p[s_ * 3 + 1], sz = p[s_ * 3 + 2];
  const float tx = p[t_ * 3], ty = p[t_ * 3 + 1], tz = p[t_ * 3 + 2];
  const float rx = tx - sx, ry = ty - sy, rz = tz - sz;
  const float a = tx * sx + ty * sy + tz * sz;
  const float rr = rx * rx + ry * ry + rz * rz;
  const float d = sqrtf(fmaxf(rr, 1e-6f));
  const float inv = 1.0f / (1.0f + d);
  const float r0 = rx * inv, r1 = ry * inv, r2 = rz * inv;
  rn[e * 3] = r0; rn[e * 3 + 1] = r1; rn[e * 3 + 2] = r2;
  const int rk = rank[e];
  rnp[rk * 3] = r0; rnp[rk * 3 + 1] = r1; rnp[rk * 3 + 2] = r2;
  alignas(16) __hip_bfloat16 t8[8];
  t8[0] = __float2bfloat16(d);
  t8[1] = __float2bfloat16(a);
  t8[2] = __float2bfloat16(sqrtf(sx * sx + sy * sy + sz * sz));
  t8[3] = __float2bfloat16(sqrtf(tx * tx + ty * ty + tz * tz));
  t8[4] = t8[5] = t8[6] = t8[7] = __float2bfloat16(0.0f);
  __hip_bfloat16* tp = tail + (size_t)e * 32;
  uint4 z; z.x = z.y = z.z = z.w = 0;
  *(uint4*)tp = *(const uint4*)t8;
  *(uint4*)(tp + 8) = z;
  *(uint4*)(tp + 16) = z;
  *(uint4*)(tp + 24) = z;
}

__global__ void cvt_e_k(const float* __restrict__ e, __hip_bfloat16* __restrict__ ebf) {
  const int i = blockIdx.x * blockDim.x + threadIdx.x;
  const float* p = e + (size_t)i * 8;
  alignas(16) __hip_bfloat16 t8[8];
#pragma unroll
  for (int j = 0; j < 8; j++) t8[j] = __float2bfloat16(p[j]);
  *(uint4*)(ebf + (size_t)i * 8) = *(const uint4*)t8;
}

__global__ void count_k(const int* __restrict__ tgt, int* __restrict__ rawcnt) {
  const int e = blockIdx.x * blockDim.x + threadIdx.x;
  if (e < NE) atomicAdd(&rawcnt[tgt[e]], 1);
}

__global__ __launch_bounds__(256) void scan_k(const int* __restrict__ rawcnt, int* __restrict__ off) {
  __shared__ int ts[256];
  const int tid = threadIdx.x;
  const int base = tid * 32;
  int local[32];
  int s = 0;
#pragma unroll
  for (int i = 0; i < 32; i++) { local[i] = s; s += rawcnt[base + i]; }
  ts[tid] = s;
  __syncthreads();
  if (tid == 0) {
    int acc = 0;
    for (int i = 0; i < 256; i++) { int t = ts[i]; ts[i] = acc; acc += t; }
    off[NN] = acc;
  }
  __syncthreads();
  const int pre = ts[tid];
#pragma unroll
  for (int i = 0; i < 32; i++) off[base + i] = pre + local[i];
}

// ---- scatter: rank[e] = CSR position; psrc[pos] = src[e]
__global__ void scatter_k(const int* __restrict__ tgt, const int* __restrict__ srcp,
                          const int* __restrict__ off,
                          int* __restrict__ cursor, int* __restrict__ rank, int* __restrict__ psrc) {
  const int e = blockIdx.x * blockDim.x + threadIdx.x;
  if (e < NE) {
    const int t = tgt[e];
    const int pos = off[t] + atomicAdd(&cursor[t], 1);
    rank[e] = pos;
    psrc[pos] = srcp[e];
  }
}

// ---- CSR aggregation: one block (256 thr) per node. Sequential payload reads.
__global__ __launch_bounds__(256) void agg_k(const int* __restrict__ off, const int* __restrict__ psrc,
                                             const __hip_bfloat16* __restrict__ h,
                                             const __hip_bfloat16* __restrict__ wv,
                                             const float* __restrict__ mp,
                                             const float* __restrict__ rnp,
                                             const float* __restrict__ v_old,
                                             float* __restrict__ v_new,
                                             float* __restrict__ Hagg,
                                             float* __restrict__ p_o,
                                             int hasv) {
  const int n = blockIdx.x;
  const int c = threadIdx.x;
  const int e0 = off[n], e1 = off[n + 1];
  const int c3 = c >> 6, ln = c & 63;
  float hs = 0.f, vs = 0.f, ps = 0.f;
  int j = e0;
  for (; j + 2 <= e1; j += 2) {
    const float h0 = __bfloat162float(h[(size_t)j * HIDc + c]);
    const float h1 = __bfloat162float(h[(size_t)(j + 1) * HIDc + c]);
    hs += h0 + h1;
    if (c < 192) {
      const int s0 = psrc[j], s1 = psrc[j + 1];
      float m0 = __bfloat162float(wv[(size_t)j * 128 + 64 + ln]) * rnp[j * 3 + c3];
      float m1 = __bfloat162float(wv[(size_t)(j + 1) * 128 + 64 + ln]) * rnp[(j + 1) * 3 + c3];
      if (hasv) {
        m0 += __bfloat162float(wv[(size_t)j * 128 + ln]) * v_old[(size_t)s0 * 192 + c];
        m1 += __bfloat162float(wv[(size_t)(j + 1) * 128 + ln]) * v_old[(size_t)s1 * 192 + c];
      }
      vs += m0 + m1;
    } else if (c < 195) {
      ps += mp[j * 3 + (c - 192)] + mp[(j + 1) * 3 + (c - 192)];
    }
  }
  for (; j < e1; j++) {
    hs += __bfloat162float(h[(size_t)j * HIDc + c]);
    if (c < 192) {
      float mv = __bfloat162float(wv[(size_t)j * 128 + 64 + ln]) * rnp[j * 3 + c3];
      if (hasv) mv += __bfloat162float(wv[(size_t)j * 128 + ln]) * v_old[(size_t)psrc[j] * 192 + c];
      vs += mv;
    } else if (c < 195) {
      ps += mp[j * 3 + (c - 192)];
    }
  }
  Hagg[(size_t)n * HIDc + c] = hs;
  const float inv = 1.0f / fmaxf((float)(e1 - e0), 1.0f);
  if (c < 192)      v_new[(size_t)n * 192 + c] = v_old[(size_t)n * 192 + c] + vs * inv;
  else if (c < 195) p_o[n * 3 + (c - 192)]    += ps * inv;
}

__global__ void zero_k(float* __restrict__ ptr, int n) {
  const int i = blockIdx.x * blockDim.x + threadIdx.x;
  if (i < n) ptr[i] = 0.f;
}

// ---- weight prep -> swizzled streams: chunk p of k-step t holds
// W^T[n][t*32 + kc*8 .. +8) with kc = p>>8, n = (p&255) ^ swz(kc).
__global__ void prep_w1abs_k(const float* __restrict__ W1, __hip_bfloat16* __restrict__ W1aS,
                             __hip_bfloat16* __restrict__ W1bS) {
  const int idx = blockIdx.x * blockDim.x + threadIdx.x;
  if (idx >= NL * T2 * 1024) return;
  const int p = idx & 1023, t = (idx >> 10) % T2, l = idx / (T2 * 1024);
  const int kc = p >> 8, n = (p & 255) ^ swz(kc);
  alignas(16) __hip_bfloat16 a8[8], b8[8];
#pragma unroll
  for (int j = 0; j < 8; j++) {
    const int k = t * 32 + kc * 8 + j;   // 0..255
    a8[j] = __float2bfloat16(W1[((size_t)l * DINc + k) * HIDc + n]);
    b8[j] = __float2bfloat16(W1[((size_t)l * DINc + 256 + k) * HIDc + n]);
  }
  *(uint4*)(W1aS + (size_t)idx * 8) = *(const uint4*)a8;
  *(uint4*)(W1bS + (size_t)idx * 8) = *(const uint4*)b8;
}

__global__ void prep_w1es_k(const float* __restrict__ W1, __hip_bfloat16* __restrict__ W1eS) {
  const int idx = blockIdx.x * blockDim.x + threadIdx.x;
  if (idx >= NL * TE * 1024) return;
  const int p = idx & 1023, t = (idx >> 10) % TE, l = idx / (TE * 1024);
  const int kc = p >> 8, n = (p & 255) ^ swz(kc);
  alignas(16) __hip_bfloat16 e8[8];
#pragma unroll
  for (int j = 0; j < 8; j++) {
    const int k = t * 32 + kc * 8 + j;   // 0..159
    const int row = (k < 128) ? (512 + k) : ((k < 132) ? (640 + (k - 128)) : -1);
    e8[j] = __float2bfloat16(row >= 0 ? W1[((size_t)l * DINc + row) * HIDc + n] : 0.f);
  }
  *(uint4*)(W1eS + (size_t)idx * 8) = *(const uint4*)e8;
}

__global__ void prep_w2s_k(const float* __restrict__ W2, __hip_bfloat16* __restrict__ W2sS,
                           __hip_bfloat16* __restrict__ W2aS) {
  const int idx = blockIdx.x * blockDim.x + threadIdx.x;
  if (idx >= NL * T2 * 1024) return;
  const int p = idx & 1023, t = (idx >> 10) & 7, l = idx >> 13;
  const int kc = p >> 8, n = (p & 255) ^ swz(kc);
  const float* W2l = W2 + (size_t)l * HIDc * DOUTc;
  const int cs = (n < 128) ? (256 + n) : (257 + n);  // wv1|wv2 then e_new (skip col 384)
  alignas(16) __hip_bfloat16 s8[8], a8[8];
#pragma unroll
  for (int j = 0; j < 8; j++) {
    const int k = t * 32 + kc * 8 + j;
    s8[j] = __float2bfloat16(W2l[(size_t)k * DOUTc + cs]);
    a8[j] = __float2bfloat16(W2l[(size_t)k * DOUTc + n]);
  }
  *(uint4*)(W2sS + (size_t)idx * 8) = *(const uint4*)s8;
  *(uint4*)(W2aS + (size_t)idx * 8) = *(const uint4*)a8;
}

__global__ void prep_uts_k(const float* __restrict__ U1, const float* __restrict__ U2,
                           __hip_bfloat16* __restrict__ U1S, __hip_bfloat16* __restrict__ U2S) {
  const int idx = blockIdx.x * blockDim.x + threadIdx.x;
  if (idx >= NL * T2 * 1024) return;
  const int p = idx & 1023, t = (idx >> 10) & 7, l = idx >> 13;
  const int kc = p >> 8, n = (p & 255) ^ swz(kc);
  alignas(16) __hip_bfloat16 u1[8], u2[8];
#pragma unroll
  for (int j = 0; j < 8; j++) {
    const int k = t * 32 + kc * 8 + j;
    u1[j] = __float2bfloat16(U1[((size_t)l * HIDc + k) * HIDc + n]);
    u2[j] = __float2bfloat16(U2[((size_t)l * HIDc + k) * HIDc + n]);
  }
  *(uint4*)(U1S + (size_t)idx * 8) = *(const uint4*)u1;
  *(uint4*)(U2S + (size_t)idx * 8) = *(const uint4*)u2;
}

__global__ void prep_w384_k(const float* __restrict__ W2, __hip_bfloat16* __restrict__ w384) {
  const int idx = blockIdx.x * blockDim.x + threadIdx.x;
  if (idx >= NL * HIDc) return;
  const int k = idx & 255, l = idx >> 8;
  w384[idx] = __float2bfloat16(W2[((size_t)l * HIDc + k) * DOUTc + 384]);
}

}  // namespace

extern "C" void kernel_launch(void* const* d_in, const int* in_sizes, int n_in,
                              void* d_out, int out_size, void* d_ws, size_t ws_size,
                              hipStream_t stream) {
  (void)in_sizes; (void)n_in; (void)out_size; (void)ws_size;
  const float* s_in = (const float*)d_in[0];
  const float* v_in = (const float*)d_in[1];
  const float* p_in = (const float*)d_in[2];
  const float* e_in = (const float*)d_in[3];
  const int*   ei   = (const int*)d_in[4];
  const float* ln_g = (const float*)d_in[5];
  const float* ln_b = (const float*)d_in[6];
  const float* W1   = (const float*)d_in[7];
  const float* b1   = (const float*)d_in[8];
  const float* W2   = (const float*)d_in[9];
  const float* b2   = (const float*)d_in[10];
  const float* U1   = (const float*)d_in[11];
  const float* bU1  = (const float*)d_in[12];
  const float* U2   = (const float*)d_in[13];
  const float* bU2  = (const float*)d_in[14];

  float* s_o = (float*)d_out;
  float* v_o = s_o + (size_t)NN * SD;
  float* e_o = v_o + (size_t)NN * 192;
  float* p_o = e_o + (size_t)NE * ED;

  const int* srcp = ei;
  const int* tgtp = ei + NE;

  char* wp = (char*)d_ws;
  auto alloc = [&](size_t bytes) -> char* {
    char* r = wp; wp += (bytes + 255) & ~(size_t)255; return r;
  };
  __hip_bfloat16* s_ln = (__hip_bfloat16*)alloc((size_t)NN * SD * 2);
  __hip_bfloat16* hbuf = (__hip_bfloat16*)alloc((size_t)NE * HIDc * 2);
  __hip_bfloat16* ebf  = (__hip_bfloat16*)alloc((size_t)NE * ED * 2);
  __hip_bfloat16* wvbuf= (__hip_bfloat16*)alloc((size_t)NE * 128 * 2);
  __hip_bfloat16* tailb= (__hip_bfloat16*)alloc((size_t)NE * 32 * 2);
  __hip_bfloat16* p1buf= (__hip_bfloat16*)alloc((size_t)NN * SD * 2);
  __hip_bfloat16* p2buf= (__hip_bfloat16*)alloc((size_t)NN * SD * 2);
  float* rnbuf = (float*)alloc((size_t)NE * 3 * 4);
  float* rnpbuf= (float*)alloc((size_t)NE * 3 * 4);
  float* Hagg  = (float*)alloc((size_t)NN * SD * 4);
  float* vprev = (float*)alloc((size_t)NN * 192 * 4);
  float* mpbuf = (float*)alloc((size_t)NE * 3 * 4);
  float* zerobias = (float*)alloc(256 * 4);
  int*   rawcnt= (int*)alloc((size_t)NN * 4);
  int*   offb  = (int*)alloc((size_t)(NN + 1) * 4);
  int*   cursor= (int*)alloc((size_t)NN * 4);
  int*   rankb = (int*)alloc((size_t)NE * 4);
  int*   psrcb = (int*)alloc((size_t)NE * 4);
  __hip_bfloat16* W1aS = (__hip_bfloat16*)alloc((size_t)NL * T2 * 1024 * 8 * 2);
  __hip_bfloat16* W1bS = (__hip_bfloat16*)alloc((size_t)NL * T2 * 1024 * 8 * 2);
  __hip_bfloat16* W1eS = (__hip_bfloat16*)alloc((size_t)NL * TE * 1024 * 8 * 2);
  __hip_bfloat16* W2sS = (__hip_bfloat16*)alloc((size_t)NL * T2 * 1024 * 8 * 2);
  __hip_bfloat16* W2aS = (__hip_bfloat16*)alloc((size_t)NL * T2 * 1024 * 8 * 2);
  __hip_bfloat16* U1S  = (__hip_bfloat16*)alloc((size_t)NL * T2 * 1024 * 8 * 2);
  __hip_bfloat16* U2S  = (__hip_bfloat16*)alloc((size_t)NL * T2 * 1024 * 8 * 2);
  __hip_bfloat16* w384 = (__hip_bfloat16*)alloc((size_t)NL * HIDc * 2);

  hipMemcpyAsync(s_o, s_in, (size_t)NN * SD * 4, hipMemcpyDeviceToDevice, stream);
  hipMemcpyAsync(vprev, v_in, (size_t)NN * 192 * 4, hipMemcpyDeviceToDevice, stream);
  hipMemcpyAsync(p_o, p_in, (size_t)NN * 3 * 4, hipMemcpyDeviceToDevice, stream);

  prep_w1abs_k<<<(NL * T2 * 1024 + 255) / 256, 256, 0, stream>>>(W1, W1aS, W1bS);
  prep_w1es_k<<<(NL * TE * 1024 + 255) / 256, 256, 0, stream>>>(W1, W1eS);
  prep_w2s_k<<<(NL * T2 * 1024 + 255) / 256, 256, 0, stream>>>(W2, W2sS, W2aS);
  prep_uts_k<<<(NL * T2 * 1024 + 255) / 256, 256, 0, stream>>>(U1, U2, U1S, U2S);
  prep_w384_k<<<(NL * HIDc + 255) / 256, 256, 0, stream>>>(W2, w384);
  cvt_e_k<<<NE * ED / 8 / 256, 256, 0, stream>>>(e_in, ebf);
  zero_k<<<1, 256, 0, stream>>>(zerobias, 256);

  // ---- CSR build (once; edge_index layer-invariant)
  zero_k<<<(NN + 255) / 256, 256, 0, stream>>>((float*)rawcnt, NN);
  zero_k<<<(NN + 255) / 256, 256, 0, stream>>>((float*)cursor, NN);
  count_k<<<NE / 256, 256, 0, stream>>>(tgtp, rawcnt);
  scan_k<<<1, 256, 0, stream>>>(rawcnt, offb);
  scatter_k<<<NE / 256, 256, 0, stream>>>(tgtp, srcp, offb, cursor, rankb, psrcb);

  for (int l = 0; l < NL; l++) {
    ln_k<<<NN / 4, 256, 0, stream>>>(s_o, ln_g + l * SD, ln_b + l * SD, s_ln);
    edge_attr_k<<<NE / 256, 256, 0, stream>>>(p_o, srcp, tgtp, rankb, rnbuf, rnpbuf, tailb);

    // P1 = s_ln @ W1a + b1 ; P2 = s_ln @ W1b  (single dual launch, 256 blocks)
    GemmArgs gp{};
    gp.Wt = W1aS + (size_t)l * T2 * 1024 * 8; gp.bias = b1 + l * HIDc; gp.bf_out = p1buf;
    gp.Wtb = W1bS + (size_t)l * T2 * 1024 * 8; gp.biasb = zerobias; gp.bf_outb = p2buf;
    gp.Abf = s_ln; gp.dual = 1;
    gemm_k<MODE_LIN, SRC_BF16, 256, 64><<<2 * NN / 64, 256, 0, stream>>>(gp);

    // fused edge kernel: h + out2 (h/wv/mp written at rank[e])
    FusedArgs gf{};
    gf.W1e = W1eS + (size_t)l * TE * 1024 * 8;
    gf.W2s = W2sS + (size_t)l * T2 * 1024 * 8;
    gf.b2L = b2 + l * DOUTc;
    gf.src = srcp; gf.tgt = tgtp; gf.rank = rankb;
    gf.e_bf = ebf; gf.tail = tailb;
    gf.p1 = p1buf; gf.p2 = p2buf; gf.w384 = w384 + l * HIDc;
    gf.rn = rnbuf; gf.mp = mpbuf;
    gf.h_out = hbuf; gf.wv_out = wvbuf; gf.e_bf_out = ebf; gf.e_f32_out = e_o;
    gf.write_e_f32 = (l == NL - 1) ? 1 : 0;
    fused_k<<<NE / 64, 256, 0, stream>>>(gf);

    // v ping-pong: 5 layers -> final write lands in v_o.
    const float* vold = (l & 1) ? (const float*)v_o : (const float*)vprev;
    float* vnew = (l & 1) ? vprev : v_o;
    agg_k<<<NN, 256, 0, stream>>>(offb, psrcb, hbuf, wvbuf, mpbuf, rnpbuf,
                                  vold, vnew, Hagg, p_o, (l > 0) ? 1 : 0);

    // fused node MLP: s += Hagg@W2a + cnt*b2 ; (l<4) s += silu(s@U1+bU1)@U2+bU2
    Node3Args gn{};
    gn.W2a = W2aS + (size_t)l * T2 * 1024 * 8;
    gn.U1s = U1S + (size_t)l * T2 * 1024 * 8;
    gn.U2s = U2S + (size_t)l * T2 * 1024 * 8;
    gn.b2L = b2 + l * DOUTc; gn.bU1 = bU1 + l * HIDc; gn.bU2 = bU2 + l * HIDc;
    gn.Hagg = Hagg; gn.rawcnt = rawcnt; gn.s_out = s_o;
    if (l < NL - 1) node3_k<0><<<NN / 32, 256, 0, stream>>>(gn);
    else            node3_k<1><<<NN / 32, 256, 0, stream>>>(gn);
  }
}

// Round 13
// 1021.185 us; speedup vs baseline: 3.6099x; 1.0691x over previous
//
#include <hip/hip_runtime.h>
#include <hip/hip_bf16.h>

namespace {

constexpr int NN   = 8192;    // nodes
constexpr int NE   = 131072;  // edges
constexpr int SD   = 256;     // SDIM
constexpr int ED   = 128;     // EDIM
constexpr int NL   = 5;       // layers
constexpr int DINc = 644;     // 2*SD + ED + 4
constexpr int KE   = 160;     // edge-GEMM K: 128 e + 4 scalars + pad
constexpr int TE   = 5;       // KE/32
constexpr int T2   = 8;       // 256/32
constexpr int DOUTc= 513;
constexpr int HIDc = 256;

typedef __bf16 bf16x8 __attribute__((ext_vector_type(8)));
typedef float  f32x4  __attribute__((ext_vector_type(4)));

__device__ __forceinline__ float siluf(float x) { return x / (1.0f + __expf(-x)); }

// async global->LDS, 16B/lane. LDS dest is wave-uniform base (+lane*16 in HW).
__device__ __forceinline__ void gl_lds16(const void* gsrc, void* lds_uniform_base) {
  __builtin_amdgcn_global_load_lds(
      (const __attribute__((address_space(1))) unsigned int*)gsrc,
      (__attribute__((address_space(3))) unsigned int*)lds_uniform_base, 16, 0, 0);
}

__device__ __forceinline__ void wait_vm4() {
  asm volatile("s_waitcnt vmcnt(4)" ::: "memory");
  __builtin_amdgcn_sched_barrier(0);
}
__device__ __forceinline__ void wait_vm0() {
  asm volatile("s_waitcnt vmcnt(0)" ::: "memory");
  __builtin_amdgcn_sched_barrier(0);
}

// bank-group swizzle: (5x)&7 is a permutation on 0..7.
__device__ __host__ __forceinline__ int swz(int kc) { return (kc * 5) & 7; }
__device__ __forceinline__ int apos(int kc, int row) { return kc * 64  + (row ^ swz(kc)); }
__device__ __forceinline__ int bpos(int kc, int n)   { return kc * 256 + (n   ^ swz(kc)); }

enum { SRC_BF16 = 1 };

struct GemmArgs {
  const __hip_bfloat16* Wt;     // swizzled B stream
  const float* bias;
  const __hip_bfloat16* Abf;
  __hip_bfloat16* bf_out;
  const __hip_bfloat16* Wtb;    // dual second half
  const float* biasb;
  __hip_bfloat16* bf_outb;
  int dual;
};

__device__ __forceinline__ uint4 cvt8f(const float* p) {
  alignas(16) __hip_bfloat16 t8[8];
#pragma unroll
  for (int i = 0; i < 8; i++) t8[i] = __float2bfloat16(p[i]);
  return *(const uint4*)t8;
}

// Layer-0 P1/P2: BM=64, BN=256, dual-launch. A-panel staged once; barrier-free loop.
template<int KTOT, int BM>
__global__ __launch_bounds__(256) void gemm_k(GemmArgs g) {
  constexpr int T = KTOT / 32;
  constexpr int NC = KTOT / 8;
  constexpr int RPT = 256 / BM;
  constexpr int RMASK = RPT - 1;
  __shared__ alignas(16) unsigned short Apan[NC * BM * 8];
  __shared__ alignas(16) unsigned short Bsh[2][4 * 256 * 8];
  const int tid = threadIdx.x, lane = tid & 63, wave = tid >> 6;
  const int l16 = lane & 15, lhi = lane >> 4;
  const __hip_bfloat16* wtp = g.Wt;
  const float* biasp = g.bias;
  __hip_bfloat16* outp = g.bf_out;
  int blk = blockIdx.x;
  {
    const int half = gridDim.x >> 1;
    if (g.dual && blk >= half) { blk -= half; wtp = g.Wtb; biasp = g.biasb; outp = g.bf_outb; }
  }
  const int row0 = blk * BM;
  const int ar = tid / RPT, aq = tid % RPT;
  const int arow = row0 + ar;
  f32x4 acc[BM / 16][4] = {};

  auto issueB = [&](int t, int buf) {
    const __hip_bfloat16* src = wtp + (size_t)t * 1024 * 8;
    unsigned short* dst = &Bsh[buf][0];
#pragma unroll
    for (int i = 0; i < 4; i++)
      gl_lds16(src + (size_t)(i * 256 + wave * 64 + lane) * 8, dst + (i * 256 + wave * 64) * 8);
  };

  issueB(0, 0);
#pragma unroll
  for (int j = 0; j < NC / RPT; j++) {
    const int c = j * RPT + aq;
    uint4 o = *(const uint4*)(g.Abf + (size_t)arow * KTOT + c * 8);
    *(uint4*)&Apan[(c * BM + (ar ^ swz(aq))) * 8] = o;
  }
  __syncthreads();

  int cur = 0;
  for (int t = 0; t < T; ++t) {
    if (t + 1 < T) { issueB(t + 1, cur ^ 1); wait_vm4(); }
    else           { wait_vm0(); }
    bf16x8 bfr[4];
#pragma unroll
    for (int f = 0; f < 4; f++)
      bfr[f] = *(const bf16x8*)&Bsh[cur][bpos(lhi, wave * 64 + f * 16 + l16) * 8];
#pragma unroll
    for (int fr = 0; fr < BM / 16; fr++) {
      const int kc = t * 4 + lhi;
      const bf16x8 afr = *(const bf16x8*)&Apan[(kc * BM + ((fr * 16 + l16) ^ swz(kc & RMASK))) * 8];
#pragma unroll
      for (int fc = 0; fc < 4; fc++)
        acc[fr][fc] = __builtin_amdgcn_mfma_f32_16x16x32_bf16(afr, bfr[fc], acc[fr][fc], 0, 0, 0);
    }
    cur ^= 1;
  }

#pragma unroll
  for (int fr = 0; fr < BM / 16; fr++) {
#pragma unroll
    for (int fc = 0; fc < 4; fc++) {
      const int n = wave * 64 + fc * 16 + l16;
#pragma unroll
      for (int r = 0; r < 4; r++) {
        const int row = row0 + fr * 16 + lhi * 4 + r;
        outp[(size_t)row * HIDc + n] = __float2bfloat16(acc[fr][fc][r] + biasp[n]);
      }
    }
  }
}

// ==== fused node kernel: s-update + node MLP + next-layer LN + P1/P2 ====
// s1 = s_old + Hagg@W2a + cnt*b2; t = silu(s1@U1+bU1); s2 = s1 + t@U2 + bU2;
// (l<4) s_ln = LN_{l+1}(s2); P1 = s_ln@W1a_{l+1} + b1; P2 = s_ln@W1b_{l+1}.
struct Node3Args {
  const __hip_bfloat16* W2a;
  const __hip_bfloat16* U1s;
  const __hip_bfloat16* U2s;
  const __hip_bfloat16* W1an;   // next layer streams
  const __hip_bfloat16* W1bn;
  const float* b2L;
  const float* bU1;
  const float* bU2;
  const float* b1n;             // next layer b1
  const float* lng;             // next layer ln params
  const float* lnb;
  const float* Hagg;
  const int* rawcnt;
  float* s_out;
  __hip_bfloat16* p1;
  __hip_bfloat16* p2;
};

template<int LAST>
__global__ __launch_bounds__(256) void node3_k(Node3Args g) {
  constexpr int BM = 32, RPT = 8, NC = 32, T = 8;
  __shared__ alignas(16) unsigned short Apan[NC * BM * 8];      // 16 KB
  __shared__ alignas(16) unsigned short Bsh[2][4 * 256 * 8];    // 32 KB
  __shared__ float red[2][4][32];
  const int tid = threadIdx.x, lane = tid & 63, wave = tid >> 6;
  const int l16 = lane & 15, lhi = lane >> 4;
  const int row0 = blockIdx.x * BM;
  const int ar = tid >> 3, aq = tid & 7;

  auto issueB = [&](const __hip_bfloat16* W, int t, int buf) {
    const __hip_bfloat16* src = W + (size_t)t * 1024 * 8;
    unsigned short* dst = &Bsh[buf][0];
#pragma unroll
    for (int i = 0; i < 4; i++)
      gl_lds16(src + (size_t)(i * 256 + wave * 64 + lane) * 8, dst + (i * 256 + wave * 64) * 8);
  };

  f32x4 acc[4][2];   // SWAPPED: acc[n-blk][row-blk], D[n][row]
  auto kloop = [&](const __hip_bfloat16* W) {
#pragma unroll
    for (int i = 0; i < 4; i++)
#pragma unroll
      for (int j = 0; j < 2; j++) acc[i][j] = f32x4{0.f, 0.f, 0.f, 0.f};
    int cur = 0;
    for (int t = 0; t < T; ++t) {
      if (t + 1 < T) { issueB(W, t + 1, cur ^ 1); wait_vm4(); }
      else           { wait_vm0(); }
      bf16x8 wfr[4], afr[2];
#pragma unroll
      for (int f = 0; f < 4; f++)
        wfr[f] = *(const bf16x8*)&Bsh[cur][bpos(lhi, wave * 64 + f * 16 + l16) * 8];
#pragma unroll
      for (int f = 0; f < 2; f++) {
        const int kc = t * 4 + lhi;
        afr[f] = *(const bf16x8*)&Apan[(kc * BM + ((f * 16 + l16) ^ swz(kc & 7))) * 8];
      }
#pragma unroll
      for (int fr = 0; fr < 4; fr++)
#pragma unroll
        for (int fc = 0; fc < 2; fc++)
          acc[fr][fc] = __builtin_amdgcn_mfma_f32_16x16x32_bf16(wfr[fr], afr[fc], acc[fr][fc], 0, 0, 0);
      cur ^= 1;
    }
  };

  // ---- stage Hagg panel (f32 -> bf16)
  issueB(g.W2a, 0, 0);
#pragma unroll
  for (int j = 0; j < NC / RPT; j++) {
    const int c = j * RPT + aq;
    uint4 o = cvt8f(g.Hagg + (size_t)(row0 + ar) * SD + c * 8);
    *(uint4*)&Apan[(c * BM + (ar ^ swz(aq))) * 8] = o;
  }
  __syncthreads();

  // ---- step A: Hagg @ W2a -> s1
  kloop(g.W2a);
  __syncthreads();
  if constexpr (!LAST) issueB(g.U1s, 0, 0);

#pragma unroll
  for (int fr = 0; fr < 4; fr++) {
    const int nb = wave * 64 + fr * 16 + lhi * 4;
    const int kc = nb >> 3, off = nb & 7;
    const f32x4 b4 = *(const f32x4*)(g.b2L + nb);
#pragma unroll
    for (int fc = 0; fc < 2; fc++) {
      const int row = fc * 16 + l16;
      const float rc = (float)g.rawcnt[row0 + row];
      float* sp = g.s_out + (size_t)(row0 + row) * SD + nb;
      f32x4 sold = *(const f32x4*)sp;
      alignas(8) __hip_bfloat16 hb[4];
      f32x4 s1;
#pragma unroll
      for (int r = 0; r < 4; r++) {
        s1[r] = sold[r] + acc[fr][fc][r] + rc * b4[r];
        hb[r] = __float2bfloat16(s1[r]);
      }
      *(f32x4*)sp = s1;
      if constexpr (!LAST)
        *(uint2*)&Apan[(kc * BM + (row ^ swz(kc & 7))) * 8 + off] = *(const uint2*)hb;
    }
  }
  if constexpr (LAST) return;

  __syncthreads();   // s1 panel visible; U1(0) landed

  // ---- step B: t = silu(s1@U1 + bU1) -> Apan
  kloop(g.U1s);
  __syncthreads();
  issueB(g.U2s, 0, 0);
#pragma unroll
  for (int fr = 0; fr < 4; fr++) {
    const int nb = wave * 64 + fr * 16 + lhi * 4;
    const int kc = nb >> 3, off = nb & 7;
    const f32x4 b4 = *(const f32x4*)(g.bU1 + nb);
#pragma unroll
    for (int fc = 0; fc < 2; fc++) {
      const int row = fc * 16 + l16;
      alignas(8) __hip_bfloat16 hb[4];
#pragma unroll
      for (int r = 0; r < 4; r++)
        hb[r] = __float2bfloat16(siluf(acc[fr][fc][r] + b4[r]));
      *(uint2*)&Apan[(kc * BM + (row ^ swz(kc & 7))) * 8 + off] = *(const uint2*)hb;
    }
  }
  __syncthreads();   // t panel visible; U2(0) landed

  // ---- step C: s2 = s1 + t@U2 + bU2 (s_o RMW); row stats for LN
  kloop(g.U2s);
  float psum[2] = {0.f, 0.f}, psq[2] = {0.f, 0.f};
#pragma unroll
  for (int fr = 0; fr < 4; fr++) {
    const int nb = wave * 64 + fr * 16 + lhi * 4;
    const f32x4 b4 = *(const f32x4*)(g.bU2 + nb);
#pragma unroll
    for (int fc = 0; fc < 2; fc++) {
      const int row = fc * 16 + l16;
      float* sp = g.s_out + (size_t)(row0 + row) * SD + nb;
      f32x4 sv = *(const f32x4*)sp;
#pragma unroll
      for (int r = 0; r < 4; r++) {
        sv[r] += acc[fr][fc][r] + b4[r];
        psum[fc] += sv[r];
        psq[fc] += sv[r] * sv[r];
      }
      *(f32x4*)sp = sv;
      acc[fr][fc] = sv;   // keep s2 in regs
    }
  }
#pragma unroll
  for (int fc = 0; fc < 2; fc++) {
    psum[fc] += __shfl_xor(psum[fc], 16); psum[fc] += __shfl_xor(psum[fc], 32);
    psq[fc]  += __shfl_xor(psq[fc], 16);  psq[fc]  += __shfl_xor(psq[fc], 32);
  }
  if (lane < 16) {
    red[0][wave][lane] = psum[0]; red[0][wave][16 + lane] = psum[1];
    red[1][wave][lane] = psq[0];  red[1][wave][16 + lane] = psq[1];
  }
  __syncthreads();   // red visible; all waves done reading Apan (t-panel)

  float mu2[2], rs2[2];
#pragma unroll
  for (int fc = 0; fc < 2; fc++) {
    const int ri = fc * 16 + l16;
    const float S = red[0][0][ri] + red[0][1][ri] + red[0][2][ri] + red[0][3][ri];
    const float Q = red[1][0][ri] + red[1][1][ri] + red[1][2][ri] + red[1][3][ri];
    const float mu = S * (1.0f / SD);
    const float var = Q * (1.0f / SD) - mu * mu;
    mu2[fc] = mu; rs2[fc] = rsqrtf(var + 1e-5f);
  }
  // ---- s_ln = LN_{l+1}(s2) -> Apan
#pragma unroll
  for (int fr = 0; fr < 4; fr++) {
    const int nb = wave * 64 + fr * 16 + lhi * 4;
    const int kc = nb >> 3, off = nb & 7;
    const f32x4 g4 = *(const f32x4*)(g.lng + nb);
    const f32x4 bb4 = *(const f32x4*)(g.lnb + nb);
#pragma unroll
    for (int fc = 0; fc < 2; fc++) {
      const int row = fc * 16 + l16;
      alignas(8) __hip_bfloat16 hb[4];
#pragma unroll
      for (int r = 0; r < 4; r++)
        hb[r] = __float2bfloat16(g4[r] * (acc[fr][fc][r] - mu2[fc]) * rs2[fc] + bb4[r]);
      *(uint2*)&Apan[(kc * BM + (row ^ swz(kc & 7))) * 8 + off] = *(const uint2*)hb;
    }
  }
  issueB(g.W1an, 0, 0);
  __syncthreads();   // s_ln panel visible; W1a(0) landed

  // ---- step D: P1 = s_ln @ W1a_{l+1} + b1_{l+1}
  kloop(g.W1an);
#pragma unroll
  for (int fr = 0; fr < 4; fr++) {
    const int nb = wave * 64 + fr * 16 + lhi * 4;
    const f32x4 b4 = *(const f32x4*)(g.b1n + nb);
#pragma unroll
    for (int fc = 0; fc < 2; fc++) {
      const int row = fc * 16 + l16;
      alignas(8) __hip_bfloat16 hb[4];
#pragma unroll
      for (int r = 0; r < 4; r++)
        hb[r] = __float2bfloat16(acc[fr][fc][r] + b4[r]);
      *(uint2*)(g.p1 + (size_t)(row0 + row) * SD + nb) = *(const uint2*)hb;
    }
  }
  // ---- step E: P2 = s_ln @ W1b_{l+1}  (Apan unchanged; B slices wave-private)
  issueB(g.W1bn, 0, 0);
  kloop(g.W1bn);
#pragma unroll
  for (int fr = 0; fr < 4; fr++) {
    const int nb = wave * 64 + fr * 16 + lhi * 4;
#pragma unroll
    for (int fc = 0; fc < 2; fc++) {
      const int row = fc * 16 + l16;
      alignas(8) __hip_bfloat16 hb[4];
#pragma unroll
      for (int r = 0; r < 4; r++)
        hb[r] = __float2bfloat16(acc[fr][fc][r]);
      *(uint2*)(g.p2 + (size_t)(row0 + row) * SD + nb) = *(const uint2*)hb;
    }
  }
}

// ==== fused edge kernel (R8 structure + in-kernel edge attrs) ====
struct FusedArgs {
  const __hip_bfloat16* W1e;
  const __hip_bfloat16* W2s;
  const float* b2L;
  const int* src; const int* tgt;
  const int* rank;
  const float* pos;             // p_o [NN][3]
  const __hip_bfloat16* e_bf;
  const __hip_bfloat16* p1;
  const __hip_bfloat16* p2;
  const __hip_bfloat16* w384;
  float* rnp;                   // [NE][3] out, PERMUTED
  float* mp;                    // [NE][3] out, PERMUTED
  __hip_bfloat16* h_out;        // [NE][256], PERMUTED
  __hip_bfloat16* wv_out;       // [NE][128], PERMUTED
  __hip_bfloat16* e_bf_out;     // [NE][128], edge order
  float* e_f32_out;             // d_out e region, edge order
  int write_e_f32;
};

__global__ __launch_bounds__(256) void fused_k(FusedArgs g) {
  __shared__ alignas(16) unsigned short Ash[4 * 64 * 8];        // 4 KB (edge A)
  __shared__ alignas(16) unsigned short Bsh[2][4 * 256 * 8];    // 32 KB (W stream dbuf)
  __shared__ alignas(16) unsigned short Hsh[32 * 64 * 8];       // 32 KB (psum -> h)
  __shared__ float wps[4][64];
  __shared__ float RnL[64][3];
  __shared__ unsigned int EdL[64][2];
  __shared__ int Rk[64];
  const int tid = threadIdx.x, lane = tid & 63, wave = tid >> 6;
  const int l16 = lane & 15, lhi = lane >> 4;
  const int row0 = blockIdx.x * 64;
  const int ar = tid >> 2, aq = tid & 3;
  const int arow = row0 + ar;
  const int sn = g.src[arow], tn = g.tgt[arow];

  auto issueW = [&](const __hip_bfloat16* W, int t, int buf) {
    const __hip_bfloat16* src = W + (size_t)t * 1024 * 8;
    unsigned short* dst = &Bsh[buf][0];
#pragma unroll
    for (int i = 0; i < 4; i++)
      gl_lds16(src + (size_t)(i * 256 + wave * 64 + lane) * 8, dst + (i * 256 + wave * 64) * 8);
  };
  auto loadA = [&](int t, uint4& o) {
    if (t < 4) {
      o = *(const uint4*)(g.e_bf + (size_t)arow * ED + t * 32 + aq * 8);
    } else {
      o.x = o.y = o.z = o.w = 0;
      if (aq == 0) { o.x = EdL[ar][0]; o.y = EdL[ar][1]; }
    }
  };

  uint4 a;
  loadA(0, a);
  issueW(g.W1e, 0, 0);

  // ---- in-kernel edge attrs (replaces edge_attr_k): d,a,pn -> EdL; rn -> RnL + rnp
  if (tid < 64) {
    const int e = row0 + tid;
    const int rk = g.rank[e];
    Rk[tid] = rk;
    const int s_ = g.src[e], t_ = g.tgt[e];
    const float sx = g.pos[s_ * 3], sy = g.pos[s_ * 3 + 1], sz = g.pos[s_ * 3 + 2];
    const float tx = g.pos[t_ * 3], ty = g.pos[t_ * 3 + 1], tz = g.pos[t_ * 3 + 2];
    const float rx = tx - sx, ry = ty - sy, rz = tz - sz;
    const float av = tx * sx + ty * sy + tz * sz;
    const float rr = rx * rx + ry * ry + rz * rz;
    const float d = sqrtf(fmaxf(rr, 1e-6f));
    const float inv = 1.0f / (1.0f + d);
    const float r0 = rx * inv, r1 = ry * inv, r2 = rz * inv;
    RnL[tid][0] = r0; RnL[tid][1] = r1; RnL[tid][2] = r2;
    g.rnp[rk * 3] = r0; g.rnp[rk * 3 + 1] = r1; g.rnp[rk * 3 + 2] = r2;
    alignas(8) __hip_bfloat16 q[4];
    q[0] = __float2bfloat16(d);
    q[1] = __float2bfloat16(av);
    q[2] = __float2bfloat16(sqrtf(sx * sx + sy * sy + sz * sz));
    q[3] = __float2bfloat16(sqrtf(tx * tx + ty * ty + tz * tz));
    EdL[tid][0] = ((const unsigned*)q)[0];
    EdL[tid][1] = ((const unsigned*)q)[1];
  }

  // ---- stage Psum = P1[sn] + P2[tn] into Hsh
#pragma unroll
  for (int j = 0; j < 8; j++) {
    const int c = j * 4 + aq;
    uint4 r1 = *(const uint4*)(g.p1 + (size_t)sn * SD + c * 8);
    uint4 r2 = *(const uint4*)(g.p2 + (size_t)tn * SD + c * 8);
    const __hip_bfloat16* h1 = (const __hip_bfloat16*)&r1;
    const __hip_bfloat16* h2 = (const __hip_bfloat16*)&r2;
    alignas(16) __hip_bfloat16 o8[8];
#pragma unroll
    for (int m = 0; m < 8; m++)
      o8[m] = __float2bfloat16(__bfloat162float(h1[m]) + __bfloat162float(h2[m]));
    *(uint4*)&Hsh[(c * 64 + (ar ^ swz(aq))) * 8] = *(const uint4*)o8;
  }

  // ---- phase 1: SWAPPED operands -> D[n][row]
  f32x4 acc1[4][4] = {};
  int cur = 0;
  for (int t = 0; t < TE; ++t) {
    *(uint4*)&Ash[apos(aq, ar) * 8] = a;
    __syncthreads();
    if (t + 1 < TE) { issueW(g.W1e, t + 1, cur ^ 1); loadA(t + 1, a); }
    bf16x8 wfr[4], efr[4];
#pragma unroll
    for (int f = 0; f < 4; f++) {
      wfr[f] = *(const bf16x8*)&Bsh[cur][bpos(lhi, wave * 64 + f * 16 + l16) * 8];
      efr[f] = *(const bf16x8*)&Ash[apos(lhi, f * 16 + l16) * 8];
    }
#pragma unroll
    for (int fr = 0; fr < 4; fr++)
#pragma unroll
      for (int fc = 0; fc < 4; fc++)
        acc1[fr][fc] = __builtin_amdgcn_mfma_f32_16x16x32_bf16(wfr[fr], efr[fc], acc1[fr][fc], 0, 0, 0);
    __syncthreads();
    cur ^= 1;
  }

  issueW(g.W2s, 0, 0);

  // ---- epilogue-1: h = silu(acc1 + psum); Hsh in-place; global h (PERMUTED); wp partials
  float pw[4] = {0.f, 0.f, 0.f, 0.f};
#pragma unroll
  for (int fr = 0; fr < 4; fr++) {
    const int nb = wave * 64 + fr * 16 + lhi * 4;
    const int kc = nb >> 3, off = nb & 7;
    uint2 wr = *(const uint2*)(g.w384 + nb);
    const __hip_bfloat16* w4 = (const __hip_bfloat16*)&wr;
#pragma unroll
    for (int fc = 0; fc < 4; fc++) {
      const int row = fc * 16 + l16;
      unsigned short* slot = &Hsh[(kc * 64 + (row ^ swz(kc & 3))) * 8 + off];
      uint2 pr = *(const uint2*)slot;
      const __hip_bfloat16* pp = (const __hip_bfloat16*)&pr;
      alignas(8) __hip_bfloat16 hb[4];
#pragma unroll
      for (int r = 0; r < 4; r++) {
        const float hv = siluf(acc1[fr][fc][r] + __bfloat162float(pp[r]));
        hb[r] = __float2bfloat16(hv);
        pw[fc] += hv * __bfloat162float(w4[r]);
      }
      *(uint2*)slot = *(const uint2*)hb;
      *(uint2*)(g.h_out + (size_t)Rk[row] * HIDc + nb) = *(const uint2*)hb;
    }
  }

  // ---- wp reduce
#pragma unroll
  for (int fc = 0; fc < 4; fc++) {
    pw[fc] += __shfl_xor(pw[fc], 16);
    pw[fc] += __shfl_xor(pw[fc], 32);
  }
  if (lane < 16) {
#pragma unroll
    for (int fc = 0; fc < 4; fc++) wps[wave][fc * 16 + lane] = pw[fc];
  }
  __syncthreads();
  if (tid < 64) {
    const float s = wps[0][tid] + wps[1][tid] + wps[2][tid] + wps[3][tid];
    const float wpt = tanhf(s + g.b2L[384]);
    const int rk = Rk[tid];
#pragma unroll
    for (int c = 0; c < 3; c++)
      g.mp[(size_t)rk * 3 + c] = wpt * RnL[tid][c];
  }

  // ---- phase 2: out2 = h @ W2s. Barrier-free; Bsh[2] dbuf, counted vmcnt(4).
  f32x4 acc2[4][4] = {};
  cur = 0;
  for (int t = 0; t < T2; ++t) {
    if (t + 1 < T2) { issueW(g.W2s, t + 1, cur ^ 1); wait_vm4(); }
    else            { wait_vm0(); }
    bf16x8 afr[4], bfr[4];
#pragma unroll
    for (int f = 0; f < 4; f++) {
      const int kc = t * 4 + lhi;
      afr[f] = *(const bf16x8*)&Hsh[(kc * 64 + ((f * 16 + l16) ^ swz(lhi))) * 8];
      bfr[f] = *(const bf16x8*)&Bsh[cur][bpos(lhi, wave * 64 + f * 16 + l16) * 8];
    }
#pragma unroll
    for (int fr = 0; fr < 4; fr++)
#pragma unroll
      for (int fc = 0; fc < 4; fc++)
        acc2[fr][fc] = __builtin_amdgcn_mfma_f32_16x16x32_bf16(afr[fr], bfr[fc], acc2[fr][fc], 0, 0, 0);
    cur ^= 1;
  }

  // ---- epilogue-2: wv (PERMUTED) | e_new (edge order)
#pragma unroll
  for (int fr = 0; fr < 4; fr++) {
#pragma unroll
    for (int fc = 0; fc < 4; fc++) {
      const int n = wave * 64 + fc * 16 + l16;
#pragma unroll
      for (int r = 0; r < 4; r++) {
        const int lr = fr * 16 + lhi * 4 + r;
        const int row = row0 + lr;
        const float valf = acc2[fr][fc][r];
        if (n < 128) {
          g.wv_out[(size_t)Rk[lr] * 128 + n] = __float2bfloat16(valf + g.b2L[256 + n]);
        } else {
          const float sv = siluf(valf + g.b2L[257 + n]);
          g.e_bf_out[(size_t)row * ED + (n - 128)] = __float2bfloat16(sv);
          if (g.write_e_f32) g.e_f32_out[(size_t)row * ED + (n - 128)] = sv;
        }
      }
    }
  }
}

// ---- LayerNorm (layer 0 only). 4 nodes/block, wave per node.
__global__ __launch_bounds__(256) void ln_k(const float* __restrict__ s,
                                            const float* __restrict__ gl, const float* __restrict__ bl,
                                            __hip_bfloat16* __restrict__ s_ln) {
  const int wave = threadIdx.x >> 6, lane = threadIdx.x & 63;
  const int node = blockIdx.x * 4 + wave;
  const float* srow = s + (size_t)node * SD;
  float x[4], sum = 0.f, sq = 0.f;
#pragma unroll
  for (int i = 0; i < 4; i++) { x[i] = srow[lane * 4 + i]; sum += x[i]; sq += x[i] * x[i]; }
#pragma unroll
  for (int off = 1; off < 64; off <<= 1) { sum += __shfl_xor(sum, off); sq += __shfl_xor(sq, off); }
  const float mu = sum * (1.0f / SD);
  const float var = sq * (1.0f / SD) - mu * mu;
  const float rstd = rsqrtf(var + 1e-5f);
#pragma unroll
  for (int i = 0; i < 4; i++) {
    const int c = lane * 4 + i;
    s_ln[(size_t)node * SD + c] = __float2bfloat16(gl[c] * (x[i] - mu) * rstd + bl[c]);
  }
}

__global__ void cvt_e_k(const float* __restrict__ e, __hip_bfloat16* __restrict__ ebf) {
  const int i = blockIdx.x * blockDim.x + threadIdx.x;
  const float* p = e + (size_t)i * 8;
  alignas(16) __hip_bfloat16 t8[8];
#pragma unroll
  for (int j = 0; j < 8; j++) t8[j] = __float2bfloat16(p[j]);
  *(uint4*)(ebf + (size_t)i * 8) = *(const uint4*)t8;
}

__global__ void count_k(const int* __restrict__ tgt, int* __restrict__ rawcnt) {
  const int e = blockIdx.x * blockDim.x + threadIdx.x;
  if (e < NE) atomicAdd(&rawcnt[tgt[e]], 1);
}

__global__ __launch_bounds__(256) void scan_k(const int* __restrict__ rawcnt, int* __restrict__ off) {
  __shared__ int ts[256];
  const int tid = threadIdx.x;
  const int base = tid * 32;
  int local[32];
  int s = 0;
#pragma unroll
  for (int i = 0; i < 32; i++) { local[i] = s; s += rawcnt[base + i]; }
  ts[tid] = s;
  __syncthreads();
  if (tid == 0) {
    int acc = 0;
    for (int i = 0; i < 256; i++) { int t = ts[i]; ts[i] = acc; acc += t; }
    off[NN] = acc;
  }
  __syncthreads();
  const int pre = ts[tid];
#pragma unroll
  for (int i = 0; i < 32; i++) off[base + i] = pre + local[i];
}

__global__ void scatter_k(const int* __restrict__ tgt, const int* __restrict__ srcp,
                          const int* __restrict__ off,
                          int* __restrict__ cursor, int* __restrict__ rank, int* __restrict__ psrc) {
  const int e = blockIdx.x * blockDim.x + threadIdx.x;
  if (e < NE) {
    const int t = tgt[e];
    const int pos = off[t] + atomicAdd(&cursor[t], 1);
    rank[e] = pos;
    psrc[pos] = srcp[e];
  }
}

// ---- CSR aggregation: one block per node; sequential payload reads.
__global__ __launch_bounds__(256) void agg_k(const int* __restrict__ off, const int* __restrict__ psrc,
                                             const __hip_bfloat16* __restrict__ h,
                                             const __hip_bfloat16* __restrict__ wv,
                                             const float* __restrict__ mp,
                                             const float* __restrict__ rnp,
                                             const float* __restrict__ v_old,
                                             float* __restrict__ v_new,
                                             float* __restrict__ Hagg,
                                             float* __restrict__ p_o,
                                             int hasv) {
  const int n = blockIdx.x;
  const int c = threadIdx.x;
  const int e0 = off[n], e1 = off[n + 1];
  const int c3 = c >> 6, ln = c & 63;
  float hs = 0.f, vs = 0.f, ps = 0.f;
  int j = e0;
  for (; j + 2 <= e1; j += 2) {
    const float h0 = __bfloat162float(h[(size_t)j * HIDc + c]);
    const float h1 = __bfloat162float(h[(size_t)(j + 1) * HIDc + c]);
    hs += h0 + h1;
    if (c < 192) {
      const int s0 = psrc[j], s1 = psrc[j + 1];
      float m0 = __bfloat162float(wv[(size_t)j * 128 + 64 + ln]) * rnp[j * 3 + c3];
      float m1 = __bfloat162float(wv[(size_t)(j + 1) * 128 + 64 + ln]) * rnp[(j + 1) * 3 + c3];
      if (hasv) {
        m0 += __bfloat162float(wv[(size_t)j * 128 + ln]) * v_old[(size_t)s0 * 192 + c];
        m1 += __bfloat162float(wv[(size_t)(j + 1) * 128 + ln]) * v_old[(size_t)s1 * 192 + c];
      }
      vs += m0 + m1;
    } else if (c < 195) {
      ps += mp[j * 3 + (c - 192)] + mp[(j + 1) * 3 + (c - 192)];
    }
  }
  for (; j < e1; j++) {
    hs += __bfloat162float(h[(size_t)j * HIDc + c]);
    if (c < 192) {
      float mv = __bfloat162float(wv[(size_t)j * 128 + 64 + ln]) * rnp[j * 3 + c3];
      if (hasv) mv += __bfloat162float(wv[(size_t)j * 128 + ln]) * v_old[(size_t)psrc[j] * 192 + c];
      vs += mv;
    } else if (c < 195) {
      ps += mp[j * 3 + (c - 192)];
    }
  }
  Hagg[(size_t)n * HIDc + c] = hs;
  const float inv = 1.0f / fmaxf((float)(e1 - e0), 1.0f);
  if (c < 192)      v_new[(size_t)n * 192 + c] = v_old[(size_t)n * 192 + c] + vs * inv;
  else if (c < 195) p_o[n * 3 + (c - 192)]    += ps * inv;
}

__global__ void zero_k(float* __restrict__ ptr, int n) {
  const int i = blockIdx.x * blockDim.x + threadIdx.x;
  if (i < n) ptr[i] = 0.f;
}

// ---- weight prep -> swizzled streams
__global__ void prep_w1abs_k(const float* __restrict__ W1, __hip_bfloat16* __restrict__ W1aS,
                             __hip_bfloat16* __restrict__ W1bS) {
  const int idx = blockIdx.x * blockDim.x + threadIdx.x;
  if (idx >= NL * T2 * 1024) return;
  const int p = idx & 1023, t = (idx >> 10) % T2, l = idx / (T2 * 1024);
  const int kc = p >> 8, n = (p & 255) ^ swz(kc);
  alignas(16) __hip_bfloat16 a8[8], b8[8];
#pragma unroll
  for (int j = 0; j < 8; j++) {
    const int k = t * 32 + kc * 8 + j;
    a8[j] = __float2bfloat16(W1[((size_t)l * DINc + k) * HIDc + n]);
    b8[j] = __float2bfloat16(W1[((size_t)l * DINc + 256 + k) * HIDc + n]);
  }
  *(uint4*)(W1aS + (size_t)idx * 8) = *(const uint4*)a8;
  *(uint4*)(W1bS + (size_t)idx * 8) = *(const uint4*)b8;
}

__global__ void prep_w1es_k(const float* __restrict__ W1, __hip_bfloat16* __restrict__ W1eS) {
  const int idx = blockIdx.x * blockDim.x + threadIdx.x;
  if (idx >= NL * TE * 1024) return;
  const int p = idx & 1023, t = (idx >> 10) % TE, l = idx / (TE * 1024);
  const int kc = p >> 8, n = (p & 255) ^ swz(kc);
  alignas(16) __hip_bfloat16 e8[8];
#pragma unroll
  for (int j = 0; j < 8; j++) {
    const int k = t * 32 + kc * 8 + j;
    const int row = (k < 128) ? (512 + k) : ((k < 132) ? (640 + (k - 128)) : -1);
    e8[j] = __float2bfloat16(row >= 0 ? W1[((size_t)l * DINc + row) * HIDc + n] : 0.f);
  }
  *(uint4*)(W1eS + (size_t)idx * 8) = *(const uint4*)e8;
}

__global__ void prep_w2s_k(const float* __restrict__ W2, __hip_bfloat16* __restrict__ W2sS,
                           __hip_bfloat16* __restrict__ W2aS) {
  const int idx = blockIdx.x * blockDim.x + threadIdx.x;
  if (idx >= NL * T2 * 1024) return;
  const int p = idx & 1023, t = (idx >> 10) & 7, l = idx >> 13;
  const int kc = p >> 8, n = (p & 255) ^ swz(kc);
  const float* W2l = W2 + (size_t)l * HIDc * DOUTc;
  const int cs = (n < 128) ? (256 + n) : (257 + n);
  alignas(16) __hip_bfloat16 s8[8], a8[8];
#pragma unroll
  for (int j = 0; j < 8; j++) {
    const int k = t * 32 + kc * 8 + j;
    s8[j] = __float2bfloat16(W2l[(size_t)k * DOUTc + cs]);
    a8[j] = __float2bfloat16(W2l[(size_t)k * DOUTc + n]);
  }
  *(uint4*)(W2sS + (size_t)idx * 8) = *(const uint4*)s8;
  *(uint4*)(W2aS + (size_t)idx * 8) = *(const uint4*)a8;
}

__global__ void prep_uts_k(const float* __restrict__ U1, const float* __restrict__ U2,
                           __hip_bfloat16* __restrict__ U1S, __hip_bfloat16* __restrict__ U2S) {
  const int idx = blockIdx.x * blockDim.x + threadIdx.x;
  if (idx >= NL * T2 * 1024) return;
  const int p = idx & 1023, t = (idx >> 10) & 7, l = idx >> 13;
  const int kc = p >> 8, n = (p & 255) ^ swz(kc);
  alignas(16) __hip_bfloat16 u1[8], u2[8];
#pragma unroll
  for (int j = 0; j < 8; j++) {
    const int k = t * 32 + kc * 8 + j;
    u1[j] = __float2bfloat16(U1[((size_t)l * HIDc + k) * HIDc + n]);
    u2[j] = __float2bfloat16(U2[((size_t)l * HIDc + k) * HIDc + n]);
  }
  *(uint4*)(U1S + (size_t)idx * 8) = *(const uint4*)u1;
  *(uint4*)(U2S + (size_t)idx * 8) = *(const uint4*)u2;
}

__global__ void prep_w384_k(const float* __restrict__ W2, __hip_bfloat16* __restrict__ w384) {
  const int idx = blockIdx.x * blockDim.x + threadIdx.x;
  if (idx >= NL * HIDc) return;
  const int k = idx & 255, l = idx >> 8;
  w384[idx] = __float2bfloat16(W2[((size_t)l * HIDc + k) * DOUTc + 384]);
}

}  // namespace

extern "C" void kernel_launch(void* const* d_in, const int* in_sizes, int n_in,
                              void* d_out, int out_size, void* d_ws, size_t ws_size,
                              hipStream_t stream) {
  (void)in_sizes; (void)n_in; (void)out_size; (void)ws_size;
  const float* s_in = (const float*)d_in[0];
  const float* v_in = (const float*)d_in[1];
  const float* p_in = (const float*)d_in[2];
  const float* e_in = (const float*)d_in[3];
  const int*   ei   = (const int*)d_in[4];
  const float* ln_g = (const float*)d_in[5];
  const float* ln_b = (const float*)d_in[6];
  const float* W1   = (const float*)d_in[7];
  const float* b1   = (const float*)d_in[8];
  const float* W2   = (const float*)d_in[9];
  const float* b2   = (const float*)d_in[10];
  const float* U1   = (const float*)d_in[11];
  const float* bU1  = (const float*)d_in[12];
  const float* U2   = (const float*)d_in[13];
  const float* bU2  = (const float*)d_in[14];

  float* s_o = (float*)d_out;
  float* v_o = s_o + (size_t)NN * SD;
  float* e_o = v_o + (size_t)NN * 192;
  float* p_o = e_o + (size_t)NE * ED;

  const int* srcp = ei;
  const int* tgtp = ei + NE;

  char* wp = (char*)d_ws;
  auto alloc = [&](size_t bytes) -> char* {
    char* r = wp; wp += (bytes + 255) & ~(size_t)255; return r;
  };
  __hip_bfloat16* s_ln = (__hip_bfloat16*)alloc((size_t)NN * SD * 2);
  __hip_bfloat16* hbuf = (__hip_bfloat16*)alloc((size_t)NE * HIDc * 2);
  __hip_bfloat16* ebf  = (__hip_bfloat16*)alloc((size_t)NE * ED * 2);
  __hip_bfloat16* wvbuf= (__hip_bfloat16*)alloc((size_t)NE * 128 * 2);
  __hip_bfloat16* p1buf= (__hip_bfloat16*)alloc((size_t)NN * SD * 2);
  __hip_bfloat16* p2buf= (__hip_bfloat16*)alloc((size_t)NN * SD * 2);
  float* rnpbuf= (float*)alloc((size_t)NE * 3 * 4);
  float* Hagg  = (float*)alloc((size_t)NN * SD * 4);
  float* vprev = (float*)alloc((size_t)NN * 192 * 4);
  float* mpbuf = (float*)alloc((size_t)NE * 3 * 4);
  float* zerobias = (float*)alloc(256 * 4);
  int*   rawcnt= (int*)alloc((size_t)NN * 4);
  int*   offb  = (int*)alloc((size_t)(NN + 1) * 4);
  int*   cursor= (int*)alloc((size_t)NN * 4);
  int*   rankb = (int*)alloc((size_t)NE * 4);
  int*   psrcb = (int*)alloc((size_t)NE * 4);
  __hip_bfloat16* W1aS = (__hip_bfloat16*)alloc((size_t)NL * T2 * 1024 * 8 * 2);
  __hip_bfloat16* W1bS = (__hip_bfloat16*)alloc((size_t)NL * T2 * 1024 * 8 * 2);
  __hip_bfloat16* W1eS = (__hip_bfloat16*)alloc((size_t)NL * TE * 1024 * 8 * 2);
  __hip_bfloat16* W2sS = (__hip_bfloat16*)alloc((size_t)NL * T2 * 1024 * 8 * 2);
  __hip_bfloat16* W2aS = (__hip_bfloat16*)alloc((size_t)NL * T2 * 1024 * 8 * 2);
  __hip_bfloat16* U1S  = (__hip_bfloat16*)alloc((size_t)NL * T2 * 1024 * 8 * 2);
  __hip_bfloat16* U2S  = (__hip_bfloat16*)alloc((size_t)NL * T2 * 1024 * 8 * 2);
  __hip_bfloat16* w384 = (__hip_bfloat16*)alloc((size_t)NL * HIDc * 2);

  hipMemcpyAsync(s_o, s_in, (size_t)NN * SD * 4, hipMemcpyDeviceToDevice, stream);
  hipMemcpyAsync(vprev, v_in, (size_t)NN * 192 * 4, hipMemcpyDeviceToDevice, stream);
  hipMemcpyAsync(p_o, p_in, (size_t)NN * 3 * 4, hipMemcpyDeviceToDevice, stream);

  prep_w1abs_k<<<(NL * T2 * 1024 + 255) / 256, 256, 0, stream>>>(W1, W1aS, W1bS);
  prep_w1es_k<<<(NL * TE * 1024 + 255) / 256, 256, 0, stream>>>(W1, W1eS);
  prep_w2s_k<<<(NL * T2 * 1024 + 255) / 256, 256, 0, stream>>>(W2, W2sS, W2aS);
  prep_uts_k<<<(NL * T2 * 1024 + 255) / 256, 256, 0, stream>>>(U1, U2, U1S, U2S);
  prep_w384_k<<<(NL * HIDc + 255) / 256, 256, 0, stream>>>(W2, w384);
  cvt_e_k<<<NE * ED / 8 / 256, 256, 0, stream>>>(e_in, ebf);
  zero_k<<<1, 256, 0, stream>>>(zerobias, 256);

  // ---- CSR build (once; edge_index layer-invariant)
  zero_k<<<(NN + 255) / 256, 256, 0, stream>>>((float*)rawcnt, NN);
  zero_k<<<(NN + 255) / 256, 256, 0, stream>>>((float*)cursor, NN);
  count_k<<<NE / 256, 256, 0, stream>>>(tgtp, rawcnt);
  scan_k<<<1, 256, 0, stream>>>(rawcnt, offb);
  scatter_k<<<NE / 256, 256, 0, stream>>>(tgtp, srcp, offb, cursor, rankb, psrcb);

  // ---- layer 0: LN + P1/P2 (subsequent layers fold these into node3)
  ln_k<<<NN / 4, 256, 0, stream>>>(s_o, ln_g, ln_b, s_ln);
  GemmArgs gp{};
  gp.Wt = W1aS; gp.bias = b1; gp.bf_out = p1buf;
  gp.Wtb = W1bS; gp.biasb = zerobias; gp.bf_outb = p2buf;
  gp.Abf = s_ln; gp.dual = 1;
  gemm_k<256, 64><<<2 * NN / 64, 256, 0, stream>>>(gp);

  for (int l = 0; l < NL; l++) {
    // fused edge kernel: attrs + h + out2 (h/wv/mp/rnp written at rank[e])
    FusedArgs gf{};
    gf.W1e = W1eS + (size_t)l * TE * 1024 * 8;
    gf.W2s = W2sS + (size_t)l * T2 * 1024 * 8;
    gf.b2L = b2 + l * DOUTc;
    gf.src = srcp; gf.tgt = tgtp; gf.rank = rankb;
    gf.pos = p_o; gf.e_bf = ebf;
    gf.p1 = p1buf; gf.p2 = p2buf; gf.w384 = w384 + l * HIDc;
    gf.rnp = rnpbuf; gf.mp = mpbuf;
    gf.h_out = hbuf; gf.wv_out = wvbuf; gf.e_bf_out = ebf; gf.e_f32_out = e_o;
    gf.write_e_f32 = (l == NL - 1) ? 1 : 0;
    fused_k<<<NE / 64, 256, 0, stream>>>(gf);

    // v ping-pong: 5 layers -> final write lands in v_o.
    const float* vold = (l & 1) ? (const float*)v_o : (const float*)vprev;
    float* vnew = (l & 1) ? vprev : v_o;
    agg_k<<<NN, 256, 0, stream>>>(offb, psrcb, hbuf, wvbuf, mpbuf, rnpbuf,
                                  vold, vnew, Hagg, p_o, (l > 0) ? 1 : 0);

    // fused node MLP (+ next-layer LN/P1/P2 when l<4)
    Node3Args gn{};
    gn.W2a = W2aS + (size_t)l * T2 * 1024 * 8;
    gn.U1s = U1S + (size_t)l * T2 * 1024 * 8;
    gn.U2s = U2S + (size_t)l * T2 * 1024 * 8;
    gn.b2L = b2 + l * DOUTc; gn.bU1 = bU1 + l * HIDc; gn.bU2 = bU2 + l * HIDc;
    gn.Hagg = Hagg; gn.rawcnt = rawcnt; gn.s_out = s_o;
    if (l < NL - 1) {
      gn.W1an = W1aS + (size_t)(l + 1) * T2 * 1024 * 8;
      gn.W1bn = W1bS + (size_t)(l + 1) * T2 * 1024 * 8;
      gn.b1n = b1 + (l + 1) * HIDc;
      gn.lng = ln_g + (l + 1) * SD; gn.lnb = ln_b + (l + 1) * SD;
      gn.p1 = p1buf; gn.p2 = p2buf;
      node3_k<0><<<NN / 32, 256, 0, stream>>>(gn);
    } else {
      node3_k<1><<<NN / 32, 256, 0, stream>>>(gn);
    }
  }
}